// Round 1
// baseline (2907.598 us; speedup 1.0000x reference)
//
#include <hip/hip_runtime.h>

typedef unsigned short u16;
typedef __attribute__((ext_vector_type(4))) float f32x4;
typedef __attribute__((ext_vector_type(8))) short short8;
typedef __attribute__((ext_vector_type(4))) unsigned int uv4;
typedef __attribute__((ext_vector_type(4))) float fv4;
typedef __attribute__((ext_vector_type(4))) unsigned short usv4;

#define S_LEN 2048
#define NBLK 128
#define DMODEL 512
#define VOCAB 32000
#define QLEN 2048
#define KVLEN 4096
#define CSPLIT 20
#define NCHUNK 25   // 25 chunks of 64 cols = 1600 cols per split; 20*1600 = 32000

__device__ __forceinline__ float bf2f(u16 u){
  union { unsigned int i; float f; } x; x.i = ((unsigned int)u) << 16; return x.f;
}
__device__ __forceinline__ u16 f2bf(float f){
  union { float f; unsigned int i; } x; x.f = f;
  unsigned int r = x.i + 0x7fffu + ((x.i >> 16) & 1u);
  return (u16)(r >> 16);
}
__device__ __forceinline__ float wred_max(float v){
  #pragma unroll
  for (int o = 32; o >= 1; o >>= 1) v = fmaxf(v, __shfl_xor(v, o));
  return v;
}
__device__ __forceinline__ float wred_sum(float v){
  #pragma unroll
  for (int o = 32; o >= 1; o >>= 1) v += __shfl_xor(v, o);
  return v;
}

// ---------------- transpose + cast f32(K,N) -> bf16(N,K) ----------------
__global__ __launch_bounds__(256) void transpose_cast(const float* __restrict__ in,
                                                      u16* __restrict__ out,
                                                      int K, int N){
  __shared__ float tile[32][33];
  int t = threadIdx.x, tx = t & 31, ty = t >> 5;
  int nb = blockIdx.x * 32, kb = blockIdx.y * 32;
  #pragma unroll
  for (int i = 0; i < 4; i++){
    int r = ty + i * 8;
    tile[r][tx] = in[(size_t)(kb + r) * N + nb + tx];
  }
  __syncthreads();
  #pragma unroll
  for (int i = 0; i < 4; i++){
    int r = ty + i * 8;
    out[(size_t)(nb + r) * K + kb + tx] = f2bf(tile[tx][r]);
  }
}

// ---------------- build kv_in (bf16 4096x512): [hidden ; noise_embedding] ----------------
__global__ __launch_bounds__(128) void build_kv(const float* __restrict__ hidden,
                                                const float* __restrict__ embed,
                                                const int* __restrict__ input_ids,
                                                const int* __restrict__ anchors,
                                                const unsigned char* __restrict__ keep,
                                                u16* __restrict__ kvb){
  int row = blockIdx.x;           // 0..4095
  int t = threadIdx.x;            // 0..127
  const float* src;
  if (row < S_LEN){
    src = hidden + (size_t)row * DMODEL;
  } else {
    int q = row - S_LEN;
    int id = 3;                   // MASK_TOKEN_ID
    if ((q & 15) == 0){
      int n = q >> 4;
      if (keep[n]){
        int a = anchors[n]; a = min(max(a, 0), S_LEN - 1);
        id = input_ids[a];
      }
    }
    src = embed + (size_t)id * DMODEL;
  }
  int c = t * 4;
  fv4 v = *(const fv4*)&src[c];
  usv4 o; o[0] = f2bf(v[0]); o[1] = f2bf(v[1]); o[2] = f2bf(v[2]); o[3] = f2bf(v[3]);
  *(usv4*)&kvb[(size_t)row * DMODEL + c] = o;
}

// ---------------- generic 64x64 tile bf16 GEMM: C[M,N] = A[M,K] * B[K,N], B given transposed (N,K) ----------------
template<int TRANS>
__global__ __launch_bounds__(256) void gemm64(const u16* __restrict__ A,
                                              const u16* __restrict__ BT,
                                              u16* __restrict__ C,
                                              int M, int N, int K, int ldc){
  __shared__ __align__(16) u16 As[64][72];
  __shared__ __align__(16) u16 Bs[64][72];
  int t = threadIdx.x, w = t >> 6, lane = t & 63;
  int wm = w >> 1, wn = w & 1;
  int rowbase = blockIdx.x * 64, colbase = blockIdx.y * 64;
  f32x4 acc[2][2];
  #pragma unroll
  for (int i = 0; i < 2; i++)
    #pragma unroll
    for (int j = 0; j < 2; j++)
      acc[i][j] = (f32x4){0.f, 0.f, 0.f, 0.f};

  int srow = t >> 2, sc0 = (t & 3) * 8;
  for (int kb = 0; kb < K; kb += 64){
    __syncthreads();
    *(uv4*)&As[srow][sc0]      = *(const uv4*)&A [(size_t)(rowbase + srow) * K + kb + sc0];
    *(uv4*)&As[srow][sc0 + 32] = *(const uv4*)&A [(size_t)(rowbase + srow) * K + kb + sc0 + 32];
    *(uv4*)&Bs[srow][sc0]      = *(const uv4*)&BT[(size_t)(colbase + srow) * K + kb + sc0];
    *(uv4*)&Bs[srow][sc0 + 32] = *(const uv4*)&BT[(size_t)(colbase + srow) * K + kb + sc0 + 32];
    __syncthreads();
    #pragma unroll
    for (int ks = 0; ks < 2; ks++){
      int ko = ks * 32 + (lane >> 4) * 8;
      short8 a0 = *(const short8*)&As[wm * 32 +      (lane & 15)][ko];
      short8 a1 = *(const short8*)&As[wm * 32 + 16 + (lane & 15)][ko];
      short8 b0 = *(const short8*)&Bs[wn * 32 +      (lane & 15)][ko];
      short8 b1 = *(const short8*)&Bs[wn * 32 + 16 + (lane & 15)][ko];
      acc[0][0] = __builtin_amdgcn_mfma_f32_16x16x32_bf16(a0, b0, acc[0][0], 0, 0, 0);
      acc[0][1] = __builtin_amdgcn_mfma_f32_16x16x32_bf16(a0, b1, acc[0][1], 0, 0, 0);
      acc[1][0] = __builtin_amdgcn_mfma_f32_16x16x32_bf16(a1, b0, acc[1][0], 0, 0, 0);
      acc[1][1] = __builtin_amdgcn_mfma_f32_16x16x32_bf16(a1, b1, acc[1][1], 0, 0, 0);
    }
  }
  #pragma unroll
  for (int mf = 0; mf < 2; mf++)
    #pragma unroll
    for (int nf = 0; nf < 2; nf++)
      #pragma unroll
      for (int r = 0; r < 4; r++){
        int row = rowbase + wm * 32 + mf * 16 + (lane >> 4) * 4 + r;
        int col = colbase + wn * 32 + nf * 16 + (lane & 15);
        u16 vv = f2bf(acc[mf][nf][r]);
        if (TRANS) C[(size_t)col * ldc + row] = vv;
        else       C[(size_t)row * ldc + col] = vv;
      }
}

// ---------------- attention: one (draft block n, head h) per workgroup ----------------
__global__ __launch_bounds__(256) void attn_kernel(const u16* __restrict__ qb,
                                                   const u16* __restrict__ kT,   // (512, 4096)
                                                   const u16* __restrict__ vb,   // (4096, 512)
                                                   const int* __restrict__ anchors,
                                                   const unsigned char* __restrict__ keep,
                                                   u16* __restrict__ attnb){
  int n = blockIdx.x, h = blockIdx.y;
  int t = threadIdx.x, w = t >> 6, lane = t & 63;
  __shared__ float q_s[16][64];
  #pragma unroll
  for (int i = 0; i < 4; i++){
    int e = t + i * 256; int r = e >> 6, d = e & 63;
    q_s[r][d] = bf2f(qb[(size_t)(n * 16 + r) * DMODEL + h * 64 + d]);
  }
  __syncthreads();
  int anchor = anchors[n];
  bool kp = keep[n] != 0;
  const u16* kTh = kT + (size_t)h * 64 * KVLEN;
  const u16* vh  = vb + h * 64;

  for (int rr = 0; rr < 4; rr++){
    int row = w * 4 + rr;
    float outv;
    if (kp){
      float m = -3e38f, l = 0.f, acc = 0.f;
      // context keys [0, anchor) then the 16 draft keys of block n
      for (int seg = 0; seg < 2; seg++){
        int segbase = (seg == 0) ? 0 : (S_LEN + n * 16);
        int seglen  = (seg == 0) ? anchor : 16;
        for (int kb = 0; kb < seglen; kb += 64){
          int nk = min(64, seglen - kb);
          int key = segbase + kb + ((lane < nk) ? lane : 0);
          float s = 0.f;
          #pragma unroll
          for (int d = 0; d < 64; d++)
            s += q_s[row][d] * bf2f(kTh[(size_t)d * KVLEN + key]);
          s *= 0.125f;
          if (lane >= nk) s = -3e38f;
          float cmax = wred_max(s);
          float mn = fmaxf(m, cmax);
          float sc = expf(m - mn);
          float p = (lane < nk) ? expf(s - mn) : 0.f;
          float ps = wred_sum(p);
          l = l * sc + ps;
          acc *= sc;
          for (int j = 0; j < nk; j++){
            float pj = __shfl(p, j);
            acc += pj * bf2f(vh[(size_t)(segbase + kb + j) * DMODEL + lane]);
          }
          m = mn;
        }
      }
      outv = acc / l;
    } else {
      // all keys masked (-1e9) -> softmax is uniform over all 4096 keys
      float acc = 0.f;
      for (int key = 0; key < KVLEN; key++)
        acc += bf2f(vh[(size_t)key * DMODEL + lane]);
      outv = acc * (1.f / 4096.f);
    }
    attnb[(size_t)(n * 16 + row) * DMODEL + h * 64 + lane] = f2bf(outv);
  }
}

// ---------------- LM head GEMM fused with online logsumexp / target / argmax partials ----------------
__global__ __launch_bounds__(256) void lm_partial(const u16* __restrict__ A,    // (2048, 512)
                                                  const u16* __restrict__ WT,   // (32000, 512)
                                                  const int* __restrict__ input_ids,
                                                  const int* __restrict__ anchors,
                                                  float* __restrict__ pm, float* __restrict__ pl,
                                                  float* __restrict__ pt, float* __restrict__ pbv,
                                                  int* __restrict__ pbi){
  __shared__ __align__(16) u16 As[64][72];
  __shared__ __align__(16) u16 Bs[64][72];
  __shared__ int tcol_s[64];
  int rowbase = blockIdx.x * 64;
  int split = blockIdx.y;
  int t = threadIdx.x, w = t >> 6, lane = t & 63;
  if (t < 64){
    int r = rowbase + t; int n = r >> 4, off = r & 15;
    int lab = anchors[n] + off;
    int safe = min(max(lab, 0), S_LEN - 1);
    tcol_s[t] = input_ids[safe];
  }
  __syncthreads();

  float m_run[4], l_run[4], t_run[4], bv_run[4]; int bi_run[4];
  #pragma unroll
  for (int r = 0; r < 4; r++){
    m_run[r] = -3e38f; l_run[r] = 0.f; t_run[r] = -3e38f; bv_run[r] = -3e38f; bi_run[r] = 0;
  }

  int srow = t >> 2, sc0 = (t & 3) * 8;
  int myrow_l = w * 16 + (lane >> 4) * 4;    // + r

  for (int c = 0; c < NCHUNK; c++){
    int cb = split * (NCHUNK * 64) + c * 64;
    f32x4 acc[4];
    #pragma unroll
    for (int nf = 0; nf < 4; nf++) acc[nf] = (f32x4){0.f, 0.f, 0.f, 0.f};

    for (int kt = 0; kt < 8; kt++){
      __syncthreads();
      *(uv4*)&As[srow][sc0]      = *(const uv4*)&A [(size_t)(rowbase + srow) * DMODEL + kt * 64 + sc0];
      *(uv4*)&As[srow][sc0 + 32] = *(const uv4*)&A [(size_t)(rowbase + srow) * DMODEL + kt * 64 + sc0 + 32];
      *(uv4*)&Bs[srow][sc0]      = *(const uv4*)&WT[(size_t)(cb + srow) * DMODEL + kt * 64 + sc0];
      *(uv4*)&Bs[srow][sc0 + 32] = *(const uv4*)&WT[(size_t)(cb + srow) * DMODEL + kt * 64 + sc0 + 32];
      __syncthreads();
      #pragma unroll
      for (int ks = 0; ks < 2; ks++){
        int ko = ks * 32 + (lane >> 4) * 8;
        short8 af = *(const short8*)&As[w * 16 + (lane & 15)][ko];
        #pragma unroll
        for (int nf = 0; nf < 4; nf++){
          short8 bf = *(const short8*)&Bs[nf * 16 + (lane & 15)][ko];
          acc[nf] = __builtin_amdgcn_mfma_f32_16x16x32_bf16(af, bf, acc[nf], 0, 0, 0);
        }
      }
    }

    // epilogue: online softmax stats per row (16-lane subgroup shares a row)
    #pragma unroll
    for (int r = 0; r < 4; r++){
      float cmax = fmaxf(fmaxf(acc[0][r], acc[1][r]), fmaxf(acc[2][r], acc[3][r]));
      #pragma unroll
      for (int mm = 1; mm < 16; mm <<= 1) cmax = fmaxf(cmax, __shfl_xor(cmax, mm));
      float mn = fmaxf(m_run[r], cmax);
      float se = expf(acc[0][r] - mn) + expf(acc[1][r] - mn) + expf(acc[2][r] - mn) + expf(acc[3][r] - mn);
      #pragma unroll
      for (int mm = 1; mm < 16; mm <<= 1) se += __shfl_xor(se, mm);
      l_run[r] = l_run[r] * expf(m_run[r] - mn) + se;
      m_run[r] = mn;
      // target logit
      int tc = tcol_s[myrow_l + r] - cb;
      if (tc >= 0 && tc < 64){
        int nf = tc >> 4;
        float tv = ((lane & 15) == (tc & 15)) ? acc[nf][r] : -3e38f;
        #pragma unroll
        for (int mm = 1; mm < 16; mm <<= 1) tv = fmaxf(tv, __shfl_xor(tv, mm));
        t_run[r] = fmaxf(t_run[r], tv);
      }
      // argmax (first-max = lowest index on ties)
      float lv = -3e38f; int li = 0;
      #pragma unroll
      for (int nf = 0; nf < 4; nf++){
        float v = acc[nf][r];
        int col = cb + nf * 16 + (lane & 15);
        if (v > lv){ lv = v; li = col; }
      }
      #pragma unroll
      for (int mm = 1; mm < 16; mm <<= 1){
        float ov = __shfl_xor(lv, mm); int oi = __shfl_xor(li, mm);
        if (ov > lv || (ov == lv && oi < li)){ lv = ov; li = oi; }
      }
      if (lv > bv_run[r]){ bv_run[r] = lv; bi_run[r] = li; }
    }
  }

  if ((lane & 15) == 0){
    #pragma unroll
    for (int r = 0; r < 4; r++){
      int rl = myrow_l + r;
      size_t idx = (size_t)(rowbase + rl) * CSPLIT + split;
      pm[idx] = m_run[r]; pl[idx] = l_run[r]; pt[idx] = t_run[r];
      pbv[idx] = bv_run[r]; pbi[idx] = bi_run[r];
    }
  }
}

// ---------------- final reduction: combine partials -> loss, accuracy ----------------
__global__ __launch_bounds__(256) void loss_final(const float* __restrict__ pm, const float* __restrict__ pl,
                                                  const float* __restrict__ pt, const float* __restrict__ pbv,
                                                  const int* __restrict__ pbi,
                                                  const int* __restrict__ input_ids,
                                                  const int* __restrict__ anchors,
                                                  const unsigned char* __restrict__ keep,
                                                  const float* __restrict__ loss_mask,
                                                  float* __restrict__ out){
  int t = threadIdx.x;
  float lsum = 0.f, wsum = 0.f, csum = 0.f;
  for (int r = t; r < QLEN; r += 256){
    float M = -3e38f;
    for (int s = 0; s < CSPLIT; s++) M = fmaxf(M, pm[(size_t)r * CSPLIT + s]);
    float L = 0.f;
    for (int s = 0; s < CSPLIT; s++) L += pl[(size_t)r * CSPLIT + s] * expf(pm[(size_t)r * CSPLIT + s] - M);
    float tv = -3e38f;
    for (int s = 0; s < CSPLIT; s++) tv = fmaxf(tv, pt[(size_t)r * CSPLIT + s]);
    float bv = -3e38f; int bi = 0;
    for (int s = 0; s < CSPLIT; s++){
      float v = pbv[(size_t)r * CSPLIT + s];
      if (v > bv){ bv = v; bi = pbi[(size_t)r * CSPLIT + s]; }
    }
    int n = r >> 4, off = r & 15;
    int lab = anchors[n] + off;
    int valid = (lab < S_LEN) ? 1 : 0;
    int safe = min(max(lab, 0), S_LEN - 1);
    int tgt = input_ids[safe];
    float wgt = (keep[n] ? 1.f : 0.f) * (valid ? 1.f : 0.f) * ((off > 0) ? 1.f : 0.f) * loss_mask[safe];
    float logp = tv - M - logf(L);
    lsum += -logp * wgt;
    wsum += wgt;
    csum += ((bi == tgt) && (wgt > 0.5f)) ? 1.f : 0.f;
  }
  __shared__ float sl[256], sw[256], sc_[256];
  sl[t] = lsum; sw[t] = wsum; sc_[t] = csum;
  __syncthreads();
  for (int s = 128; s >= 1; s >>= 1){
    if (t < s){ sl[t] += sl[t + s]; sw[t] += sw[t + s]; sc_[t] += sc_[t + s]; }
    __syncthreads();
  }
  if (t == 0){
    out[0] = sl[0] / (sw[0] + 1e-6f);
    out[1] = sc_[0] / (sw[0] + 1e-6f);
  }
}

// ---------------- host ----------------
extern "C" void kernel_launch(void* const* d_in, const int* in_sizes, int n_in,
                              void* d_out, int out_size, void* d_ws, size_t ws_size,
                              hipStream_t stream) {
  const int*   input_ids = (const int*)  d_in[0];
  const float* hidden    = (const float*)d_in[1];
  const float* loss_mask = (const float*)d_in[2];
  const int*   anchors   = (const int*)  d_in[3];
  const unsigned char* keep = (const unsigned char*)d_in[4];
  const float* embed     = (const float*)d_in[5];
  const float* Wq        = (const float*)d_in[6];
  const float* Wk        = (const float*)d_in[7];
  const float* Wv        = (const float*)d_in[8];
  const float* Wo        = (const float*)d_in[9];
  const float* Wlm       = (const float*)d_in[10];

  char* ws = (char*)d_ws;
  size_t off = 0;
  auto take = [&](size_t bytes) -> char* {
    char* p = ws + off;
    off += (bytes + 255) & ~(size_t)255;
    return p;
  };
  u16* WqT  = (u16*)take((size_t)512 * 512 * 2);
  u16* WkT  = (u16*)take((size_t)512 * 512 * 2);
  u16* WvT  = (u16*)take((size_t)512 * 512 * 2);
  u16* WoT  = (u16*)take((size_t)512 * 512 * 2);
  u16* WlmT = (u16*)take((size_t)VOCAB * 512 * 2);
  u16* kvb  = (u16*)take((size_t)KVLEN * 512 * 2);
  u16* qb2  = (u16*)take((size_t)QLEN * 512 * 2);
  u16* kTb  = (u16*)take((size_t)512 * KVLEN * 2);
  u16* vb   = (u16*)take((size_t)KVLEN * 512 * 2);
  u16* attnb= (u16*)take((size_t)QLEN * 512 * 2);
  u16* ob   = (u16*)take((size_t)QLEN * 512 * 2);
  float* pm = (float*)take((size_t)QLEN * CSPLIT * 4);
  float* pl = (float*)take((size_t)QLEN * CSPLIT * 4);
  float* pt = (float*)take((size_t)QLEN * CSPLIT * 4);
  float* pbv= (float*)take((size_t)QLEN * CSPLIT * 4);
  int*   pbi= (int*)  take((size_t)QLEN * CSPLIT * 4);

  transpose_cast<<<dim3(16, 16),   256, 0, stream>>>(Wq,  WqT,  512, 512);
  transpose_cast<<<dim3(16, 16),   256, 0, stream>>>(Wk,  WkT,  512, 512);
  transpose_cast<<<dim3(16, 16),   256, 0, stream>>>(Wv,  WvT,  512, 512);
  transpose_cast<<<dim3(16, 16),   256, 0, stream>>>(Wo,  WoT,  512, 512);
  transpose_cast<<<dim3(1000, 16), 256, 0, stream>>>(Wlm, WlmT, 512, VOCAB);

  build_kv<<<KVLEN, 128, 0, stream>>>(hidden, embed, input_ids, anchors, keep, kvb);

  gemm64<1><<<dim3(64, 8), 256, 0, stream>>>(kvb, WkT, kTb, KVLEN, 512, 512, KVLEN); // k^T (512,4096)
  gemm64<0><<<dim3(64, 8), 256, 0, stream>>>(kvb, WvT, vb,  KVLEN, 512, 512, 512);   // v  (4096,512)
  gemm64<0><<<dim3(32, 8), 256, 0, stream>>>(kvb + (size_t)S_LEN * 512, WqT, qb2, QLEN, 512, 512, 512); // q

  attn_kernel<<<dim3(NBLK, 8), 256, 0, stream>>>(qb2, kTb, vb, anchors, keep, attnb);

  gemm64<0><<<dim3(32, 8), 256, 0, stream>>>(attnb, WoT, ob, QLEN, 512, 512, 512);   // o = attn @ Wo

  lm_partial<<<dim3(32, CSPLIT), 256, 0, stream>>>(ob, WlmT, input_ids, anchors, pm, pl, pt, pbv, pbi);

  loss_final<<<1, 256, 0, stream>>>(pm, pl, pt, pbv, pbi, input_ids, anchors, keep, loss_mask, (float*)d_out);
}

// Round 2
// 421.545 us; speedup vs baseline: 6.8975x; 6.8975x over previous
//
#include <hip/hip_runtime.h>

typedef unsigned short u16;
typedef __attribute__((ext_vector_type(4))) float f32x4;
typedef __attribute__((ext_vector_type(8))) short short8;
typedef __attribute__((ext_vector_type(4))) unsigned int uv4;
typedef __attribute__((ext_vector_type(4))) float fv4;
typedef __attribute__((ext_vector_type(4))) unsigned short usv4;

#define S_LEN 2048
#define NBLK 128
#define DMODEL 512
#define VOCAB 32000
#define QLEN 2048
#define KVLEN 4096
#define CSPLIT 20
#define NCHUNK 25   // 25 chunks of 64 cols = 1600 cols per split; 20*1600 = 32000

__device__ __forceinline__ float bf2f(u16 u){
  union { unsigned int i; float f; } x; x.i = ((unsigned int)u) << 16; return x.f;
}
__device__ __forceinline__ u16 f2bf(float f){
  union { float f; unsigned int i; } x; x.f = f;
  unsigned int r = x.i + 0x7fffu + ((x.i >> 16) & 1u);
  return (u16)(r >> 16);
}

// ---------------- transpose + cast f32(K,N) -> bf16(N,K) ----------------
__global__ __launch_bounds__(256) void transpose_cast(const float* __restrict__ in,
                                                      u16* __restrict__ out,
                                                      int K, int N){
  __shared__ float tile[32][33];
  int t = threadIdx.x, tx = t & 31, ty = t >> 5;
  int nb = blockIdx.x * 32, kb = blockIdx.y * 32;
  #pragma unroll
  for (int i = 0; i < 4; i++){
    int r = ty + i * 8;
    tile[r][tx] = in[(size_t)(kb + r) * N + nb + tx];
  }
  __syncthreads();
  #pragma unroll
  for (int i = 0; i < 4; i++){
    int r = ty + i * 8;
    out[(size_t)(nb + r) * K + kb + tx] = f2bf(tile[tx][r]);
  }
}

// ---------------- build kv_in (bf16 4096x512): [hidden ; noise_embedding] ----------------
__global__ __launch_bounds__(128) void build_kv(const float* __restrict__ hidden,
                                                const float* __restrict__ embed,
                                                const int* __restrict__ input_ids,
                                                const int* __restrict__ anchors,
                                                const unsigned char* __restrict__ keep,
                                                u16* __restrict__ kvb){
  int row = blockIdx.x;           // 0..4095
  int t = threadIdx.x;            // 0..127
  const float* src;
  if (row < S_LEN){
    src = hidden + (size_t)row * DMODEL;
  } else {
    int q = row - S_LEN;
    int id = 3;                   // MASK_TOKEN_ID
    if ((q & 15) == 0){
      int n = q >> 4;
      if (keep[n]){
        int a = anchors[n]; a = min(max(a, 0), S_LEN - 1);
        id = input_ids[a];
      }
    }
    src = embed + (size_t)id * DMODEL;
  }
  int c = t * 4;
  fv4 v = *(const fv4*)&src[c];
  usv4 o; o[0] = f2bf(v[0]); o[1] = f2bf(v[1]); o[2] = f2bf(v[2]); o[3] = f2bf(v[3]);
  *(usv4*)&kvb[(size_t)row * DMODEL + c] = o;
}

// ---------------- generic 64x64 tile bf16 GEMM: C[M,N] = A[M,K] * B[K,N], B given transposed (N,K) ----------------
template<int TRANS>
__global__ __launch_bounds__(256) void gemm64(const u16* __restrict__ A,
                                              const u16* __restrict__ BT,
                                              u16* __restrict__ C,
                                              int M, int N, int K, int ldc){
  __shared__ __align__(16) u16 As[64][72];
  __shared__ __align__(16) u16 Bs[64][72];
  int t = threadIdx.x, w = t >> 6, lane = t & 63;
  int wm = w >> 1, wn = w & 1;
  int rowbase = blockIdx.x * 64, colbase = blockIdx.y * 64;
  f32x4 acc[2][2];
  #pragma unroll
  for (int i = 0; i < 2; i++)
    #pragma unroll
    for (int j = 0; j < 2; j++)
      acc[i][j] = (f32x4){0.f, 0.f, 0.f, 0.f};

  int srow = t >> 2, sc0 = (t & 3) * 8;
  for (int kb = 0; kb < K; kb += 64){
    __syncthreads();
    *(uv4*)&As[srow][sc0]      = *(const uv4*)&A [(size_t)(rowbase + srow) * K + kb + sc0];
    *(uv4*)&As[srow][sc0 + 32] = *(const uv4*)&A [(size_t)(rowbase + srow) * K + kb + sc0 + 32];
    *(uv4*)&Bs[srow][sc0]      = *(const uv4*)&BT[(size_t)(colbase + srow) * K + kb + sc0];
    *(uv4*)&Bs[srow][sc0 + 32] = *(const uv4*)&BT[(size_t)(colbase + srow) * K + kb + sc0 + 32];
    __syncthreads();
    #pragma unroll
    for (int ks = 0; ks < 2; ks++){
      int ko = ks * 32 + (lane >> 4) * 8;
      short8 a0 = *(const short8*)&As[wm * 32 +      (lane & 15)][ko];
      short8 a1 = *(const short8*)&As[wm * 32 + 16 + (lane & 15)][ko];
      short8 b0 = *(const short8*)&Bs[wn * 32 +      (lane & 15)][ko];
      short8 b1 = *(const short8*)&Bs[wn * 32 + 16 + (lane & 15)][ko];
      acc[0][0] = __builtin_amdgcn_mfma_f32_16x16x32_bf16(a0, b0, acc[0][0], 0, 0, 0);
      acc[0][1] = __builtin_amdgcn_mfma_f32_16x16x32_bf16(a0, b1, acc[0][1], 0, 0, 0);
      acc[1][0] = __builtin_amdgcn_mfma_f32_16x16x32_bf16(a1, b0, acc[1][0], 0, 0, 0);
      acc[1][1] = __builtin_amdgcn_mfma_f32_16x16x32_bf16(a1, b1, acc[1][1], 0, 0, 0);
    }
  }
  #pragma unroll
  for (int mf = 0; mf < 2; mf++)
    #pragma unroll
    for (int nf = 0; nf < 2; nf++)
      #pragma unroll
      for (int r = 0; r < 4; r++){
        int row = rowbase + wm * 32 + mf * 16 + (lane >> 4) * 4 + r;
        int col = colbase + wn * 32 + nf * 16 + (lane & 15);
        u16 vv = f2bf(acc[mf][nf][r]);
        if (TRANS) C[(size_t)col * ldc + row] = vv;
        else       C[(size_t)row * ldc + col] = vv;
      }
}

// ---------------- MFMA flash attention: one (draft block n, head h) per workgroup ----------------
// qb: (2048,512) bf16; kb: (4096,512) bf16; vT: (512,4096) bf16
// 4 waves split the key-chunk range (flash-decode); merge m/l/O via LDS.
__global__ __launch_bounds__(256) void attn_mfma(const u16* __restrict__ qb,
                                                 const u16* __restrict__ kb,
                                                 const u16* __restrict__ vT,
                                                 const int* __restrict__ anchors,
                                                 const unsigned char* __restrict__ keep,
                                                 u16* __restrict__ attnb){
  int n = blockIdx.x, h = blockIdx.y;
  int t = threadIdx.x, w = t >> 6, lane = t & 63;
  int g = lane >> 4, li = lane & 15;

  __shared__ __align__(16) u16 q_s[16][72];
  __shared__ __align__(16) u16 p_s[4][16][72];
  __shared__ float o_s[4][16][64];
  __shared__ float ml_s[4][2][16];

  // stage Q tile (16 x 64)
  {
    int r = t >> 4, c4 = (t & 15) * 4;
    *(usv4*)&q_s[r][c4] = *(const usv4*)&qb[(size_t)(n * 16 + r) * DMODEL + h * 64 + c4];
  }
  __syncthreads();

  int anchor = anchors[n];
  bool kp = keep[n] != 0;
  const u16* kh  = kb + h * 64;
  const u16* vTh = vT + (size_t)(h * 64) * KVLEN;

  if (!kp){
    // all keys masked -> softmax uniform over all 4096 keys -> mean of V rows
    if (w == 0){
      float acc = 0.f;
      const u16* row = vTh + (size_t)lane * KVLEN;
      for (int k2 = 0; k2 < KVLEN; k2 += 8){
        short8 vv = *(const short8*)&row[k2];
        #pragma unroll
        for (int j = 0; j < 8; j++) acc += bf2f((u16)vv[j]);
      }
      acc *= (1.f / 4096.f);
      u16 ov = f2bf(acc);
      for (int r = 0; r < 16; r++)
        attnb[(size_t)(n * 16 + r) * DMODEL + h * 64 + lane] = ov;
    }
    return;
  }

  // Q A-fragments (row = li, k = ks*32 + g*8)
  short8 qa[2];
  #pragma unroll
  for (int ks = 0; ks < 2; ks++)
    qa[ks] = *(const short8*)&q_s[li][ks * 32 + g * 8];

  int nctx = (anchor + 63) >> 6;
  int ntot = nctx + 1;             // + draft chunk (16 keys of own block)

  f32x4 o_acc[4];
  float m[4], l[4];
  #pragma unroll
  for (int i = 0; i < 4; i++){ o_acc[i] = (f32x4){0.f,0.f,0.f,0.f}; m[i] = -3e38f; l[i] = 0.f; }

  for (int c = w; c < ntot; c += 4){
    bool draft = (c == nctx);
    int kbase = draft ? (S_LEN + n * 16) : c * 64;
    int nk    = draft ? 16 : min(64, anchor - c * 64);

    // ---- S = Q K^T (16 x 64 keys), K-dim = d = 64 ----
    f32x4 s[4];
    #pragma unroll
    for (int nf = 0; nf < 4; nf++) s[nf] = (f32x4){0.f,0.f,0.f,0.f};
    #pragma unroll
    for (int ks = 0; ks < 2; ks++){
      #pragma unroll
      for (int nf = 0; nf < 4; nf++){
        int krow = min(kbase + nf * 16 + li, KVLEN - 1);
        short8 bfrag = *(const short8*)&kh[(size_t)krow * DMODEL + ks * 32 + g * 8];
        s[nf] = __builtin_amdgcn_mfma_f32_16x16x32_bf16(qa[ks], bfrag, s[nf], 0, 0, 0);
      }
    }

    // ---- online softmax (row = g*4+r, col = nf*16+li) ----
    #pragma unroll
    for (int r = 0; r < 4; r++){
      float mx = -3e38f;
      #pragma unroll
      for (int nf = 0; nf < 4; nf++){
        float sv = s[nf][r] * 0.125f;
        if (nf * 16 + li >= nk) sv = -3e38f;
        s[nf][r] = sv;
        mx = fmaxf(mx, sv);
      }
      #pragma unroll
      for (int mm = 1; mm < 16; mm <<= 1) mx = fmaxf(mx, __shfl_xor(mx, mm));
      float mn = fmaxf(m[r], mx);
      float sc = expf(m[r] - mn);
      float ps = 0.f;
      #pragma unroll
      for (int nf = 0; nf < 4; nf++){
        float p = expf(s[nf][r] - mn);
        ps += p;
        p_s[w][g * 4 + r][nf * 16 + li] = f2bf(p);
      }
      #pragma unroll
      for (int mm = 1; mm < 16; mm <<= 1) ps += __shfl_xor(ps, mm);
      l[r] = l[r] * sc + ps;
      m[r] = mn;
      #pragma unroll
      for (int nfd = 0; nfd < 4; nfd++) o_acc[nfd][r] *= sc;
    }

    // ---- O += P V  (K-dim = keys; P from LDS as A-fragments; V^T fragments from global) ----
    #pragma unroll
    for (int ks = 0; ks < 2; ks++){
      short8 pa = *(const short8*)&p_s[w][li][ks * 32 + g * 8];
      int kcol = min(kbase + ks * 32 + g * 8, KVLEN - 8);
      #pragma unroll
      for (int nfd = 0; nfd < 4; nfd++){
        short8 vfrag = *(const short8*)&vTh[(size_t)(nfd * 16 + li) * KVLEN + kcol];
        o_acc[nfd] = __builtin_amdgcn_mfma_f32_16x16x32_bf16(pa, vfrag, o_acc[nfd], 0, 0, 0);
      }
    }
  }

  // ---- write per-wave partials, merge across waves ----
  #pragma unroll
  for (int r = 0; r < 4; r++){
    if (li == 0){ ml_s[w][0][g * 4 + r] = m[r]; ml_s[w][1][g * 4 + r] = l[r]; }
    #pragma unroll
    for (int nfd = 0; nfd < 4; nfd++)
      o_s[w][g * 4 + r][nfd * 16 + li] = o_acc[nfd][r];
  }
  __syncthreads();

  {
    int row = t >> 4, c0 = (t & 15) * 4;
    float M = -3e38f;
    #pragma unroll
    for (int ww = 0; ww < 4; ww++) M = fmaxf(M, ml_s[ww][0][row]);
    float L = 0.f, ew[4];
    #pragma unroll
    for (int ww = 0; ww < 4; ww++){
      ew[ww] = expf(ml_s[ww][0][row] - M);
      L += ml_s[ww][1][row] * ew[ww];
    }
    float inv = 1.f / L;
    #pragma unroll
    for (int j = 0; j < 4; j++){
      float ov = 0.f;
      #pragma unroll
      for (int ww = 0; ww < 4; ww++) ov += o_s[ww][row][c0 + j] * ew[ww];
      attnb[(size_t)(n * 16 + row) * DMODEL + h * 64 + c0 + j] = f2bf(ov * inv);
    }
  }
}

// ---------------- LM head GEMM fused with online logsumexp / target / argmax partials ----------------
__global__ __launch_bounds__(256) void lm_partial(const u16* __restrict__ A,    // (2048, 512)
                                                  const u16* __restrict__ WT,   // (32000, 512)
                                                  const int* __restrict__ input_ids,
                                                  const int* __restrict__ anchors,
                                                  float* __restrict__ pm, float* __restrict__ pl,
                                                  float* __restrict__ pt, float* __restrict__ pbv,
                                                  int* __restrict__ pbi){
  __shared__ __align__(16) u16 As[64][72];
  __shared__ __align__(16) u16 Bs[64][72];
  __shared__ int tcol_s[64];
  int rowbase = blockIdx.x * 64;
  int split = blockIdx.y;
  int t = threadIdx.x, w = t >> 6, lane = t & 63;
  if (t < 64){
    int r = rowbase + t; int n = r >> 4, off = r & 15;
    int lab = anchors[n] + off;
    int safe = min(max(lab, 0), S_LEN - 1);
    tcol_s[t] = input_ids[safe];
  }
  __syncthreads();

  float m_run[4], l_run[4], t_run[4], bv_run[4]; int bi_run[4];
  #pragma unroll
  for (int r = 0; r < 4; r++){
    m_run[r] = -3e38f; l_run[r] = 0.f; t_run[r] = -3e38f; bv_run[r] = -3e38f; bi_run[r] = 0;
  }

  int srow = t >> 2, sc0 = (t & 3) * 8;
  int myrow_l = w * 16 + (lane >> 4) * 4;    // + r

  for (int c = 0; c < NCHUNK; c++){
    int cb = split * (NCHUNK * 64) + c * 64;
    f32x4 acc[4];
    #pragma unroll
    for (int nf = 0; nf < 4; nf++) acc[nf] = (f32x4){0.f, 0.f, 0.f, 0.f};

    for (int kt = 0; kt < 8; kt++){
      __syncthreads();
      *(uv4*)&As[srow][sc0]      = *(const uv4*)&A [(size_t)(rowbase + srow) * DMODEL + kt * 64 + sc0];
      *(uv4*)&As[srow][sc0 + 32] = *(const uv4*)&A [(size_t)(rowbase + srow) * DMODEL + kt * 64 + sc0 + 32];
      *(uv4*)&Bs[srow][sc0]      = *(const uv4*)&WT[(size_t)(cb + srow) * DMODEL + kt * 64 + sc0];
      *(uv4*)&Bs[srow][sc0 + 32] = *(const uv4*)&WT[(size_t)(cb + srow) * DMODEL + kt * 64 + sc0 + 32];
      __syncthreads();
      #pragma unroll
      for (int ks = 0; ks < 2; ks++){
        int ko = ks * 32 + (lane >> 4) * 8;
        short8 af = *(const short8*)&As[w * 16 + (lane & 15)][ko];
        #pragma unroll
        for (int nf = 0; nf < 4; nf++){
          short8 bf = *(const short8*)&Bs[nf * 16 + (lane & 15)][ko];
          acc[nf] = __builtin_amdgcn_mfma_f32_16x16x32_bf16(af, bf, acc[nf], 0, 0, 0);
        }
      }
    }

    // epilogue: online softmax stats per row (16-lane subgroup shares a row)
    #pragma unroll
    for (int r = 0; r < 4; r++){
      float cmax = fmaxf(fmaxf(acc[0][r], acc[1][r]), fmaxf(acc[2][r], acc[3][r]));
      #pragma unroll
      for (int mm = 1; mm < 16; mm <<= 1) cmax = fmaxf(cmax, __shfl_xor(cmax, mm));
      float mn = fmaxf(m_run[r], cmax);
      float se = expf(acc[0][r] - mn) + expf(acc[1][r] - mn) + expf(acc[2][r] - mn) + expf(acc[3][r] - mn);
      #pragma unroll
      for (int mm = 1; mm < 16; mm <<= 1) se += __shfl_xor(se, mm);
      l_run[r] = l_run[r] * expf(m_run[r] - mn) + se;
      m_run[r] = mn;
      // target logit
      int tc = tcol_s[myrow_l + r] - cb;
      if (tc >= 0 && tc < 64){
        int nf = tc >> 4;
        float tv = ((lane & 15) == (tc & 15)) ? acc[nf][r] : -3e38f;
        #pragma unroll
        for (int mm = 1; mm < 16; mm <<= 1) tv = fmaxf(tv, __shfl_xor(tv, mm));
        t_run[r] = fmaxf(t_run[r], tv);
      }
      // argmax (first-max = lowest index on ties)
      float lv = -3e38f; int li = 0;
      #pragma unroll
      for (int nf = 0; nf < 4; nf++){
        float v = acc[nf][r];
        int col = cb + nf * 16 + (lane & 15);
        if (v > lv){ lv = v; li = col; }
      }
      #pragma unroll
      for (int mm = 1; mm < 16; mm <<= 1){
        float ov = __shfl_xor(lv, mm); int oi = __shfl_xor(li, mm);
        if (ov > lv || (ov == lv && oi < li)){ lv = ov; li = oi; }
      }
      if (lv > bv_run[r]){ bv_run[r] = lv; bi_run[r] = li; }
    }
  }

  if ((lane & 15) == 0){
    #pragma unroll
    for (int r = 0; r < 4; r++){
      int rl = myrow_l + r;
      size_t idx = (size_t)(rowbase + rl) * CSPLIT + split;
      pm[idx] = m_run[r]; pl[idx] = l_run[r]; pt[idx] = t_run[r];
      pbv[idx] = bv_run[r]; pbi[idx] = bi_run[r];
    }
  }
}

// ---------------- final reduction: combine partials -> loss, accuracy ----------------
__global__ __launch_bounds__(256) void loss_final(const float* __restrict__ pm, const float* __restrict__ pl,
                                                  const float* __restrict__ pt, const float* __restrict__ pbv,
                                                  const int* __restrict__ pbi,
                                                  const int* __restrict__ input_ids,
                                                  const int* __restrict__ anchors,
                                                  const unsigned char* __restrict__ keep,
                                                  const float* __restrict__ loss_mask,
                                                  float* __restrict__ out){
  int t = threadIdx.x;
  float lsum = 0.f, wsum = 0.f, csum = 0.f;
  for (int r = t; r < QLEN; r += 256){
    float M = -3e38f;
    for (int s = 0; s < CSPLIT; s++) M = fmaxf(M, pm[(size_t)r * CSPLIT + s]);
    float L = 0.f;
    for (int s = 0; s < CSPLIT; s++) L += pl[(size_t)r * CSPLIT + s] * expf(pm[(size_t)r * CSPLIT + s] - M);
    float tv = -3e38f;
    for (int s = 0; s < CSPLIT; s++) tv = fmaxf(tv, pt[(size_t)r * CSPLIT + s]);
    float bv = -3e38f; int bi = 0;
    for (int s = 0; s < CSPLIT; s++){
      float v = pbv[(size_t)r * CSPLIT + s];
      if (v > bv){ bv = v; bi = pbi[(size_t)r * CSPLIT + s]; }
    }
    int n = r >> 4, off = r & 15;
    int lab = anchors[n] + off;
    int valid = (lab < S_LEN) ? 1 : 0;
    int safe = min(max(lab, 0), S_LEN - 1);
    int tgt = input_ids[safe];
    float wgt = (keep[n] ? 1.f : 0.f) * (valid ? 1.f : 0.f) * ((off > 0) ? 1.f : 0.f) * loss_mask[safe];
    float logp = tv - M - logf(L);
    lsum += -logp * wgt;
    wsum += wgt;
    csum += ((bi == tgt) && (wgt > 0.5f)) ? 1.f : 0.f;
  }
  __shared__ float sl[256], sw[256], sc_[256];
  sl[t] = lsum; sw[t] = wsum; sc_[t] = csum;
  __syncthreads();
  for (int s = 128; s >= 1; s >>= 1){
    if (t < s){ sl[t] += sl[t + s]; sw[t] += sw[t + s]; sc_[t] += sc_[t + s]; }
    __syncthreads();
  }
  if (t == 0){
    out[0] = sl[0] / (sw[0] + 1e-6f);
    out[1] = sc_[0] / (sw[0] + 1e-6f);
  }
}

// ---------------- host ----------------
extern "C" void kernel_launch(void* const* d_in, const int* in_sizes, int n_in,
                              void* d_out, int out_size, void* d_ws, size_t ws_size,
                              hipStream_t stream) {
  const int*   input_ids = (const int*)  d_in[0];
  const float* hidden    = (const float*)d_in[1];
  const float* loss_mask = (const float*)d_in[2];
  const int*   anchors   = (const int*)  d_in[3];
  const unsigned char* keep = (const unsigned char*)d_in[4];
  const float* embed     = (const float*)d_in[5];
  const float* Wq        = (const float*)d_in[6];
  const float* Wk        = (const float*)d_in[7];
  const float* Wv        = (const float*)d_in[8];
  const float* Wo        = (const float*)d_in[9];
  const float* Wlm       = (const float*)d_in[10];

  char* ws = (char*)d_ws;
  size_t off = 0;
  auto take = [&](size_t bytes) -> char* {
    char* p = ws + off;
    off += (bytes + 255) & ~(size_t)255;
    return p;
  };
  u16* WqT  = (u16*)take((size_t)512 * 512 * 2);
  u16* WkT  = (u16*)take((size_t)512 * 512 * 2);
  u16* WvT  = (u16*)take((size_t)512 * 512 * 2);
  u16* WoT  = (u16*)take((size_t)512 * 512 * 2);
  u16* WlmT = (u16*)take((size_t)VOCAB * 512 * 2);
  u16* kvb  = (u16*)take((size_t)KVLEN * 512 * 2);
  u16* qb2  = (u16*)take((size_t)QLEN * 512 * 2);
  u16* kb   = (u16*)take((size_t)KVLEN * 512 * 2);
  u16* vTb  = (u16*)take((size_t)512 * KVLEN * 2);
  u16* attnb= (u16*)take((size_t)QLEN * 512 * 2);
  u16* ob   = (u16*)take((size_t)QLEN * 512 * 2);
  float* pm = (float*)take((size_t)QLEN * CSPLIT * 4);
  float* pl = (float*)take((size_t)QLEN * CSPLIT * 4);
  float* pt = (float*)take((size_t)QLEN * CSPLIT * 4);
  float* pbv= (float*)take((size_t)QLEN * CSPLIT * 4);
  int*   pbi= (int*)  take((size_t)QLEN * CSPLIT * 4);

  transpose_cast<<<dim3(16, 16),   256, 0, stream>>>(Wq,  WqT,  512, 512);
  transpose_cast<<<dim3(16, 16),   256, 0, stream>>>(Wk,  WkT,  512, 512);
  transpose_cast<<<dim3(16, 16),   256, 0, stream>>>(Wv,  WvT,  512, 512);
  transpose_cast<<<dim3(16, 16),   256, 0, stream>>>(Wo,  WoT,  512, 512);
  transpose_cast<<<dim3(1000, 16), 256, 0, stream>>>(Wlm, WlmT, 512, VOCAB);

  build_kv<<<KVLEN, 128, 0, stream>>>(hidden, embed, input_ids, anchors, keep, kvb);

  gemm64<0><<<dim3(64, 8), 256, 0, stream>>>(kvb, WkT, kb,  KVLEN, 512, 512, 512);   // k (4096,512)
  gemm64<1><<<dim3(64, 8), 256, 0, stream>>>(kvb, WvT, vTb, KVLEN, 512, 512, KVLEN); // v^T (512,4096)
  gemm64<0><<<dim3(32, 8), 256, 0, stream>>>(kvb + (size_t)S_LEN * 512, WqT, qb2, QLEN, 512, 512, 512); // q

  attn_mfma<<<dim3(NBLK, 8), 256, 0, stream>>>(qb2, kb, vTb, anchors, keep, attnb);

  gemm64<0><<<dim3(32, 8), 256, 0, stream>>>(attnb, WoT, ob, QLEN, 512, 512, 512);   // o = attn @ Wo

  lm_partial<<<dim3(32, CSPLIT), 256, 0, stream>>>(ob, WlmT, input_ids, anchors, pm, pl, pt, pbv, pbi);

  loss_final<<<1, 256, 0, stream>>>(pm, pl, pt, pbv, pbi, input_ids, anchors, keep, loss_mask, (float*)d_out);
}

// Round 3
// 380.052 us; speedup vs baseline: 7.6505x; 1.1092x over previous
//
#include <hip/hip_runtime.h>

typedef unsigned short u16;
typedef __attribute__((ext_vector_type(4))) float f32x4;
typedef __attribute__((ext_vector_type(8))) short short8;
typedef __attribute__((ext_vector_type(4))) unsigned int uv4;
typedef __attribute__((ext_vector_type(4))) float fv4;
typedef __attribute__((ext_vector_type(4))) unsigned short usv4;

#define S_LEN 2048
#define NBLK 128
#define DMODEL 512
#define VOCAB 32000
#define QLEN 2048
#define KVLEN 4096
#define NSPLIT 500   // 32000 cols / 64-col half-tiles

#define GAS(p) ((const __attribute__((address_space(1))) void*)(const void*)(p))
#define LAS(p) ((__attribute__((address_space(3))) void*)(void*)(p))

__device__ __forceinline__ float bf2f(u16 u){
  union { unsigned int i; float f; } x; x.i = ((unsigned int)u) << 16; return x.f;
}
__device__ __forceinline__ u16 f2bf(float f){
  union { float f; unsigned int i; } x; x.f = f;
  unsigned int r = x.i + 0x7fffu + ((x.i >> 16) & 1u);
  return (u16)(r >> 16);
}

// ---------------- transpose + cast f32(K,N) -> bf16(N,K) ----------------
__global__ __launch_bounds__(256) void transpose_cast(const float* __restrict__ in,
                                                      u16* __restrict__ out,
                                                      int K, int N){
  __shared__ float tile[32][33];
  int t = threadIdx.x, tx = t & 31, ty = t >> 5;
  int nb = blockIdx.x * 32, kb = blockIdx.y * 32;
  #pragma unroll
  for (int i = 0; i < 4; i++){
    int r = ty + i * 8;
    tile[r][tx] = in[(size_t)(kb + r) * N + nb + tx];
  }
  __syncthreads();
  #pragma unroll
  for (int i = 0; i < 4; i++){
    int r = ty + i * 8;
    out[(size_t)(nb + r) * K + kb + tx] = f2bf(tile[tx][r]);
  }
}

// ---------------- build kv_in (bf16 4096x512): [hidden ; noise_embedding] ----------------
__global__ __launch_bounds__(128) void build_kv(const float* __restrict__ hidden,
                                                const float* __restrict__ embed,
                                                const int* __restrict__ input_ids,
                                                const int* __restrict__ anchors,
                                                const unsigned char* __restrict__ keep,
                                                u16* __restrict__ kvb){
  int row = blockIdx.x;           // 0..4095
  int t = threadIdx.x;            // 0..127
  const float* src;
  if (row < S_LEN){
    src = hidden + (size_t)row * DMODEL;
  } else {
    int q = row - S_LEN;
    int id = 3;                   // MASK_TOKEN_ID
    if ((q & 15) == 0){
      int n = q >> 4;
      if (keep[n]){
        int a = anchors[n]; a = min(max(a, 0), S_LEN - 1);
        id = input_ids[a];
      }
    }
    src = embed + (size_t)id * DMODEL;
  }
  int c = t * 4;
  fv4 v = *(const fv4*)&src[c];
  usv4 o; o[0] = f2bf(v[0]); o[1] = f2bf(v[1]); o[2] = f2bf(v[2]); o[3] = f2bf(v[3]);
  *(usv4*)&kvb[(size_t)row * DMODEL + c] = o;
}

// ---------------- generic 64x64 tile bf16 GEMM: C[M,N] = A[M,K] * B[K,N], B given transposed (N,K) ----------------
template<int TRANS>
__global__ __launch_bounds__(256) void gemm64(const u16* __restrict__ A,
                                              const u16* __restrict__ BT,
                                              u16* __restrict__ C,
                                              int M, int N, int K, int ldc){
  __shared__ __align__(16) u16 As[64][72];
  __shared__ __align__(16) u16 Bs[64][72];
  int t = threadIdx.x, w = t >> 6, lane = t & 63;
  int wm = w >> 1, wn = w & 1;
  int rowbase = blockIdx.x * 64, colbase = blockIdx.y * 64;
  f32x4 acc[2][2];
  #pragma unroll
  for (int i = 0; i < 2; i++)
    #pragma unroll
    for (int j = 0; j < 2; j++)
      acc[i][j] = (f32x4){0.f, 0.f, 0.f, 0.f};

  int srow = t >> 2, sc0 = (t & 3) * 8;
  for (int kb = 0; kb < K; kb += 64){
    __syncthreads();
    *(uv4*)&As[srow][sc0]      = *(const uv4*)&A [(size_t)(rowbase + srow) * K + kb + sc0];
    *(uv4*)&As[srow][sc0 + 32] = *(const uv4*)&A [(size_t)(rowbase + srow) * K + kb + sc0 + 32];
    *(uv4*)&Bs[srow][sc0]      = *(const uv4*)&BT[(size_t)(colbase + srow) * K + kb + sc0];
    *(uv4*)&Bs[srow][sc0 + 32] = *(const uv4*)&BT[(size_t)(colbase + srow) * K + kb + sc0 + 32];
    __syncthreads();
    #pragma unroll
    for (int ks = 0; ks < 2; ks++){
      int ko = ks * 32 + (lane >> 4) * 8;
      short8 a0 = *(const short8*)&As[wm * 32 +      (lane & 15)][ko];
      short8 a1 = *(const short8*)&As[wm * 32 + 16 + (lane & 15)][ko];
      short8 b0 = *(const short8*)&Bs[wn * 32 +      (lane & 15)][ko];
      short8 b1 = *(const short8*)&Bs[wn * 32 + 16 + (lane & 15)][ko];
      acc[0][0] = __builtin_amdgcn_mfma_f32_16x16x32_bf16(a0, b0, acc[0][0], 0, 0, 0);
      acc[0][1] = __builtin_amdgcn_mfma_f32_16x16x32_bf16(a0, b1, acc[0][1], 0, 0, 0);
      acc[1][0] = __builtin_amdgcn_mfma_f32_16x16x32_bf16(a1, b0, acc[1][0], 0, 0, 0);
      acc[1][1] = __builtin_amdgcn_mfma_f32_16x16x32_bf16(a1, b1, acc[1][1], 0, 0, 0);
    }
  }
  #pragma unroll
  for (int mf = 0; mf < 2; mf++)
    #pragma unroll
    for (int nf = 0; nf < 2; nf++)
      #pragma unroll
      for (int r = 0; r < 4; r++){
        int row = rowbase + wm * 32 + mf * 16 + (lane >> 4) * 4 + r;
        int col = colbase + wn * 32 + nf * 16 + (lane & 15);
        u16 vv = f2bf(acc[mf][nf][r]);
        if (TRANS) C[(size_t)col * ldc + row] = vv;
        else       C[(size_t)row * ldc + col] = vv;
      }
}

// ---------------- MFMA flash attention: one (draft block n, head h) per workgroup ----------------
__global__ __launch_bounds__(256) void attn_mfma(const u16* __restrict__ qb,
                                                 const u16* __restrict__ kb,
                                                 const u16* __restrict__ vT,
                                                 const int* __restrict__ anchors,
                                                 const unsigned char* __restrict__ keep,
                                                 u16* __restrict__ attnb){
  int n = blockIdx.x, h = blockIdx.y;
  int t = threadIdx.x, w = t >> 6, lane = t & 63;
  int g = lane >> 4, li = lane & 15;

  __shared__ __align__(16) u16 q_s[16][72];
  __shared__ __align__(16) u16 p_s[4][16][72];
  __shared__ float o_s[4][16][64];
  __shared__ float ml_s[4][2][16];

  // stage Q tile (16 x 64)
  {
    int r = t >> 4, c4 = (t & 15) * 4;
    *(usv4*)&q_s[r][c4] = *(const usv4*)&qb[(size_t)(n * 16 + r) * DMODEL + h * 64 + c4];
  }
  __syncthreads();

  int anchor = anchors[n];
  bool kp = keep[n] != 0;
  const u16* kh  = kb + h * 64;
  const u16* vTh = vT + (size_t)(h * 64) * KVLEN;

  if (!kp){
    if (w == 0){
      float acc = 0.f;
      const u16* row = vTh + (size_t)lane * KVLEN;
      for (int k2 = 0; k2 < KVLEN; k2 += 8){
        short8 vv = *(const short8*)&row[k2];
        #pragma unroll
        for (int j = 0; j < 8; j++) acc += bf2f((u16)vv[j]);
      }
      acc *= (1.f / 4096.f);
      u16 ov = f2bf(acc);
      for (int r = 0; r < 16; r++)
        attnb[(size_t)(n * 16 + r) * DMODEL + h * 64 + lane] = ov;
    }
    return;
  }

  short8 qa[2];
  #pragma unroll
  for (int ks = 0; ks < 2; ks++)
    qa[ks] = *(const short8*)&q_s[li][ks * 32 + g * 8];

  int nctx = (anchor + 63) >> 6;
  int ntot = nctx + 1;

  f32x4 o_acc[4];
  float m[4], l[4];
  #pragma unroll
  for (int i = 0; i < 4; i++){ o_acc[i] = (f32x4){0.f,0.f,0.f,0.f}; m[i] = -3e38f; l[i] = 0.f; }

  for (int c = w; c < ntot; c += 4){
    bool draft = (c == nctx);
    int kbase = draft ? (S_LEN + n * 16) : c * 64;
    int nk    = draft ? 16 : min(64, anchor - c * 64);

    f32x4 s[4];
    #pragma unroll
    for (int nf = 0; nf < 4; nf++) s[nf] = (f32x4){0.f,0.f,0.f,0.f};
    #pragma unroll
    for (int ks = 0; ks < 2; ks++){
      #pragma unroll
      for (int nf = 0; nf < 4; nf++){
        int krow = min(kbase + nf * 16 + li, KVLEN - 1);
        short8 bfrag = *(const short8*)&kh[(size_t)krow * DMODEL + ks * 32 + g * 8];
        s[nf] = __builtin_amdgcn_mfma_f32_16x16x32_bf16(qa[ks], bfrag, s[nf], 0, 0, 0);
      }
    }

    #pragma unroll
    for (int r = 0; r < 4; r++){
      float mx = -3e38f;
      #pragma unroll
      for (int nf = 0; nf < 4; nf++){
        float sv = s[nf][r] * 0.125f;
        if (nf * 16 + li >= nk) sv = -3e38f;
        s[nf][r] = sv;
        mx = fmaxf(mx, sv);
      }
      #pragma unroll
      for (int mm = 1; mm < 16; mm <<= 1) mx = fmaxf(mx, __shfl_xor(mx, mm));
      float mn = fmaxf(m[r], mx);
      float sc = expf(m[r] - mn);
      float ps = 0.f;
      #pragma unroll
      for (int nf = 0; nf < 4; nf++){
        float p = expf(s[nf][r] - mn);
        ps += p;
        p_s[w][g * 4 + r][nf * 16 + li] = f2bf(p);
      }
      #pragma unroll
      for (int mm = 1; mm < 16; mm <<= 1) ps += __shfl_xor(ps, mm);
      l[r] = l[r] * sc + ps;
      m[r] = mn;
      #pragma unroll
      for (int nfd = 0; nfd < 4; nfd++) o_acc[nfd][r] *= sc;
    }

    #pragma unroll
    for (int ks = 0; ks < 2; ks++){
      short8 pa = *(const short8*)&p_s[w][li][ks * 32 + g * 8];
      int kcol = min(kbase + ks * 32 + g * 8, KVLEN - 8);
      #pragma unroll
      for (int nfd = 0; nfd < 4; nfd++){
        short8 vfrag = *(const short8*)&vTh[(size_t)(nfd * 16 + li) * KVLEN + kcol];
        o_acc[nfd] = __builtin_amdgcn_mfma_f32_16x16x32_bf16(pa, vfrag, o_acc[nfd], 0, 0, 0);
      }
    }
  }

  #pragma unroll
  for (int r = 0; r < 4; r++){
    if (li == 0){ ml_s[w][0][g * 4 + r] = m[r]; ml_s[w][1][g * 4 + r] = l[r]; }
    #pragma unroll
    for (int nfd = 0; nfd < 4; nfd++)
      o_s[w][g * 4 + r][nfd * 16 + li] = o_acc[nfd][r];
  }
  __syncthreads();

  {
    int row = t >> 4, c0 = (t & 15) * 4;
    float M = -3e38f;
    #pragma unroll
    for (int ww = 0; ww < 4; ww++) M = fmaxf(M, ml_s[ww][0][row]);
    float L = 0.f, ew[4];
    #pragma unroll
    for (int ww = 0; ww < 4; ww++){
      ew[ww] = expf(ml_s[ww][0][row] - M);
      L += ml_s[ww][1][row] * ew[ww];
    }
    float inv = 1.f / L;
    #pragma unroll
    for (int j = 0; j < 4; j++){
      float ov = 0.f;
      #pragma unroll
      for (int ww = 0; ww < 4; ww++) ov += o_s[ww][row][c0 + j] * ew[ww];
      attnb[(size_t)(n * 16 + row) * DMODEL + h * 64 + c0 + j] = f2bf(ov * inv);
    }
  }
}

// ---------------- LM head: 128x128-tile MFMA GEMM (global_load_lds staging) + fused softmax stats ----------------
// A: (2048,512) bf16, WT: (32000,512) bf16. Grid (16, 250). Full K per block ->
// complete logits for a 128-col span; per-64-col-half stats written as split partials.
__global__ __launch_bounds__(256) void lm_fused(const u16* __restrict__ A,
                                                const u16* __restrict__ WT,
                                                const int* __restrict__ input_ids,
                                                const int* __restrict__ anchors,
                                                float* __restrict__ pm, float* __restrict__ pl,
                                                float* __restrict__ pt, float* __restrict__ pbv,
                                                int* __restrict__ pbi){
  __shared__ __align__(16) u16 As[128 * 64];
  __shared__ __align__(16) u16 Bs[128 * 64];
  __shared__ int tcol_s[128];
  int rowbase = blockIdx.x * 128;
  int colbase = blockIdx.y * 128;
  int t = threadIdx.x, w = t >> 6, lane = t & 63;
  int g = lane >> 4, li = lane & 15;
  int wm = w >> 1, wn = w & 1;

  if (t < 128){
    int r = rowbase + t; int n = r >> 4, off = r & 15;
    int lab = anchors[n] + off;
    int safe = min(max(lab, 0), S_LEN - 1);
    tcol_s[t] = input_ids[safe];
  }

  f32x4 acc[4][4];
  #pragma unroll
  for (int i = 0; i < 4; i++)
    #pragma unroll
    for (int j = 0; j < 4; j++)
      acc[i][j] = (f32x4){0.f, 0.f, 0.f, 0.f};

  int lr8 = lane >> 3, lc8 = (lane & 7) * 8;
  for (int kt = 0; kt < 8; kt++){
    int kb = kt * 64;
    __syncthreads();
    #pragma unroll
    for (int i = 0; i < 4; i++){
      int slab = w * 4 + i;
      const u16* sa = &A [(size_t)(rowbase + slab * 8 + lr8) * DMODEL + kb + lc8];
      const u16* sb = &WT[(size_t)(colbase + slab * 8 + lr8) * DMODEL + kb + lc8];
      __builtin_amdgcn_global_load_lds(GAS(sa), LAS(&As[slab * 512]), 16, 0, 0);
      __builtin_amdgcn_global_load_lds(GAS(sb), LAS(&Bs[slab * 512]), 16, 0, 0);
    }
    __syncthreads();
    #pragma unroll
    for (int ks = 0; ks < 2; ks++){
      short8 af[4], bf[4];
      #pragma unroll
      for (int i = 0; i < 4; i++){
        af[i] = *(const short8*)&As[(wm * 64 + i * 16 + li) * 64 + ks * 32 + g * 8];
        bf[i] = *(const short8*)&Bs[(wn * 64 + i * 16 + li) * 64 + ks * 32 + g * 8];
      }
      #pragma unroll
      for (int mf = 0; mf < 4; mf++)
        #pragma unroll
        for (int nf = 0; nf < 4; nf++)
          acc[mf][nf] = __builtin_amdgcn_mfma_f32_16x16x32_bf16(af[mf], bf[nf], acc[mf][nf], 0, 0, 0);
    }
  }

  // epilogue: complete logits; per-row stats over this wave's 64-col half
  int mycolbase = colbase + wn * 64;
  int split = blockIdx.y * 2 + wn;
  #pragma unroll
  for (int mf = 0; mf < 4; mf++){
    #pragma unroll
    for (int r = 0; r < 4; r++){
      int rowl = wm * 64 + mf * 16 + g * 4 + r;
      float v0 = acc[mf][0][r], v1 = acc[mf][1][r], v2 = acc[mf][2][r], v3 = acc[mf][3][r];
      float mx = fmaxf(fmaxf(v0, v1), fmaxf(v2, v3));
      #pragma unroll
      for (int mm = 1; mm < 16; mm <<= 1) mx = fmaxf(mx, __shfl_xor(mx, mm));
      float se = expf(v0 - mx) + expf(v1 - mx) + expf(v2 - mx) + expf(v3 - mx);
      #pragma unroll
      for (int mm = 1; mm < 16; mm <<= 1) se += __shfl_xor(se, mm);
      // target logit (static nf indexing to avoid scratch)
      int tc = tcol_s[rowl] - mycolbase;
      bool inr = (tc >= 0) && (tc < 64);
      float tv = -3e38f;
      tv = fmaxf(tv, (inr && (tc >> 4) == 0 && li == (tc & 15)) ? v0 : -3e38f);
      tv = fmaxf(tv, (inr && (tc >> 4) == 1 && li == (tc & 15)) ? v1 : -3e38f);
      tv = fmaxf(tv, (inr && (tc >> 4) == 2 && li == (tc & 15)) ? v2 : -3e38f);
      tv = fmaxf(tv, (inr && (tc >> 4) == 3 && li == (tc & 15)) ? v3 : -3e38f);
      #pragma unroll
      for (int mm = 1; mm < 16; mm <<= 1) tv = fmaxf(tv, __shfl_xor(tv, mm));
      // argmax, first-max (lowest index) wins
      float lv = -3e38f; int lidx = 0x7fffffff;
      #pragma unroll
      for (int nf = 0; nf < 4; nf++){
        float v = (nf == 0) ? v0 : (nf == 1) ? v1 : (nf == 2) ? v2 : v3;
        int col = mycolbase + nf * 16 + li;
        if (v > lv || (v == lv && col < lidx)){ lv = v; lidx = col; }
      }
      #pragma unroll
      for (int mm = 1; mm < 16; mm <<= 1){
        float ov = __shfl_xor(lv, mm); int oi = __shfl_xor(lidx, mm);
        if (ov > lv || (ov == lv && oi < lidx)){ lv = ov; lidx = oi; }
      }
      if (li == 0){
        size_t idx = (size_t)(rowbase + rowl) * NSPLIT + split;
        pm[idx] = mx; pl[idx] = se; pt[idx] = tv; pbv[idx] = lv; pbi[idx] = lidx;
      }
    }
  }
}

// ---------------- per-row split merge: one wave per row ----------------
__global__ __launch_bounds__(256) void loss_rows(const float* __restrict__ pm, const float* __restrict__ pl,
                                                 const float* __restrict__ pt, const float* __restrict__ pbv,
                                                 const int* __restrict__ pbi,
                                                 const int* __restrict__ input_ids,
                                                 const int* __restrict__ anchors,
                                                 const unsigned char* __restrict__ keep,
                                                 const float* __restrict__ loss_mask,
                                                 float* __restrict__ rowacc){
  int t = threadIdx.x, w = t >> 6, lane = t & 63;
  int row = blockIdx.x * 4 + w;
  float M = -3e38f, L = 0.f, TV = -3e38f, BV = -3e38f; int BI = 0x7fffffff;
  for (int s = lane; s < NSPLIT; s += 64){
    size_t idx = (size_t)row * NSPLIT + s;
    float m_ = pm[idx], l_ = pl[idx];
    float nm = fmaxf(M, m_);
    L = L * expf(M - nm) + l_ * expf(m_ - nm);
    M = nm;
    TV = fmaxf(TV, pt[idx]);
    float bv_ = pbv[idx]; int bi_ = pbi[idx];
    if (bv_ > BV || (bv_ == BV && bi_ < BI)){ BV = bv_; BI = bi_; }
  }
  #pragma unroll
  for (int mm = 1; mm < 64; mm <<= 1){
    float om = __shfl_xor(M, mm), ol = __shfl_xor(L, mm);
    float nm = fmaxf(M, om);
    L = L * expf(M - nm) + ol * expf(om - nm); M = nm;
    TV = fmaxf(TV, __shfl_xor(TV, mm));
    float ob = __shfl_xor(BV, mm); int oi = __shfl_xor(BI, mm);
    if (ob > BV || (ob == BV && oi < BI)){ BV = ob; BI = oi; }
  }
  if (lane == 0){
    int n = row >> 4, off = row & 15;
    int lab = anchors[n] + off;
    int valid = (lab < S_LEN) ? 1 : 0;
    int safe = min(max(lab, 0), S_LEN - 1);
    int tgt = input_ids[safe];
    float wgt = (keep[n] ? 1.f : 0.f) * (valid ? 1.f : 0.f) * ((off > 0) ? 1.f : 0.f) * loss_mask[safe];
    float logp = TV - M - logf(L);
    rowacc[row * 3 + 0] = -logp * wgt;
    rowacc[row * 3 + 1] = wgt;
    rowacc[row * 3 + 2] = ((BI == tgt) && (wgt > 0.5f)) ? 1.f : 0.f;
  }
}

// ---------------- final sum over rows ----------------
__global__ __launch_bounds__(256) void final_sum(const float* __restrict__ rowacc, float* __restrict__ out){
  int t = threadIdx.x;
  float a = 0.f, b = 0.f, c = 0.f;
  for (int r = t; r < QLEN; r += 256){
    a += rowacc[r * 3 + 0]; b += rowacc[r * 3 + 1]; c += rowacc[r * 3 + 2];
  }
  __shared__ float sa[256], sb[256], sc_[256];
  sa[t] = a; sb[t] = b; sc_[t] = c;
  __syncthreads();
  for (int s = 128; s >= 1; s >>= 1){
    if (t < s){ sa[t] += sa[t + s]; sb[t] += sb[t + s]; sc_[t] += sc_[t + s]; }
    __syncthreads();
  }
  if (t == 0){
    out[0] = sa[0] / (sb[0] + 1e-6f);
    out[1] = sc_[0] / (sb[0] + 1e-6f);
  }
}

// ---------------- host ----------------
extern "C" void kernel_launch(void* const* d_in, const int* in_sizes, int n_in,
                              void* d_out, int out_size, void* d_ws, size_t ws_size,
                              hipStream_t stream) {
  const int*   input_ids = (const int*)  d_in[0];
  const float* hidden    = (const float*)d_in[1];
  const float* loss_mask = (const float*)d_in[2];
  const int*   anchors   = (const int*)  d_in[3];
  const unsigned char* keep = (const unsigned char*)d_in[4];
  const float* embed     = (const float*)d_in[5];
  const float* Wq        = (const float*)d_in[6];
  const float* Wk        = (const float*)d_in[7];
  const float* Wv        = (const float*)d_in[8];
  const float* Wo        = (const float*)d_in[9];
  const float* Wlm       = (const float*)d_in[10];

  char* ws = (char*)d_ws;
  size_t off = 0;
  auto take = [&](size_t bytes) -> char* {
    char* p = ws + off;
    off += (bytes + 255) & ~(size_t)255;
    return p;
  };
  u16* WqT  = (u16*)take((size_t)512 * 512 * 2);
  u16* WkT  = (u16*)take((size_t)512 * 512 * 2);
  u16* WvT  = (u16*)take((size_t)512 * 512 * 2);
  u16* WoT  = (u16*)take((size_t)512 * 512 * 2);
  u16* WlmT = (u16*)take((size_t)VOCAB * 512 * 2);
  u16* kvb  = (u16*)take((size_t)KVLEN * 512 * 2);
  u16* qb2  = (u16*)take((size_t)QLEN * 512 * 2);
  u16* kb   = (u16*)take((size_t)KVLEN * 512 * 2);
  u16* vTb  = (u16*)take((size_t)512 * KVLEN * 2);
  u16* attnb= (u16*)take((size_t)QLEN * 512 * 2);
  u16* ob   = (u16*)take((size_t)QLEN * 512 * 2);
  float* pm = (float*)take((size_t)QLEN * NSPLIT * 4);
  float* pl = (float*)take((size_t)QLEN * NSPLIT * 4);
  float* pt = (float*)take((size_t)QLEN * NSPLIT * 4);
  float* pbv= (float*)take((size_t)QLEN * NSPLIT * 4);
  int*   pbi= (int*)  take((size_t)QLEN * NSPLIT * 4);
  float* rowacc = (float*)take((size_t)QLEN * 3 * 4);

  transpose_cast<<<dim3(16, 16),   256, 0, stream>>>(Wq,  WqT,  512, 512);
  transpose_cast<<<dim3(16, 16),   256, 0, stream>>>(Wk,  WkT,  512, 512);
  transpose_cast<<<dim3(16, 16),   256, 0, stream>>>(Wv,  WvT,  512, 512);
  transpose_cast<<<dim3(16, 16),   256, 0, stream>>>(Wo,  WoT,  512, 512);
  transpose_cast<<<dim3(1000, 16), 256, 0, stream>>>(Wlm, WlmT, 512, VOCAB);

  build_kv<<<KVLEN, 128, 0, stream>>>(hidden, embed, input_ids, anchors, keep, kvb);

  gemm64<0><<<dim3(64, 8), 256, 0, stream>>>(kvb, WkT, kb,  KVLEN, 512, 512, 512);   // k (4096,512)
  gemm64<1><<<dim3(64, 8), 256, 0, stream>>>(kvb, WvT, vTb, KVLEN, 512, 512, KVLEN); // v^T (512,4096)
  gemm64<0><<<dim3(32, 8), 256, 0, stream>>>(kvb + (size_t)S_LEN * 512, WqT, qb2, QLEN, 512, 512, 512); // q

  attn_mfma<<<dim3(NBLK, 8), 256, 0, stream>>>(qb2, kb, vTb, anchors, keep, attnb);

  gemm64<0><<<dim3(32, 8), 256, 0, stream>>>(attnb, WoT, ob, QLEN, 512, 512, 512);   // o = attn @ Wo

  lm_fused<<<dim3(16, 250), 256, 0, stream>>>(ob, WlmT, input_ids, anchors, pm, pl, pt, pbv, pbi);

  loss_rows<<<512, 256, 0, stream>>>(pm, pl, pt, pbv, pbi, input_ids, anchors, keep, loss_mask, rowacc);

  final_sum<<<1, 256, 0, stream>>>(rowacc, (float*)d_out);
}

// Round 4
// 311.162 us; speedup vs baseline: 9.3443x; 1.2214x over previous
//
#include <hip/hip_runtime.h>

typedef unsigned short u16;
typedef __attribute__((ext_vector_type(4))) float f32x4;
typedef __attribute__((ext_vector_type(8))) short short8;
typedef __attribute__((ext_vector_type(4))) unsigned int uv4;
typedef __attribute__((ext_vector_type(4))) float fv4;
typedef __attribute__((ext_vector_type(4))) unsigned short usv4;

#define S_LEN 2048
#define NBLK 128
#define DMODEL 512
#define VOCAB 32000
#define QLEN 2048
#define KVLEN 4096
#define NSPLIT 500   // 32000 vocab / 64-col wave spans

#define GAS(p) ((const __attribute__((address_space(1))) void*)(const void*)(p))
#define LAS(p) ((__attribute__((address_space(3))) void*)(void*)(p))

__device__ __forceinline__ float bf2f(u16 u){
  union { unsigned int i; float f; } x; x.i = ((unsigned int)u) << 16; return x.f;
}
__device__ __forceinline__ u16 f2bf(float f){
  union { float f; unsigned int i; } x; x.f = f;
  unsigned int r = x.i + 0x7fffu + ((x.i >> 16) & 1u);
  return (u16)(r >> 16);
}

// ---------------- transpose + cast f32(K,N) -> bf16(N,K) ----------------
__global__ __launch_bounds__(256) void transpose_cast(const float* __restrict__ in,
                                                      u16* __restrict__ out,
                                                      int K, int N){
  __shared__ float tile[32][33];
  int t = threadIdx.x, tx = t & 31, ty = t >> 5;
  int nb = blockIdx.x * 32, kb = blockIdx.y * 32;
  #pragma unroll
  for (int i = 0; i < 4; i++){
    int r = ty + i * 8;
    tile[r][tx] = in[(size_t)(kb + r) * N + nb + tx];
  }
  __syncthreads();
  #pragma unroll
  for (int i = 0; i < 4; i++){
    int r = ty + i * 8;
    out[(size_t)(nb + r) * K + kb + tx] = f2bf(tile[tx][r]);
  }
}

// ---------------- build kv_in (bf16 4096x512): [hidden ; noise_embedding] ----------------
__global__ __launch_bounds__(128) void build_kv(const float* __restrict__ hidden,
                                                const float* __restrict__ embed,
                                                const int* __restrict__ input_ids,
                                                const int* __restrict__ anchors,
                                                const unsigned char* __restrict__ keep,
                                                u16* __restrict__ kvb){
  int row = blockIdx.x;           // 0..4095
  int t = threadIdx.x;            // 0..127
  const float* src;
  if (row < S_LEN){
    src = hidden + (size_t)row * DMODEL;
  } else {
    int q = row - S_LEN;
    int id = 3;                   // MASK_TOKEN_ID
    if ((q & 15) == 0){
      int n = q >> 4;
      if (keep[n]){
        int a = anchors[n]; a = min(max(a, 0), S_LEN - 1);
        id = input_ids[a];
      }
    }
    src = embed + (size_t)id * DMODEL;
  }
  int c = t * 4;
  fv4 v = *(const fv4*)&src[c];
  usv4 o; o[0] = f2bf(v[0]); o[1] = f2bf(v[1]); o[2] = f2bf(v[2]); o[3] = f2bf(v[3]);
  *(usv4*)&kvb[(size_t)row * DMODEL + c] = o;
}

// ---------------- generic 64x64 tile bf16 GEMM: C[M,N] = A[M,K] * B[K,N], B given transposed (N,K) ----------------
template<int TRANS>
__global__ __launch_bounds__(256) void gemm64(const u16* __restrict__ A,
                                              const u16* __restrict__ BT,
                                              u16* __restrict__ C,
                                              int M, int N, int K, int ldc){
  __shared__ __align__(16) u16 As[64][72];
  __shared__ __align__(16) u16 Bs[64][72];
  int t = threadIdx.x, w = t >> 6, lane = t & 63;
  int wm = w >> 1, wn = w & 1;
  int rowbase = blockIdx.x * 64, colbase = blockIdx.y * 64;
  f32x4 acc[2][2];
  #pragma unroll
  for (int i = 0; i < 2; i++)
    #pragma unroll
    for (int j = 0; j < 2; j++)
      acc[i][j] = (f32x4){0.f, 0.f, 0.f, 0.f};

  int srow = t >> 2, sc0 = (t & 3) * 8;
  for (int kb = 0; kb < K; kb += 64){
    __syncthreads();
    *(uv4*)&As[srow][sc0]      = *(const uv4*)&A [(size_t)(rowbase + srow) * K + kb + sc0];
    *(uv4*)&As[srow][sc0 + 32] = *(const uv4*)&A [(size_t)(rowbase + srow) * K + kb + sc0 + 32];
    *(uv4*)&Bs[srow][sc0]      = *(const uv4*)&BT[(size_t)(colbase + srow) * K + kb + sc0];
    *(uv4*)&Bs[srow][sc0 + 32] = *(const uv4*)&BT[(size_t)(colbase + srow) * K + kb + sc0 + 32];
    __syncthreads();
    #pragma unroll
    for (int ks = 0; ks < 2; ks++){
      int ko = ks * 32 + (lane >> 4) * 8;
      short8 a0 = *(const short8*)&As[wm * 32 +      (lane & 15)][ko];
      short8 a1 = *(const short8*)&As[wm * 32 + 16 + (lane & 15)][ko];
      short8 b0 = *(const short8*)&Bs[wn * 32 +      (lane & 15)][ko];
      short8 b1 = *(const short8*)&Bs[wn * 32 + 16 + (lane & 15)][ko];
      acc[0][0] = __builtin_amdgcn_mfma_f32_16x16x32_bf16(a0, b0, acc[0][0], 0, 0, 0);
      acc[0][1] = __builtin_amdgcn_mfma_f32_16x16x32_bf16(a0, b1, acc[0][1], 0, 0, 0);
      acc[1][0] = __builtin_amdgcn_mfma_f32_16x16x32_bf16(a1, b0, acc[1][0], 0, 0, 0);
      acc[1][1] = __builtin_amdgcn_mfma_f32_16x16x32_bf16(a1, b1, acc[1][1], 0, 0, 0);
    }
  }
  #pragma unroll
  for (int mf = 0; mf < 2; mf++)
    #pragma unroll
    for (int nf = 0; nf < 2; nf++)
      #pragma unroll
      for (int r = 0; r < 4; r++){
        int row = rowbase + wm * 32 + mf * 16 + (lane >> 4) * 4 + r;
        int col = colbase + wn * 32 + nf * 16 + (lane & 15);
        u16 vv = f2bf(acc[mf][nf][r]);
        if (TRANS) C[(size_t)col * ldc + row] = vv;
        else       C[(size_t)row * ldc + col] = vv;
      }
}

// ---------------- MFMA flash attention: one (draft block n, head h) per workgroup ----------------
__global__ __launch_bounds__(256) void attn_mfma(const u16* __restrict__ qb,
                                                 const u16* __restrict__ kb,
                                                 const u16* __restrict__ vT,
                                                 const int* __restrict__ anchors,
                                                 const unsigned char* __restrict__ keep,
                                                 u16* __restrict__ attnb){
  int n = blockIdx.x, h = blockIdx.y;
  int t = threadIdx.x, w = t >> 6, lane = t & 63;
  int g = lane >> 4, li = lane & 15;

  __shared__ __align__(16) u16 q_s[16][72];
  __shared__ __align__(16) u16 p_s[4][16][72];
  __shared__ float o_s[4][16][64];
  __shared__ float ml_s[4][2][16];

  // stage Q tile (16 x 64)
  {
    int r = t >> 4, c4 = (t & 15) * 4;
    *(usv4*)&q_s[r][c4] = *(const usv4*)&qb[(size_t)(n * 16 + r) * DMODEL + h * 64 + c4];
  }
  __syncthreads();

  int anchor = anchors[n];
  bool kp = keep[n] != 0;
  const u16* kh  = kb + h * 64;
  const u16* vTh = vT + (size_t)(h * 64) * KVLEN;

  if (!kp){
    if (w == 0){
      float acc = 0.f;
      const u16* row = vTh + (size_t)lane * KVLEN;
      for (int k2 = 0; k2 < KVLEN; k2 += 8){
        short8 vv = *(const short8*)&row[k2];
        #pragma unroll
        for (int j = 0; j < 8; j++) acc += bf2f((u16)vv[j]);
      }
      acc *= (1.f / 4096.f);
      u16 ov = f2bf(acc);
      for (int r = 0; r < 16; r++)
        attnb[(size_t)(n * 16 + r) * DMODEL + h * 64 + lane] = ov;
    }
    return;
  }

  short8 qa[2];
  #pragma unroll
  for (int ks = 0; ks < 2; ks++)
    qa[ks] = *(const short8*)&q_s[li][ks * 32 + g * 8];

  int nctx = (anchor + 63) >> 6;
  int ntot = nctx + 1;

  f32x4 o_acc[4];
  float m[4], l[4];
  #pragma unroll
  for (int i = 0; i < 4; i++){ o_acc[i] = (f32x4){0.f,0.f,0.f,0.f}; m[i] = -3e38f; l[i] = 0.f; }

  for (int c = w; c < ntot; c += 4){
    bool draft = (c == nctx);
    int kbase = draft ? (S_LEN + n * 16) : c * 64;
    int nk    = draft ? 16 : min(64, anchor - c * 64);

    f32x4 s[4];
    #pragma unroll
    for (int nf = 0; nf < 4; nf++) s[nf] = (f32x4){0.f,0.f,0.f,0.f};
    #pragma unroll
    for (int ks = 0; ks < 2; ks++){
      #pragma unroll
      for (int nf = 0; nf < 4; nf++){
        int krow = min(kbase + nf * 16 + li, KVLEN - 1);
        short8 bfrag = *(const short8*)&kh[(size_t)krow * DMODEL + ks * 32 + g * 8];
        s[nf] = __builtin_amdgcn_mfma_f32_16x16x32_bf16(qa[ks], bfrag, s[nf], 0, 0, 0);
      }
    }

    #pragma unroll
    for (int r = 0; r < 4; r++){
      float mx = -3e38f;
      #pragma unroll
      for (int nf = 0; nf < 4; nf++){
        float sv = s[nf][r] * 0.125f;
        if (nf * 16 + li >= nk) sv = -3e38f;
        s[nf][r] = sv;
        mx = fmaxf(mx, sv);
      }
      #pragma unroll
      for (int mm = 1; mm < 16; mm <<= 1) mx = fmaxf(mx, __shfl_xor(mx, mm));
      float mn = fmaxf(m[r], mx);
      float sc = expf(m[r] - mn);
      float ps = 0.f;
      #pragma unroll
      for (int nf = 0; nf < 4; nf++){
        float p = expf(s[nf][r] - mn);
        ps += p;
        p_s[w][g * 4 + r][nf * 16 + li] = f2bf(p);
      }
      #pragma unroll
      for (int mm = 1; mm < 16; mm <<= 1) ps += __shfl_xor(ps, mm);
      l[r] = l[r] * sc + ps;
      m[r] = mn;
      #pragma unroll
      for (int nfd = 0; nfd < 4; nfd++) o_acc[nfd][r] *= sc;
    }

    #pragma unroll
    for (int ks = 0; ks < 2; ks++){
      short8 pa = *(const short8*)&p_s[w][li][ks * 32 + g * 8];
      int kcol = min(kbase + ks * 32 + g * 8, KVLEN - 8);
      #pragma unroll
      for (int nfd = 0; nfd < 4; nfd++){
        short8 vfrag = *(const short8*)&vTh[(size_t)(nfd * 16 + li) * KVLEN + kcol];
        o_acc[nfd] = __builtin_amdgcn_mfma_f32_16x16x32_bf16(pa, vfrag, o_acc[nfd], 0, 0, 0);
      }
    }
  }

  #pragma unroll
  for (int r = 0; r < 4; r++){
    if (li == 0){ ml_s[w][0][g * 4 + r] = m[r]; ml_s[w][1][g * 4 + r] = l[r]; }
    #pragma unroll
    for (int nfd = 0; nfd < 4; nfd++)
      o_s[w][g * 4 + r][nfd * 16 + li] = o_acc[nfd][r];
  }
  __syncthreads();

  {
    int row = t >> 4, c0 = (t & 15) * 4;
    float M = -3e38f;
    #pragma unroll
    for (int ww = 0; ww < 4; ww++) M = fmaxf(M, ml_s[ww][0][row]);
    float L = 0.f, ew[4];
    #pragma unroll
    for (int ww = 0; ww < 4; ww++){
      ew[ww] = expf(ml_s[ww][0][row] - M);
      L += ml_s[ww][1][row] * ew[ww];
    }
    float inv = 1.f / L;
    #pragma unroll
    for (int j = 0; j < 4; j++){
      float ov = 0.f;
      #pragma unroll
      for (int ww = 0; ww < 4; ww++) ov += o_s[ww][row][c0 + j] * ew[ww];
      attnb[(size_t)(n * 16 + row) * DMODEL + h * 64 + c0 + j] = f2bf(ov * inv);
    }
  }
}

// ---------------- LM head: swapped-operand MFMA GEMM + lane-local softmax stats ----------------
// A-operand = W_lm rows (vocab, direct from global), B-operand = ob rows (LDS, XOR-swizzled).
// Block: 64 q-rows x 256 vocab (4 waves x 64 vocab each). Grid (32, 125).
// D layout: vocab = vf*16 + g*4 + r (A-axis), q = qf*16 + li (B-axis) -> per-row stats lane-local.
__global__ __launch_bounds__(256) void lm_fused(const u16* __restrict__ obp,
                                                const u16* __restrict__ WT,
                                                const int* __restrict__ input_ids,
                                                const int* __restrict__ anchors,
                                                float* __restrict__ pl,
                                                float* __restrict__ pt, float* __restrict__ pbv,
                                                int* __restrict__ pbi){
  __shared__ __align__(16) u16 AsA[64 * 64];
  __shared__ __align__(16) u16 AsB[64 * 64];
  __shared__ int tcol_s[64];
  int qbase = blockIdx.x * 64;
  int vocabbase = blockIdx.y * 256;
  int t = threadIdx.x, w = t >> 6, lane = t & 63;
  int g = lane >> 4, li = lane & 15;
  int wvbase = vocabbase + w * 64;

  if (t < 64){
    int r = qbase + t; int n = r >> 4, off = r & 15;
    int lab = anchors[n] + off;
    int safe = min(max(lab, 0), S_LEN - 1);
    tcol_s[t] = input_ids[safe];
  }

  // W row pointers for this lane's A-fragments (row = wvbase + vf*16 + li)
  const u16* wr0 = WT + (size_t)(wvbase +  0 + li) * DMODEL;
  const u16* wr1 = WT + (size_t)(wvbase + 16 + li) * DMODEL;
  const u16* wr2 = WT + (size_t)(wvbase + 32 + li) * DMODEL;
  const u16* wr3 = WT + (size_t)(wvbase + 48 + li) * DMODEL;

  f32x4 acc[4][4];
  #pragma unroll
  for (int i = 0; i < 4; i++)
    #pragma unroll
    for (int j = 0; j < 4; j++)
      acc[i][j] = (f32x4){0.f, 0.f, 0.f, 0.f};

  // stage ob[qbase..+64)[kb..+64) into LDS, XOR-swizzled source so linear gload_lds
  // dest yields LDS[row][cg^(row&7)] = ob[row][cg*8] (both-sides swizzle, rule #21)
  int r0 = t >> 3, cg0 = t & 7;
  auto stage = [&](u16* dst, int kb){
    const u16* s0 = &obp[(size_t)(qbase + r0)      * DMODEL + kb + ((cg0 ^ (r0 & 7)) << 3)];
    const u16* s1 = &obp[(size_t)(qbase + 32 + r0) * DMODEL + kb + ((cg0 ^ (r0 & 7)) << 3)];
    __builtin_amdgcn_global_load_lds(GAS(s0), LAS(dst + w * 512), 16, 0, 0);
    __builtin_amdgcn_global_load_lds(GAS(s1), LAS(dst + 2048 + w * 512), 16, 0, 0);
  };

  stage(AsA, 0);
  __syncthreads();                       // drains vmcnt before barrier
  u16* cur = AsA; u16* nxt = AsB;

  for (int kt = 0; kt < 8; kt++){
    if (kt < 7) stage(nxt, (kt + 1) * 64);
    int kb = kt * 64;
    #pragma unroll
    for (int ks = 0; ks < 2; ks++){
      short8 wf0 = *(const short8*)(wr0 + kb + ks * 32 + g * 8);
      short8 wf1 = *(const short8*)(wr1 + kb + ks * 32 + g * 8);
      short8 wf2 = *(const short8*)(wr2 + kb + ks * 32 + g * 8);
      short8 wf3 = *(const short8*)(wr3 + kb + ks * 32 + g * 8);
      short8 obf[4];
      #pragma unroll
      for (int qf = 0; qf < 4; qf++){
        int row = qf * 16 + li;
        obf[qf] = *(const short8*)&cur[row * 64 + (((ks * 4 + g) ^ (li & 7)) << 3)];
      }
      #pragma unroll
      for (int qf = 0; qf < 4; qf++){
        acc[0][qf] = __builtin_amdgcn_mfma_f32_16x16x32_bf16(wf0, obf[qf], acc[0][qf], 0, 0, 0);
        acc[1][qf] = __builtin_amdgcn_mfma_f32_16x16x32_bf16(wf1, obf[qf], acc[1][qf], 0, 0, 0);
        acc[2][qf] = __builtin_amdgcn_mfma_f32_16x16x32_bf16(wf2, obf[qf], acc[2][qf], 0, 0, 0);
        acc[3][qf] = __builtin_amdgcn_mfma_f32_16x16x32_bf16(wf3, obf[qf], acc[3][qf], 0, 0, 0);
      }
    }
    __syncthreads();                     // drains staging of nxt + all reads of cur done
    u16* tmpp = cur; cur = nxt; nxt = tmpp;
  }

  // epilogue: lane-local stats (M == 0: logits are small; plain sum-exp is safe in f32)
  int split = blockIdx.y * 4 + w;
  #pragma unroll
  for (int qf = 0; qf < 4; qf++){
    int qloc = qf * 16 + li;
    int tc = tcol_s[qloc] - wvbase;      // target col relative to this wave's span
    float se = 0.f, tv = -3e38f, bv = -3e38f; int bi = 0x7fffffff;
    #pragma unroll
    for (int vf = 0; vf < 4; vf++){
      #pragma unroll
      for (int r = 0; r < 4; r++){
        float v = acc[vf][qf][r];
        int pos = vf * 16 + g * 4 + r;   // ascending over (vf,r) for fixed lane
        se += expf(v);
        if (pos == tc) tv = v;
        if (v > bv){ bv = v; bi = pos; } // strict > keeps earliest (first-max)
      }
    }
    #pragma unroll
    for (int off = 16; off <= 32; off <<= 1){
      se += __shfl_xor(se, off);
      tv = fmaxf(tv, __shfl_xor(tv, off));
      float ob_ = __shfl_xor(bv, off); int oi = __shfl_xor(bi, off);
      if (ob_ > bv || (ob_ == bv && oi < bi)){ bv = ob_; bi = oi; }
    }
    if (g == 0){
      size_t idx = (size_t)(qbase + qloc) * NSPLIT + split;
      pl[idx] = se; pt[idx] = tv; pbv[idx] = bv; pbi[idx] = wvbase + bi;
    }
  }
}

// ---------------- per-row split merge: one wave per row ----------------
__global__ __launch_bounds__(256) void loss_rows(const float* __restrict__ pl,
                                                 const float* __restrict__ pt, const float* __restrict__ pbv,
                                                 const int* __restrict__ pbi,
                                                 const int* __restrict__ input_ids,
                                                 const int* __restrict__ anchors,
                                                 const unsigned char* __restrict__ keep,
                                                 const float* __restrict__ loss_mask,
                                                 float* __restrict__ rowacc){
  int t = threadIdx.x, w = t >> 6, lane = t & 63;
  int row = blockIdx.x * 4 + w;
  float L = 0.f, TV = -3e38f, BV = -3e38f; int BI = 0x7fffffff;
  for (int s = lane; s < NSPLIT; s += 64){
    size_t idx = (size_t)row * NSPLIT + s;
    L += pl[idx];
    TV = fmaxf(TV, pt[idx]);
    float bv_ = pbv[idx]; int bi_ = pbi[idx];
    if (bv_ > BV || (bv_ == BV && bi_ < BI)){ BV = bv_; BI = bi_; }
  }
  #pragma unroll
  for (int mm = 1; mm < 64; mm <<= 1){
    L += __shfl_xor(L, mm);
    TV = fmaxf(TV, __shfl_xor(TV, mm));
    float ob = __shfl_xor(BV, mm); int oi = __shfl_xor(BI, mm);
    if (ob > BV || (ob == BV && oi < BI)){ BV = ob; BI = oi; }
  }
  if (lane == 0){
    int n = row >> 4, off = row & 15;
    int lab = anchors[n] + off;
    int valid = (lab < S_LEN) ? 1 : 0;
    int safe = min(max(lab, 0), S_LEN - 1);
    int tgt = input_ids[safe];
    float wgt = (keep[n] ? 1.f : 0.f) * (valid ? 1.f : 0.f) * ((off > 0) ? 1.f : 0.f) * loss_mask[safe];
    float logp = TV - logf(L);
    rowacc[row * 3 + 0] = -logp * wgt;
    rowacc[row * 3 + 1] = wgt;
    rowacc[row * 3 + 2] = ((BI == tgt) && (wgt > 0.5f)) ? 1.f : 0.f;
  }
}

// ---------------- final sum over rows ----------------
__global__ __launch_bounds__(256) void final_sum(const float* __restrict__ rowacc, float* __restrict__ out){
  int t = threadIdx.x;
  float a = 0.f, b = 0.f, c = 0.f;
  for (int r = t; r < QLEN; r += 256){
    a += rowacc[r * 3 + 0]; b += rowacc[r * 3 + 1]; c += rowacc[r * 3 + 2];
  }
  __shared__ float sa[256], sb[256], sc_[256];
  sa[t] = a; sb[t] = b; sc_[t] = c;
  __syncthreads();
  for (int s = 128; s >= 1; s >>= 1){
    if (t < s){ sa[t] += sa[t + s]; sb[t] += sb[t + s]; sc_[t] += sc_[t + s]; }
    __syncthreads();
  }
  if (t == 0){
    out[0] = sa[0] / (sb[0] + 1e-6f);
    out[1] = sc_[0] / (sb[0] + 1e-6f);
  }
}

// ---------------- host ----------------
extern "C" void kernel_launch(void* const* d_in, const int* in_sizes, int n_in,
                              void* d_out, int out_size, void* d_ws, size_t ws_size,
                              hipStream_t stream) {
  const int*   input_ids = (const int*)  d_in[0];
  const float* hidden    = (const float*)d_in[1];
  const float* loss_mask = (const float*)d_in[2];
  const int*   anchors   = (const int*)  d_in[3];
  const unsigned char* keep = (const unsigned char*)d_in[4];
  const float* embed     = (const float*)d_in[5];
  const float* Wq        = (const float*)d_in[6];
  const float* Wk        = (const float*)d_in[7];
  const float* Wv        = (const float*)d_in[8];
  const float* Wo        = (const float*)d_in[9];
  const float* Wlm       = (const float*)d_in[10];

  char* ws = (char*)d_ws;
  size_t off = 0;
  auto take = [&](size_t bytes) -> char* {
    char* p = ws + off;
    off += (bytes + 255) & ~(size_t)255;
    return p;
  };
  u16* WqT  = (u16*)take((size_t)512 * 512 * 2);
  u16* WkT  = (u16*)take((size_t)512 * 512 * 2);
  u16* WvT  = (u16*)take((size_t)512 * 512 * 2);
  u16* WoT  = (u16*)take((size_t)512 * 512 * 2);
  u16* WlmT = (u16*)take((size_t)VOCAB * 512 * 2);
  u16* kvb  = (u16*)take((size_t)KVLEN * 512 * 2);
  u16* qb2  = (u16*)take((size_t)QLEN * 512 * 2);
  u16* kb   = (u16*)take((size_t)KVLEN * 512 * 2);
  u16* vTb  = (u16*)take((size_t)512 * KVLEN * 2);
  u16* attnb= (u16*)take((size_t)QLEN * 512 * 2);
  u16* ob   = (u16*)take((size_t)QLEN * 512 * 2);
  float* pl = (float*)take((size_t)QLEN * NSPLIT * 4);
  float* pt = (float*)take((size_t)QLEN * NSPLIT * 4);
  float* pbv= (float*)take((size_t)QLEN * NSPLIT * 4);
  int*   pbi= (int*)  take((size_t)QLEN * NSPLIT * 4);
  float* rowacc = (float*)take((size_t)QLEN * 3 * 4);

  transpose_cast<<<dim3(16, 16),   256, 0, stream>>>(Wq,  WqT,  512, 512);
  transpose_cast<<<dim3(16, 16),   256, 0, stream>>>(Wk,  WkT,  512, 512);
  transpose_cast<<<dim3(16, 16),   256, 0, stream>>>(Wv,  WvT,  512, 512);
  transpose_cast<<<dim3(16, 16),   256, 0, stream>>>(Wo,  WoT,  512, 512);
  transpose_cast<<<dim3(1000, 16), 256, 0, stream>>>(Wlm, WlmT, 512, VOCAB);

  build_kv<<<KVLEN, 128, 0, stream>>>(hidden, embed, input_ids, anchors, keep, kvb);

  gemm64<0><<<dim3(64, 8), 256, 0, stream>>>(kvb, WkT, kb,  KVLEN, 512, 512, 512);   // k (4096,512)
  gemm64<1><<<dim3(64, 8), 256, 0, stream>>>(kvb, WvT, vTb, KVLEN, 512, 512, KVLEN); // v^T (512,4096)
  gemm64<0><<<dim3(32, 8), 256, 0, stream>>>(kvb + (size_t)S_LEN * 512, WqT, qb2, QLEN, 512, 512, 512); // q

  attn_mfma<<<dim3(NBLK, 8), 256, 0, stream>>>(qb2, kb, vTb, anchors, keep, attnb);

  gemm64<0><<<dim3(32, 8), 256, 0, stream>>>(attnb, WoT, ob, QLEN, 512, 512, 512);   // o = attn @ Wo

  lm_fused<<<dim3(32, 125), 256, 0, stream>>>(ob, WlmT, input_ids, anchors, pl, pt, pbv, pbi);

  loss_rows<<<512, 256, 0, stream>>>(pl, pt, pbv, pbi, input_ids, anchors, keep, loss_mask, rowacc);

  final_sum<<<1, 256, 0, stream>>>(rowacc, (float*)d_out);
}

// Round 5
// 306.743 us; speedup vs baseline: 9.4789x; 1.0144x over previous
//
#include <hip/hip_runtime.h>

typedef unsigned short u16;
typedef __attribute__((ext_vector_type(4))) float f32x4;
typedef __attribute__((ext_vector_type(8))) short short8;
typedef __attribute__((ext_vector_type(4))) unsigned int uv4;
typedef __attribute__((ext_vector_type(4))) float fv4;
typedef __attribute__((ext_vector_type(4))) unsigned short usv4;

#define S_LEN 2048
#define NBLK 128
#define DMODEL 512
#define VOCAB 32000
#define QLEN 2048
#define KVLEN 4096
#define NSPLIT 500   // 32000 vocab / 64-col wave spans

#define GAS(p) ((const __attribute__((address_space(1))) void*)(const void*)(p))
#define LAS(p) ((__attribute__((address_space(3))) void*)(void*)(p))

__device__ __forceinline__ float bf2f(u16 u){
  union { unsigned int i; float f; } x; x.i = ((unsigned int)u) << 16; return x.f;
}
__device__ __forceinline__ u16 f2bf(float f){
  union { float f; unsigned int i; } x; x.f = f;
  unsigned int r = x.i + 0x7fffu + ((x.i >> 16) & 1u);
  return (u16)(r >> 16);
}

// ---------------- transpose + cast f32(K,N) -> bf16(N,K) ----------------
__global__ __launch_bounds__(256) void transpose_cast(const float* __restrict__ in,
                                                      u16* __restrict__ out,
                                                      int K, int N){
  __shared__ float tile[32][33];
  int t = threadIdx.x, tx = t & 31, ty = t >> 5;
  int nb = blockIdx.x * 32, kb = blockIdx.y * 32;
  #pragma unroll
  for (int i = 0; i < 4; i++){
    int r = ty + i * 8;
    tile[r][tx] = in[(size_t)(kb + r) * N + nb + tx];
  }
  __syncthreads();
  #pragma unroll
  for (int i = 0; i < 4; i++){
    int r = ty + i * 8;
    out[(size_t)(nb + r) * K + kb + tx] = f2bf(tile[tx][r]);
  }
}

// ---------------- build kv_in (bf16 4096x512): [hidden ; noise_embedding] ----------------
__global__ __launch_bounds__(128) void build_kv(const float* __restrict__ hidden,
                                                const float* __restrict__ embed,
                                                const int* __restrict__ input_ids,
                                                const int* __restrict__ anchors,
                                                const unsigned char* __restrict__ keep,
                                                u16* __restrict__ kvb){
  int row = blockIdx.x;           // 0..4095
  int t = threadIdx.x;            // 0..127
  const float* src;
  if (row < S_LEN){
    src = hidden + (size_t)row * DMODEL;
  } else {
    int q = row - S_LEN;
    int id = 3;                   // MASK_TOKEN_ID
    if ((q & 15) == 0){
      int n = q >> 4;
      if (keep[n]){
        int a = anchors[n]; a = min(max(a, 0), S_LEN - 1);
        id = input_ids[a];
      }
    }
    src = embed + (size_t)id * DMODEL;
  }
  int c = t * 4;
  fv4 v = *(const fv4*)&src[c];
  usv4 o; o[0] = f2bf(v[0]); o[1] = f2bf(v[1]); o[2] = f2bf(v[2]); o[3] = f2bf(v[3]);
  *(usv4*)&kvb[(size_t)row * DMODEL + c] = o;
}

// ---------------- projection GEMM: 128x64 tile, gload_lds staged, XOR-swizzled, dbuf ----------------
// C[M,N] = A[M,K] * B[K,N], B given transposed (N,K). 4 waves; wave w owns rows w*32..+32.
template<int TRANS>
__global__ __launch_bounds__(256) void gemm128x64(const u16* __restrict__ A,
                                                  const u16* __restrict__ BT,
                                                  u16* __restrict__ C,
                                                  int M, int N, int K, int ldc){
  __shared__ __align__(16) u16 As[2][128 * 64];
  __shared__ __align__(16) u16 Bs[2][64 * 64];
  int t = threadIdx.x, w = t >> 6, lane = t & 63;
  int g = lane >> 4, li = lane & 15;
  int rowbase = blockIdx.x * 128, colbase = blockIdx.y * 64;
  int r0 = t >> 3, cg0 = t & 7;
  int swz = (cg0 ^ (r0 & 7)) << 3;   // pre-swizzled source col so linear LDS dest = swizzled layout

  auto stageA = [&](u16* dst, int kb){
    #pragma unroll
    for (int i = 0; i < 4; i++)
      __builtin_amdgcn_global_load_lds(GAS(&A[(size_t)(rowbase + r0 + i * 32) * K + kb + swz]),
                                       LAS(dst + i * 2048 + w * 512), 16, 0, 0);
  };
  auto stageB = [&](u16* dst, int kb){
    #pragma unroll
    for (int i = 0; i < 2; i++)
      __builtin_amdgcn_global_load_lds(GAS(&BT[(size_t)(colbase + r0 + i * 32) * K + kb + swz]),
                                       LAS(dst + i * 2048 + w * 512), 16, 0, 0);
  };

  f32x4 acc[2][4];
  #pragma unroll
  for (int i = 0; i < 2; i++)
    #pragma unroll
    for (int j = 0; j < 4; j++)
      acc[i][j] = (f32x4){0.f, 0.f, 0.f, 0.f};

  stageA(As[0], 0); stageB(Bs[0], 0);
  __syncthreads();

  int nkt = K >> 6;
  for (int kt = 0; kt < nkt; kt++){
    u16* curA = As[kt & 1]; u16* curB = Bs[kt & 1];
    if (kt + 1 < nkt){ stageA(As[(kt + 1) & 1], (kt + 1) * 64); stageB(Bs[(kt + 1) & 1], (kt + 1) * 64); }
    #pragma unroll
    for (int ks = 0; ks < 2; ks++){
      short8 af[2], bf[4];
      #pragma unroll
      for (int mf = 0; mf < 2; mf++){
        int row = w * 32 + mf * 16 + li;
        af[mf] = *(const short8*)&curA[row * 64 + (((ks * 4 + g) ^ (li & 7)) << 3)];
      }
      #pragma unroll
      for (int nf = 0; nf < 4; nf++){
        int row = nf * 16 + li;
        bf[nf] = *(const short8*)&curB[row * 64 + (((ks * 4 + g) ^ (li & 7)) << 3)];
      }
      #pragma unroll
      for (int mf = 0; mf < 2; mf++)
        #pragma unroll
        for (int nf = 0; nf < 4; nf++)
          acc[mf][nf] = __builtin_amdgcn_mfma_f32_16x16x32_bf16(af[mf], bf[nf], acc[mf][nf], 0, 0, 0);
    }
    __syncthreads();
  }

  #pragma unroll
  for (int mf = 0; mf < 2; mf++)
    #pragma unroll
    for (int nf = 0; nf < 4; nf++)
      #pragma unroll
      for (int r = 0; r < 4; r++){
        int row = rowbase + w * 32 + mf * 16 + g * 4 + r;
        int col = colbase + nf * 16 + li;
        u16 vv = f2bf(acc[mf][nf][r]);
        if (TRANS) C[(size_t)col * ldc + row] = vv;
        else       C[(size_t)row * ldc + col] = vv;
      }
}

// ---------------- MFMA flash attention: one (draft block n, head h) per workgroup ----------------
__global__ __launch_bounds__(256) void attn_mfma(const u16* __restrict__ qb,
                                                 const u16* __restrict__ kb,
                                                 const u16* __restrict__ vT,
                                                 const int* __restrict__ anchors,
                                                 const unsigned char* __restrict__ keep,
                                                 u16* __restrict__ attnb){
  int n = blockIdx.x, h = blockIdx.y;
  int t = threadIdx.x, w = t >> 6, lane = t & 63;
  int g = lane >> 4, li = lane & 15;

  __shared__ __align__(16) u16 q_s[16][72];
  __shared__ __align__(16) u16 p_s[4][16][72];
  __shared__ float o_s[4][16][64];
  __shared__ float ml_s[4][2][16];

  // stage Q tile (16 x 64)
  {
    int r = t >> 4, c4 = (t & 15) * 4;
    *(usv4*)&q_s[r][c4] = *(const usv4*)&qb[(size_t)(n * 16 + r) * DMODEL + h * 64 + c4];
  }
  __syncthreads();

  int anchor = anchors[n];
  bool kp = keep[n] != 0;
  const u16* kh  = kb + h * 64;
  const u16* vTh = vT + (size_t)(h * 64) * KVLEN;

  if (!kp){
    if (w == 0){
      float acc = 0.f;
      const u16* row = vTh + (size_t)lane * KVLEN;
      for (int k2 = 0; k2 < KVLEN; k2 += 8){
        short8 vv = *(const short8*)&row[k2];
        #pragma unroll
        for (int j = 0; j < 8; j++) acc += bf2f((u16)vv[j]);
      }
      acc *= (1.f / 4096.f);
      u16 ov = f2bf(acc);
      for (int r = 0; r < 16; r++)
        attnb[(size_t)(n * 16 + r) * DMODEL + h * 64 + lane] = ov;
    }
    return;
  }

  short8 qa[2];
  #pragma unroll
  for (int ks = 0; ks < 2; ks++)
    qa[ks] = *(const short8*)&q_s[li][ks * 32 + g * 8];

  int nctx = (anchor + 63) >> 6;
  int ntot = nctx + 1;

  f32x4 o_acc[4];
  float m[4], l[4];
  #pragma unroll
  for (int i = 0; i < 4; i++){ o_acc[i] = (f32x4){0.f,0.f,0.f,0.f}; m[i] = -3e38f; l[i] = 0.f; }

  for (int c = w; c < ntot; c += 4){
    bool draft = (c == nctx);
    int kbase = draft ? (S_LEN + n * 16) : c * 64;
    int nk    = draft ? 16 : min(64, anchor - c * 64);

    f32x4 s[4];
    #pragma unroll
    for (int nf = 0; nf < 4; nf++) s[nf] = (f32x4){0.f,0.f,0.f,0.f};
    #pragma unroll
    for (int ks = 0; ks < 2; ks++){
      #pragma unroll
      for (int nf = 0; nf < 4; nf++){
        int krow = min(kbase + nf * 16 + li, KVLEN - 1);
        short8 bfrag = *(const short8*)&kh[(size_t)krow * DMODEL + ks * 32 + g * 8];
        s[nf] = __builtin_amdgcn_mfma_f32_16x16x32_bf16(qa[ks], bfrag, s[nf], 0, 0, 0);
      }
    }

    #pragma unroll
    for (int r = 0; r < 4; r++){
      float mx = -3e38f;
      #pragma unroll
      for (int nf = 0; nf < 4; nf++){
        float sv = s[nf][r] * 0.125f;
        if (nf * 16 + li >= nk) sv = -3e38f;
        s[nf][r] = sv;
        mx = fmaxf(mx, sv);
      }
      #pragma unroll
      for (int mm = 1; mm < 16; mm <<= 1) mx = fmaxf(mx, __shfl_xor(mx, mm));
      float mn = fmaxf(m[r], mx);
      float sc = __expf(m[r] - mn);
      float ps = 0.f;
      #pragma unroll
      for (int nf = 0; nf < 4; nf++){
        float p = __expf(s[nf][r] - mn);
        ps += p;
        p_s[w][g * 4 + r][nf * 16 + li] = f2bf(p);
      }
      #pragma unroll
      for (int mm = 1; mm < 16; mm <<= 1) ps += __shfl_xor(ps, mm);
      l[r] = l[r] * sc + ps;
      m[r] = mn;
      #pragma unroll
      for (int nfd = 0; nfd < 4; nfd++) o_acc[nfd][r] *= sc;
    }

    #pragma unroll
    for (int ks = 0; ks < 2; ks++){
      short8 pa = *(const short8*)&p_s[w][li][ks * 32 + g * 8];
      int kcol = min(kbase + ks * 32 + g * 8, KVLEN - 8);
      #pragma unroll
      for (int nfd = 0; nfd < 4; nfd++){
        short8 vfrag = *(const short8*)&vTh[(size_t)(nfd * 16 + li) * KVLEN + kcol];
        o_acc[nfd] = __builtin_amdgcn_mfma_f32_16x16x32_bf16(pa, vfrag, o_acc[nfd], 0, 0, 0);
      }
    }
  }

  #pragma unroll
  for (int r = 0; r < 4; r++){
    if (li == 0){ ml_s[w][0][g * 4 + r] = m[r]; ml_s[w][1][g * 4 + r] = l[r]; }
    #pragma unroll
    for (int nfd = 0; nfd < 4; nfd++)
      o_s[w][g * 4 + r][nfd * 16 + li] = o_acc[nfd][r];
  }
  __syncthreads();

  {
    int row = t >> 4, c0 = (t & 15) * 4;
    float M = -3e38f;
    #pragma unroll
    for (int ww = 0; ww < 4; ww++) M = fmaxf(M, ml_s[ww][0][row]);
    float L = 0.f, ew[4];
    #pragma unroll
    for (int ww = 0; ww < 4; ww++){
      ew[ww] = __expf(ml_s[ww][0][row] - M);
      L += ml_s[ww][1][row] * ew[ww];
    }
    float inv = 1.f / L;
    #pragma unroll
    for (int j = 0; j < 4; j++){
      float ov = 0.f;
      #pragma unroll
      for (int ww = 0; ww < 4; ww++) ov += o_s[ww][row][c0 + j] * ew[ww];
      attnb[(size_t)(n * 16 + row) * DMODEL + h * 64 + c0 + j] = f2bf(ov * inv);
    }
  }
}

// ---------------- LM head: swapped-operand MFMA GEMM + lane-local softmax stats ----------------
__global__ __launch_bounds__(256) void lm_fused(const u16* __restrict__ obp,
                                                const u16* __restrict__ WT,
                                                const int* __restrict__ input_ids,
                                                const int* __restrict__ anchors,
                                                float* __restrict__ pl,
                                                float* __restrict__ pt, float* __restrict__ pbv,
                                                int* __restrict__ pbi){
  __shared__ __align__(16) u16 AsA[64 * 64];
  __shared__ __align__(16) u16 AsB[64 * 64];
  __shared__ int tcol_s[64];
  int qbase = blockIdx.x * 64;
  int vocabbase = blockIdx.y * 256;
  int t = threadIdx.x, w = t >> 6, lane = t & 63;
  int g = lane >> 4, li = lane & 15;
  int wvbase = vocabbase + w * 64;

  if (t < 64){
    int r = qbase + t; int n = r >> 4, off = r & 15;
    int lab = anchors[n] + off;
    int safe = min(max(lab, 0), S_LEN - 1);
    tcol_s[t] = input_ids[safe];
  }

  const u16* wr0 = WT + (size_t)(wvbase +  0 + li) * DMODEL;
  const u16* wr1 = WT + (size_t)(wvbase + 16 + li) * DMODEL;
  const u16* wr2 = WT + (size_t)(wvbase + 32 + li) * DMODEL;
  const u16* wr3 = WT + (size_t)(wvbase + 48 + li) * DMODEL;

  f32x4 acc[4][4];
  #pragma unroll
  for (int i = 0; i < 4; i++)
    #pragma unroll
    for (int j = 0; j < 4; j++)
      acc[i][j] = (f32x4){0.f, 0.f, 0.f, 0.f};

  int r0 = t >> 3, cg0 = t & 7;
  auto stage = [&](u16* dst, int kb){
    const u16* s0 = &obp[(size_t)(qbase + r0)      * DMODEL + kb + ((cg0 ^ (r0 & 7)) << 3)];
    const u16* s1 = &obp[(size_t)(qbase + 32 + r0) * DMODEL + kb + ((cg0 ^ (r0 & 7)) << 3)];
    __builtin_amdgcn_global_load_lds(GAS(s0), LAS(dst + w * 512), 16, 0, 0);
    __builtin_amdgcn_global_load_lds(GAS(s1), LAS(dst + 2048 + w * 512), 16, 0, 0);
  };

  stage(AsA, 0);
  __syncthreads();
  u16* cur = AsA; u16* nxt = AsB;

  for (int kt = 0; kt < 8; kt++){
    if (kt < 7) stage(nxt, (kt + 1) * 64);
    int kb = kt * 64;
    #pragma unroll
    for (int ks = 0; ks < 2; ks++){
      short8 wf0 = *(const short8*)(wr0 + kb + ks * 32 + g * 8);
      short8 wf1 = *(const short8*)(wr1 + kb + ks * 32 + g * 8);
      short8 wf2 = *(const short8*)(wr2 + kb + ks * 32 + g * 8);
      short8 wf3 = *(const short8*)(wr3 + kb + ks * 32 + g * 8);
      short8 obf[4];
      #pragma unroll
      for (int qf = 0; qf < 4; qf++){
        int row = qf * 16 + li;
        obf[qf] = *(const short8*)&cur[row * 64 + (((ks * 4 + g) ^ (li & 7)) << 3)];
      }
      #pragma unroll
      for (int qf = 0; qf < 4; qf++){
        acc[0][qf] = __builtin_amdgcn_mfma_f32_16x16x32_bf16(wf0, obf[qf], acc[0][qf], 0, 0, 0);
        acc[1][qf] = __builtin_amdgcn_mfma_f32_16x16x32_bf16(wf1, obf[qf], acc[1][qf], 0, 0, 0);
        acc[2][qf] = __builtin_amdgcn_mfma_f32_16x16x32_bf16(wf2, obf[qf], acc[2][qf], 0, 0, 0);
        acc[3][qf] = __builtin_amdgcn_mfma_f32_16x16x32_bf16(wf3, obf[qf], acc[3][qf], 0, 0, 0);
      }
    }
    __syncthreads();
    u16* tmpp = cur; cur = nxt; nxt = tmpp;
  }

  // epilogue: lane-local stats (logits are small; plain sum-exp is safe in f32)
  int split = blockIdx.y * 4 + w;
  #pragma unroll
  for (int qf = 0; qf < 4; qf++){
    int qloc = qf * 16 + li;
    int tc = tcol_s[qloc] - wvbase;
    float se = 0.f, tv = -3e38f, bv = -3e38f; int bi = 0x7fffffff;
    #pragma unroll
    for (int vf = 0; vf < 4; vf++){
      #pragma unroll
      for (int r = 0; r < 4; r++){
        float v = acc[vf][qf][r];
        int pos = vf * 16 + g * 4 + r;
        se += __expf(v);
        if (pos == tc) tv = v;
        if (v > bv){ bv = v; bi = pos; }
      }
    }
    #pragma unroll
    for (int off = 16; off <= 32; off <<= 1){
      se += __shfl_xor(se, off);
      tv = fmaxf(tv, __shfl_xor(tv, off));
      float ob_ = __shfl_xor(bv, off); int oi = __shfl_xor(bi, off);
      if (ob_ > bv || (ob_ == bv && oi < bi)){ bv = ob_; bi = oi; }
    }
    if (g == 0){
      size_t idx = (size_t)(qbase + qloc) * NSPLIT + split;
      pl[idx] = se; pt[idx] = tv; pbv[idx] = bv; pbi[idx] = wvbase + bi;
    }
  }
}

// ---------------- per-row split merge: one wave per row ----------------
__global__ __launch_bounds__(256) void loss_rows(const float* __restrict__ pl,
                                                 const float* __restrict__ pt, const float* __restrict__ pbv,
                                                 const int* __restrict__ pbi,
                                                 const int* __restrict__ input_ids,
                                                 const int* __restrict__ anchors,
                                                 const unsigned char* __restrict__ keep,
                                                 const float* __restrict__ loss_mask,
                                                 float* __restrict__ rowacc){
  int t = threadIdx.x, w = t >> 6, lane = t & 63;
  int row = blockIdx.x * 4 + w;
  float L = 0.f, TV = -3e38f, BV = -3e38f; int BI = 0x7fffffff;
  for (int s = lane; s < NSPLIT; s += 64){
    size_t idx = (size_t)row * NSPLIT + s;
    L += pl[idx];
    TV = fmaxf(TV, pt[idx]);
    float bv_ = pbv[idx]; int bi_ = pbi[idx];
    if (bv_ > BV || (bv_ == BV && bi_ < BI)){ BV = bv_; BI = bi_; }
  }
  #pragma unroll
  for (int mm = 1; mm < 64; mm <<= 1){
    L += __shfl_xor(L, mm);
    TV = fmaxf(TV, __shfl_xor(TV, mm));
    float ob = __shfl_xor(BV, mm); int oi = __shfl_xor(BI, mm);
    if (ob > BV || (ob == BV && oi < BI)){ BV = ob; BI = oi; }
  }
  if (lane == 0){
    int n = row >> 4, off = row & 15;
    int lab = anchors[n] + off;
    int valid = (lab < S_LEN) ? 1 : 0;
    int safe = min(max(lab, 0), S_LEN - 1);
    int tgt = input_ids[safe];
    float wgt = (keep[n] ? 1.f : 0.f) * (valid ? 1.f : 0.f) * ((off > 0) ? 1.f : 0.f) * loss_mask[safe];
    float logp = TV - __logf(L);
    rowacc[row * 3 + 0] = -logp * wgt;
    rowacc[row * 3 + 1] = wgt;
    rowacc[row * 3 + 2] = ((BI == tgt) && (wgt > 0.5f)) ? 1.f : 0.f;
  }
}

// ---------------- final sum over rows ----------------
__global__ __launch_bounds__(256) void final_sum(const float* __restrict__ rowacc, float* __restrict__ out){
  int t = threadIdx.x;
  float a = 0.f, b = 0.f, c = 0.f;
  for (int r = t; r < QLEN; r += 256){
    a += rowacc[r * 3 + 0]; b += rowacc[r * 3 + 1]; c += rowacc[r * 3 + 2];
  }
  __shared__ float sa[256], sb[256], sc_[256];
  sa[t] = a; sb[t] = b; sc_[t] = c;
  __syncthreads();
  for (int s = 128; s >= 1; s >>= 1){
    if (t < s){ sa[t] += sa[t + s]; sb[t] += sb[t + s]; sc_[t] += sc_[t + s]; }
    __syncthreads();
  }
  if (t == 0){
    out[0] = sa[0] / (sb[0] + 1e-6f);
    out[1] = sc_[0] / (sb[0] + 1e-6f);
  }
}

// ---------------- host ----------------
extern "C" void kernel_launch(void* const* d_in, const int* in_sizes, int n_in,
                              void* d_out, int out_size, void* d_ws, size_t ws_size,
                              hipStream_t stream) {
  const int*   input_ids = (const int*)  d_in[0];
  const float* hidden    = (const float*)d_in[1];
  const float* loss_mask = (const float*)d_in[2];
  const int*   anchors   = (const int*)  d_in[3];
  const unsigned char* keep = (const unsigned char*)d_in[4];
  const float* embed     = (const float*)d_in[5];
  const float* Wq        = (const float*)d_in[6];
  const float* Wk        = (const float*)d_in[7];
  const float* Wv        = (const float*)d_in[8];
  const float* Wo        = (const float*)d_in[9];
  const float* Wlm       = (const float*)d_in[10];

  char* ws = (char*)d_ws;
  size_t off = 0;
  auto take = [&](size_t bytes) -> char* {
    char* p = ws + off;
    off += (bytes + 255) & ~(size_t)255;
    return p;
  };
  u16* WqT  = (u16*)take((size_t)512 * 512 * 2);
  u16* WkT  = (u16*)take((size_t)512 * 512 * 2);
  u16* WvT  = (u16*)take((size_t)512 * 512 * 2);
  u16* WoT  = (u16*)take((size_t)512 * 512 * 2);
  u16* WlmT = (u16*)take((size_t)VOCAB * 512 * 2);
  u16* kvb  = (u16*)take((size_t)KVLEN * 512 * 2);
  u16* qb2  = (u16*)take((size_t)QLEN * 512 * 2);
  u16* kb   = (u16*)take((size_t)KVLEN * 512 * 2);
  u16* vTb  = (u16*)take((size_t)512 * KVLEN * 2);
  u16* attnb= (u16*)take((size_t)QLEN * 512 * 2);
  u16* ob   = (u16*)take((size_t)QLEN * 512 * 2);
  float* pl = (float*)take((size_t)QLEN * NSPLIT * 4);
  float* pt = (float*)take((size_t)QLEN * NSPLIT * 4);
  float* pbv= (float*)take((size_t)QLEN * NSPLIT * 4);
  int*   pbi= (int*)  take((size_t)QLEN * NSPLIT * 4);
  float* rowacc = (float*)take((size_t)QLEN * 3 * 4);

  transpose_cast<<<dim3(16, 16),   256, 0, stream>>>(Wq,  WqT,  512, 512);
  transpose_cast<<<dim3(16, 16),   256, 0, stream>>>(Wk,  WkT,  512, 512);
  transpose_cast<<<dim3(16, 16),   256, 0, stream>>>(Wv,  WvT,  512, 512);
  transpose_cast<<<dim3(16, 16),   256, 0, stream>>>(Wo,  WoT,  512, 512);
  transpose_cast<<<dim3(1000, 16), 256, 0, stream>>>(Wlm, WlmT, 512, VOCAB);

  build_kv<<<KVLEN, 128, 0, stream>>>(hidden, embed, input_ids, anchors, keep, kvb);

  gemm128x64<0><<<dim3(32, 8), 256, 0, stream>>>(kvb, WkT, kb,  KVLEN, 512, 512, 512);   // k (4096,512)
  gemm128x64<1><<<dim3(32, 8), 256, 0, stream>>>(kvb, WvT, vTb, KVLEN, 512, 512, KVLEN); // v^T (512,4096)
  gemm128x64<0><<<dim3(16, 8), 256, 0, stream>>>(kvb + (size_t)S_LEN * 512, WqT, qb2, QLEN, 512, 512, 512); // q

  attn_mfma<<<dim3(NBLK, 8), 256, 0, stream>>>(qb2, kb, vTb, anchors, keep, attnb);

  gemm128x64<0><<<dim3(16, 8), 256, 0, stream>>>(attnb, WoT, ob, QLEN, 512, 512, 512);   // o = attn @ Wo

  lm_fused<<<dim3(32, 125), 256, 0, stream>>>(ob, WlmT, input_ids, anchors, pl, pt, pbv, pbi);

  loss_rows<<<512, 256, 0, stream>>>(pl, pt, pbv, pbi, input_ids, anchors, keep, loss_mask, rowacc);

  final_sum<<<1, 256, 0, stream>>>(rowacc, (float*)d_out);
}

// Round 6
// 295.509 us; speedup vs baseline: 9.8393x; 1.0380x over previous
//
#include <hip/hip_runtime.h>

typedef unsigned short u16;
typedef __attribute__((ext_vector_type(4))) float f32x4;
typedef __attribute__((ext_vector_type(8))) short short8;
typedef __attribute__((ext_vector_type(4))) unsigned int uv4;
typedef __attribute__((ext_vector_type(4))) float fv4;
typedef __attribute__((ext_vector_type(4))) unsigned short usv4;

#define S_LEN 2048
#define NBLK 128
#define DMODEL 512
#define VOCAB 32000
#define QLEN 2048
#define KVLEN 4096
#define NSPLIT 500   // 32000 vocab / 64-col wave spans

#define GAS(p) ((const __attribute__((address_space(1))) void*)(const void*)(p))
#define LAS(p) ((__attribute__((address_space(3))) void*)(void*)(p))

__device__ __forceinline__ float bf2f(u16 u){
  union { unsigned int i; float f; } x; x.i = ((unsigned int)u) << 16; return x.f;
}
__device__ __forceinline__ u16 f2bf(float f){
  union { float f; unsigned int i; } x; x.f = f;
  unsigned int r = x.i + 0x7fffu + ((x.i >> 16) & 1u);
  return (u16)(r >> 16);
}

// ---------------- transpose + cast f32(K,N) -> bf16(N,K), 512x512, 4 matrices ----------------
__global__ __launch_bounds__(256) void transpose4(const float* __restrict__ i0, const float* __restrict__ i1,
                                                  const float* __restrict__ i2, const float* __restrict__ i3,
                                                  u16* __restrict__ o0, u16* __restrict__ o1,
                                                  u16* __restrict__ o2, u16* __restrict__ o3){
  const float* in; u16* out;
  switch (blockIdx.z){
    case 0: in = i0; out = o0; break;
    case 1: in = i1; out = o1; break;
    case 2: in = i2; out = o2; break;
    default: in = i3; out = o3; break;
  }
  __shared__ float tile[32][33];
  int t = threadIdx.x, tx = t & 31, ty = t >> 5;
  int nb = blockIdx.x * 32, kb = blockIdx.y * 32;
  #pragma unroll
  for (int i = 0; i < 4; i++){
    int r = ty + i * 8;
    tile[r][tx] = in[(size_t)(kb + r) * 512 + nb + tx];
  }
  __syncthreads();
  #pragma unroll
  for (int i = 0; i < 4; i++){
    int r = ty + i * 8;
    out[(size_t)(nb + r) * 512 + kb + tx] = f2bf(tile[tx][r]);
  }
}

// ---------------- transpose + cast f32(K,N) -> bf16(N,K), generic (for W_lm) ----------------
__global__ __launch_bounds__(256) void transpose_cast(const float* __restrict__ in,
                                                      u16* __restrict__ out,
                                                      int K, int N){
  __shared__ float tile[32][33];
  int t = threadIdx.x, tx = t & 31, ty = t >> 5;
  int nb = blockIdx.x * 32, kb = blockIdx.y * 32;
  #pragma unroll
  for (int i = 0; i < 4; i++){
    int r = ty + i * 8;
    tile[r][tx] = in[(size_t)(kb + r) * N + nb + tx];
  }
  __syncthreads();
  #pragma unroll
  for (int i = 0; i < 4; i++){
    int r = ty + i * 8;
    out[(size_t)(nb + r) * K + kb + tx] = f2bf(tile[tx][r]);
  }
}

// ---------------- build kv_in (bf16 4096x512): [hidden ; noise_embedding] ----------------
__global__ __launch_bounds__(128) void build_kv(const float* __restrict__ hidden,
                                                const float* __restrict__ embed,
                                                const int* __restrict__ input_ids,
                                                const int* __restrict__ anchors,
                                                const unsigned char* __restrict__ keep,
                                                u16* __restrict__ kvb){
  int row = blockIdx.x;           // 0..4095
  int t = threadIdx.x;            // 0..127
  const float* src;
  if (row < S_LEN){
    src = hidden + (size_t)row * DMODEL;
  } else {
    int q = row - S_LEN;
    int id = 3;                   // MASK_TOKEN_ID
    if ((q & 15) == 0){
      int n = q >> 4;
      if (keep[n]){
        int a = anchors[n]; a = min(max(a, 0), S_LEN - 1);
        id = input_ids[a];
      }
    }
    src = embed + (size_t)id * DMODEL;
  }
  int c = t * 4;
  fv4 v = *(const fv4*)&src[c];
  usv4 o; o[0] = f2bf(v[0]); o[1] = f2bf(v[1]); o[2] = f2bf(v[2]); o[3] = f2bf(v[3]);
  *(usv4*)&kvb[(size_t)row * DMODEL + c] = o;
}

// ---------------- projection GEMM: (64*MF)x64 tile, gload_lds staged, XOR-swizzled, dbuf ----------------
// C[M,N] = A[M,K] * B[K,N], B given transposed (N,K). 4 waves; wave w owns rows w*(16*MF)..+16*MF.
template<int TRANS, int MF>
__global__ __launch_bounds__(256) void gemmTile(const u16* __restrict__ A,
                                                const u16* __restrict__ BT,
                                                u16* __restrict__ C,
                                                int M, int N, int K, int ldc){
  __shared__ __align__(16) u16 As[2][64 * MF * 64];
  __shared__ __align__(16) u16 Bs[2][64 * 64];
  int t = threadIdx.x, w = t >> 6, lane = t & 63;
  int g = lane >> 4, li = lane & 15;
  int rowbase = blockIdx.x * (64 * MF), colbase = blockIdx.y * 64;
  int r0 = t >> 3, cg0 = t & 7;
  int swz = (cg0 ^ (r0 & 7)) << 3;   // pre-swizzled source col so linear LDS dest = swizzled layout

  auto stageA = [&](u16* dst, int kb){
    #pragma unroll
    for (int i = 0; i < 2 * MF; i++)
      __builtin_amdgcn_global_load_lds(GAS(&A[(size_t)(rowbase + r0 + i * 32) * K + kb + swz]),
                                       LAS(dst + i * 2048 + w * 512), 16, 0, 0);
  };
  auto stageB = [&](u16* dst, int kb){
    #pragma unroll
    for (int i = 0; i < 2; i++)
      __builtin_amdgcn_global_load_lds(GAS(&BT[(size_t)(colbase + r0 + i * 32) * K + kb + swz]),
                                       LAS(dst + i * 2048 + w * 512), 16, 0, 0);
  };

  f32x4 acc[MF][4];
  #pragma unroll
  for (int i = 0; i < MF; i++)
    #pragma unroll
    for (int j = 0; j < 4; j++)
      acc[i][j] = (f32x4){0.f, 0.f, 0.f, 0.f};

  stageA(As[0], 0); stageB(Bs[0], 0);
  __syncthreads();

  int nkt = K >> 6;
  for (int kt = 0; kt < nkt; kt++){
    u16* curA = As[kt & 1]; u16* curB = Bs[kt & 1];
    if (kt + 1 < nkt){ stageA(As[(kt + 1) & 1], (kt + 1) * 64); stageB(Bs[(kt + 1) & 1], (kt + 1) * 64); }
    #pragma unroll
    for (int ks = 0; ks < 2; ks++){
      short8 af[MF], bf[4];
      #pragma unroll
      for (int mf = 0; mf < MF; mf++){
        int row = w * 16 * MF + mf * 16 + li;
        af[mf] = *(const short8*)&curA[row * 64 + (((ks * 4 + g) ^ (li & 7)) << 3)];
      }
      #pragma unroll
      for (int nf = 0; nf < 4; nf++){
        int row = nf * 16 + li;
        bf[nf] = *(const short8*)&curB[row * 64 + (((ks * 4 + g) ^ (li & 7)) << 3)];
      }
      #pragma unroll
      for (int mf = 0; mf < MF; mf++)
        #pragma unroll
        for (int nf = 0; nf < 4; nf++)
          acc[mf][nf] = __builtin_amdgcn_mfma_f32_16x16x32_bf16(af[mf], bf[nf], acc[mf][nf], 0, 0, 0);
    }
    __syncthreads();
  }

  #pragma unroll
  for (int mf = 0; mf < MF; mf++)
    #pragma unroll
    for (int nf = 0; nf < 4; nf++)
      #pragma unroll
      for (int r = 0; r < 4; r++){
        int row = rowbase + w * 16 * MF + mf * 16 + g * 4 + r;
        int col = colbase + nf * 16 + li;
        u16 vv = f2bf(acc[mf][nf][r]);
        if (TRANS) C[(size_t)col * ldc + row] = vv;
        else       C[(size_t)row * ldc + col] = vv;
      }
}

// ---------------- MFMA flash attention: one (draft block n, head h) per workgroup ----------------
__global__ __launch_bounds__(256) void attn_mfma(const u16* __restrict__ qb,
                                                 const u16* __restrict__ kb,
                                                 const u16* __restrict__ vT,
                                                 const int* __restrict__ anchors,
                                                 const unsigned char* __restrict__ keep,
                                                 u16* __restrict__ attnb){
  int n = blockIdx.x, h = blockIdx.y;
  int t = threadIdx.x, w = t >> 6, lane = t & 63;
  int g = lane >> 4, li = lane & 15;

  __shared__ __align__(16) u16 q_s[16][72];
  __shared__ __align__(16) u16 p_s[4][16][72];
  __shared__ float o_s[4][16][64];
  __shared__ float ml_s[4][2][16];

  // stage Q tile (16 x 64)
  {
    int r = t >> 4, c4 = (t & 15) * 4;
    *(usv4*)&q_s[r][c4] = *(const usv4*)&qb[(size_t)(n * 16 + r) * DMODEL + h * 64 + c4];
  }
  __syncthreads();

  int anchor = anchors[n];
  bool kp = keep[n] != 0;
  const u16* kh  = kb + h * 64;
  const u16* vTh = vT + (size_t)(h * 64) * KVLEN;

  if (!kp){
    if (w == 0){
      float acc = 0.f;
      const u16* row = vTh + (size_t)lane * KVLEN;
      for (int k2 = 0; k2 < KVLEN; k2 += 8){
        short8 vv = *(const short8*)&row[k2];
        #pragma unroll
        for (int j = 0; j < 8; j++) acc += bf2f((u16)vv[j]);
      }
      acc *= (1.f / 4096.f);
      u16 ov = f2bf(acc);
      for (int r = 0; r < 16; r++)
        attnb[(size_t)(n * 16 + r) * DMODEL + h * 64 + lane] = ov;
    }
    return;
  }

  short8 qa[2];
  #pragma unroll
  for (int ks = 0; ks < 2; ks++)
    qa[ks] = *(const short8*)&q_s[li][ks * 32 + g * 8];

  int nctx = (anchor + 63) >> 6;
  int ntot = nctx + 1;

  f32x4 o_acc[4];
  float m[4], l[4];
  #pragma unroll
  for (int i = 0; i < 4; i++){ o_acc[i] = (f32x4){0.f,0.f,0.f,0.f}; m[i] = -3e38f; l[i] = 0.f; }

  for (int c = w; c < ntot; c += 4){
    bool draft = (c == nctx);
    int kbase = draft ? (S_LEN + n * 16) : c * 64;
    int nk    = draft ? 16 : min(64, anchor - c * 64);

    f32x4 s[4];
    #pragma unroll
    for (int nf = 0; nf < 4; nf++) s[nf] = (f32x4){0.f,0.f,0.f,0.f};
    #pragma unroll
    for (int ks = 0; ks < 2; ks++){
      #pragma unroll
      for (int nf = 0; nf < 4; nf++){
        int krow = min(kbase + nf * 16 + li, KVLEN - 1);
        short8 bfrag = *(const short8*)&kh[(size_t)krow * DMODEL + ks * 32 + g * 8];
        s[nf] = __builtin_amdgcn_mfma_f32_16x16x32_bf16(qa[ks], bfrag, s[nf], 0, 0, 0);
      }
    }

    #pragma unroll
    for (int r = 0; r < 4; r++){
      float mx = -3e38f;
      #pragma unroll
      for (int nf = 0; nf < 4; nf++){
        float sv = s[nf][r] * 0.125f;
        if (nf * 16 + li >= nk) sv = -3e38f;
        s[nf][r] = sv;
        mx = fmaxf(mx, sv);
      }
      #pragma unroll
      for (int mm = 1; mm < 16; mm <<= 1) mx = fmaxf(mx, __shfl_xor(mx, mm));
      float mn = fmaxf(m[r], mx);
      float sc = __expf(m[r] - mn);
      float ps = 0.f;
      #pragma unroll
      for (int nf = 0; nf < 4; nf++){
        float p = __expf(s[nf][r] - mn);
        ps += p;
        p_s[w][g * 4 + r][nf * 16 + li] = f2bf(p);
      }
      #pragma unroll
      for (int mm = 1; mm < 16; mm <<= 1) ps += __shfl_xor(ps, mm);
      l[r] = l[r] * sc + ps;
      m[r] = mn;
      #pragma unroll
      for (int nfd = 0; nfd < 4; nfd++) o_acc[nfd][r] *= sc;
    }

    #pragma unroll
    for (int ks = 0; ks < 2; ks++){
      short8 pa = *(const short8*)&p_s[w][li][ks * 32 + g * 8];
      int kcol = min(kbase + ks * 32 + g * 8, KVLEN - 8);
      #pragma unroll
      for (int nfd = 0; nfd < 4; nfd++){
        short8 vfrag = *(const short8*)&vTh[(size_t)(nfd * 16 + li) * KVLEN + kcol];
        o_acc[nfd] = __builtin_amdgcn_mfma_f32_16x16x32_bf16(pa, vfrag, o_acc[nfd], 0, 0, 0);
      }
    }
  }

  #pragma unroll
  for (int r = 0; r < 4; r++){
    if (li == 0){ ml_s[w][0][g * 4 + r] = m[r]; ml_s[w][1][g * 4 + r] = l[r]; }
    #pragma unroll
    for (int nfd = 0; nfd < 4; nfd++)
      o_s[w][g * 4 + r][nfd * 16 + li] = o_acc[nfd][r];
  }
  __syncthreads();

  {
    int row = t >> 4, c0 = (t & 15) * 4;
    float M = -3e38f;
    #pragma unroll
    for (int ww = 0; ww < 4; ww++) M = fmaxf(M, ml_s[ww][0][row]);
    float L = 0.f, ew[4];
    #pragma unroll
    for (int ww = 0; ww < 4; ww++){
      ew[ww] = __expf(ml_s[ww][0][row] - M);
      L += ml_s[ww][1][row] * ew[ww];
    }
    float inv = 1.f / L;
    #pragma unroll
    for (int j = 0; j < 4; j++){
      float ov = 0.f;
      #pragma unroll
      for (int ww = 0; ww < 4; ww++) ov += o_s[ww][row][c0 + j] * ew[ww];
      attnb[(size_t)(n * 16 + row) * DMODEL + h * 64 + c0 + j] = f2bf(ov * inv);
    }
  }
}

// ---------------- LM head: swapped-operand MFMA GEMM + lane-local softmax stats ----------------
// XCD-aware 1-D grid (4000 blocks): T = (L%8)*500 + L/8, decomposed y-major so each
// XCD owns a contiguous vocab range -> W slice fetched into ONE XCD's L2 only.
__global__ __launch_bounds__(256) void lm_fused(const u16* __restrict__ obp,
                                                const u16* __restrict__ WT,
                                                const int* __restrict__ input_ids,
                                                const int* __restrict__ anchors,
                                                float* __restrict__ pl,
                                                float* __restrict__ pt, float* __restrict__ pbv,
                                                int* __restrict__ pbi){
  __shared__ __align__(16) u16 AsA[64 * 64];
  __shared__ __align__(16) u16 AsB[64 * 64];
  __shared__ int tcol_s[64];
  int L = blockIdx.x;                       // 0..3999
  int T = (L & 7) * 500 + (L >> 3);         // bijective (4000 % 8 == 0)
  int qbase = (T & 31) * 64;                // x fastest within an XCD's T-range
  int vocabbase = (T >> 5) * 256;           // y contiguous per XCD
  int t = threadIdx.x, w = t >> 6, lane = t & 63;
  int g = lane >> 4, li = lane & 15;
  int wvbase = vocabbase + w * 64;

  if (t < 64){
    int r = qbase + t; int n = r >> 4, off = r & 15;
    int lab = anchors[n] + off;
    int safe = min(max(lab, 0), S_LEN - 1);
    tcol_s[t] = input_ids[safe];
  }

  const u16* wr0 = WT + (size_t)(wvbase +  0 + li) * DMODEL;
  const u16* wr1 = WT + (size_t)(wvbase + 16 + li) * DMODEL;
  const u16* wr2 = WT + (size_t)(wvbase + 32 + li) * DMODEL;
  const u16* wr3 = WT + (size_t)(wvbase + 48 + li) * DMODEL;

  f32x4 acc[4][4];
  #pragma unroll
  for (int i = 0; i < 4; i++)
    #pragma unroll
    for (int j = 0; j < 4; j++)
      acc[i][j] = (f32x4){0.f, 0.f, 0.f, 0.f};

  int r0 = t >> 3, cg0 = t & 7;
  auto stage = [&](u16* dst, int kb){
    const u16* s0 = &obp[(size_t)(qbase + r0)      * DMODEL + kb + ((cg0 ^ (r0 & 7)) << 3)];
    const u16* s1 = &obp[(size_t)(qbase + 32 + r0) * DMODEL + kb + ((cg0 ^ (r0 & 7)) << 3)];
    __builtin_amdgcn_global_load_lds(GAS(s0), LAS(dst + w * 512), 16, 0, 0);
    __builtin_amdgcn_global_load_lds(GAS(s1), LAS(dst + 2048 + w * 512), 16, 0, 0);
  };

  stage(AsA, 0);
  __syncthreads();
  u16* cur = AsA; u16* nxt = AsB;

  for (int kt = 0; kt < 8; kt++){
    if (kt < 7) stage(nxt, (kt + 1) * 64);
    int kb = kt * 64;
    #pragma unroll
    for (int ks = 0; ks < 2; ks++){
      short8 wf0 = *(const short8*)(wr0 + kb + ks * 32 + g * 8);
      short8 wf1 = *(const short8*)(wr1 + kb + ks * 32 + g * 8);
      short8 wf2 = *(const short8*)(wr2 + kb + ks * 32 + g * 8);
      short8 wf3 = *(const short8*)(wr3 + kb + ks * 32 + g * 8);
      short8 obf[4];
      #pragma unroll
      for (int qf = 0; qf < 4; qf++){
        int row = qf * 16 + li;
        obf[qf] = *(const short8*)&cur[row * 64 + (((ks * 4 + g) ^ (li & 7)) << 3)];
      }
      #pragma unroll
      for (int qf = 0; qf < 4; qf++){
        acc[0][qf] = __builtin_amdgcn_mfma_f32_16x16x32_bf16(wf0, obf[qf], acc[0][qf], 0, 0, 0);
        acc[1][qf] = __builtin_amdgcn_mfma_f32_16x16x32_bf16(wf1, obf[qf], acc[1][qf], 0, 0, 0);
        acc[2][qf] = __builtin_amdgcn_mfma_f32_16x16x32_bf16(wf2, obf[qf], acc[2][qf], 0, 0, 0);
        acc[3][qf] = __builtin_amdgcn_mfma_f32_16x16x32_bf16(wf3, obf[qf], acc[3][qf], 0, 0, 0);
      }
    }
    __syncthreads();
    u16* tmpp = cur; cur = nxt; nxt = tmpp;
  }

  // epilogue: lane-local stats (logits are small; plain sum-exp is safe in f32)
  int split = (T >> 5) * 4 + w;
  #pragma unroll
  for (int qf = 0; qf < 4; qf++){
    int qloc = qf * 16 + li;
    int tc = tcol_s[qloc] - wvbase;
    float se = 0.f, tv = -3e38f, bv = -3e38f; int bi = 0x7fffffff;
    #pragma unroll
    for (int vf = 0; vf < 4; vf++){
      #pragma unroll
      for (int r = 0; r < 4; r++){
        float v = acc[vf][qf][r];
        int pos = vf * 16 + g * 4 + r;
        se += __expf(v);
        if (pos == tc) tv = v;
        if (v > bv){ bv = v; bi = pos; }
      }
    }
    #pragma unroll
    for (int off = 16; off <= 32; off <<= 1){
      se += __shfl_xor(se, off);
      tv = fmaxf(tv, __shfl_xor(tv, off));
      float ob_ = __shfl_xor(bv, off); int oi = __shfl_xor(bi, off);
      if (ob_ > bv || (ob_ == bv && oi < bi)){ bv = ob_; bi = oi; }
    }
    if (g == 0){
      size_t idx = (size_t)(qbase + qloc) * NSPLIT + split;
      pl[idx] = se; pt[idx] = tv; pbv[idx] = bv; pbi[idx] = wvbase + bi;
    }
  }
}

// ---------------- per-row split merge: one wave per row ----------------
__global__ __launch_bounds__(256) void loss_rows(const float* __restrict__ pl,
                                                 const float* __restrict__ pt, const float* __restrict__ pbv,
                                                 const int* __restrict__ pbi,
                                                 const int* __restrict__ input_ids,
                                                 const int* __restrict__ anchors,
                                                 const unsigned char* __restrict__ keep,
                                                 const float* __restrict__ loss_mask,
                                                 float* __restrict__ rowacc){
  int t = threadIdx.x, w = t >> 6, lane = t & 63;
  int row = blockIdx.x * 4 + w;
  float L = 0.f, TV = -3e38f, BV = -3e38f; int BI = 0x7fffffff;
  for (int s = lane; s < NSPLIT; s += 64){
    size_t idx = (size_t)row * NSPLIT + s;
    L += pl[idx];
    TV = fmaxf(TV, pt[idx]);
    float bv_ = pbv[idx]; int bi_ = pbi[idx];
    if (bv_ > BV || (bv_ == BV && bi_ < BI)){ BV = bv_; BI = bi_; }
  }
  #pragma unroll
  for (int mm = 1; mm < 64; mm <<= 1){
    L += __shfl_xor(L, mm);
    TV = fmaxf(TV, __shfl_xor(TV, mm));
    float ob = __shfl_xor(BV, mm); int oi = __shfl_xor(BI, mm);
    if (ob > BV || (ob == BV && oi < BI)){ BV = ob; BI = oi; }
  }
  if (lane == 0){
    int n = row >> 4, off = row & 15;
    int lab = anchors[n] + off;
    int valid = (lab < S_LEN) ? 1 : 0;
    int safe = min(max(lab, 0), S_LEN - 1);
    int tgt = input_ids[safe];
    float wgt = (keep[n] ? 1.f : 0.f) * (valid ? 1.f : 0.f) * ((off > 0) ? 1.f : 0.f) * loss_mask[safe];
    float logp = TV - __logf(L);
    rowacc[row * 3 + 0] = -logp * wgt;
    rowacc[row * 3 + 1] = wgt;
    rowacc[row * 3 + 2] = ((BI == tgt) && (wgt > 0.5f)) ? 1.f : 0.f;
  }
}

// ---------------- final sum over rows ----------------
__global__ __launch_bounds__(256) void final_sum(const float* __restrict__ rowacc, float* __restrict__ out){
  int t = threadIdx.x;
  float a = 0.f, b = 0.f, c = 0.f;
  for (int r = t; r < QLEN; r += 256){
    a += rowacc[r * 3 + 0]; b += rowacc[r * 3 + 1]; c += rowacc[r * 3 + 2];
  }
  __shared__ float sa[256], sb[256], sc_[256];
  sa[t] = a; sb[t] = b; sc_[t] = c;
  __syncthreads();
  for (int s = 128; s >= 1; s >>= 1){
    if (t < s){ sa[t] += sa[t + s]; sb[t] += sb[t + s]; sc_[t] += sc_[t + s]; }
    __syncthreads();
  }
  if (t == 0){
    out[0] = sa[0] / (sb[0] + 1e-6f);
    out[1] = sc_[0] / (sb[0] + 1e-6f);
  }
}

// ---------------- host ----------------
extern "C" void kernel_launch(void* const* d_in, const int* in_sizes, int n_in,
                              void* d_out, int out_size, void* d_ws, size_t ws_size,
                              hipStream_t stream) {
  const int*   input_ids = (const int*)  d_in[0];
  const float* hidden    = (const float*)d_in[1];
  const float* loss_mask = (const float*)d_in[2];
  const int*   anchors   = (const int*)  d_in[3];
  const unsigned char* keep = (const unsigned char*)d_in[4];
  const float* embed     = (const float*)d_in[5];
  const float* Wq        = (const float*)d_in[6];
  const float* Wk        = (const float*)d_in[7];
  const float* Wv        = (const float*)d_in[8];
  const float* Wo        = (const float*)d_in[9];
  const float* Wlm       = (const float*)d_in[10];

  char* ws = (char*)d_ws;
  size_t off = 0;
  auto take = [&](size_t bytes) -> char* {
    char* p = ws + off;
    off += (bytes + 255) & ~(size_t)255;
    return p;
  };
  u16* WqT  = (u16*)take((size_t)512 * 512 * 2);
  u16* WkT  = (u16*)take((size_t)512 * 512 * 2);
  u16* WvT  = (u16*)take((size_t)512 * 512 * 2);
  u16* WoT  = (u16*)take((size_t)512 * 512 * 2);
  u16* WlmT = (u16*)take((size_t)VOCAB * 512 * 2);
  u16* kvb  = (u16*)take((size_t)KVLEN * 512 * 2);
  u16* qb2  = (u16*)take((size_t)QLEN * 512 * 2);
  u16* kb   = (u16*)take((size_t)KVLEN * 512 * 2);
  u16* vTb  = (u16*)take((size_t)512 * KVLEN * 2);
  u16* attnb= (u16*)take((size_t)QLEN * 512 * 2);
  u16* ob   = (u16*)take((size_t)QLEN * 512 * 2);
  float* pl = (float*)take((size_t)QLEN * NSPLIT * 4);
  float* pt = (float*)take((size_t)QLEN * NSPLIT * 4);
  float* pbv= (float*)take((size_t)QLEN * NSPLIT * 4);
  int*   pbi= (int*)  take((size_t)QLEN * NSPLIT * 4);
  float* rowacc = (float*)take((size_t)QLEN * 3 * 4);

  transpose4<<<dim3(16, 16, 4), 256, 0, stream>>>(Wq, Wk, Wv, Wo, WqT, WkT, WvT, WoT);
  transpose_cast<<<dim3(1000, 16), 256, 0, stream>>>(Wlm, WlmT, 512, VOCAB);

  build_kv<<<KVLEN, 128, 0, stream>>>(hidden, embed, input_ids, anchors, keep, kvb);

  gemmTile<0, 2><<<dim3(32, 8), 256, 0, stream>>>(kvb, WkT, kb,  KVLEN, 512, 512, 512);   // k (4096,512)
  gemmTile<1, 2><<<dim3(32, 8), 256, 0, stream>>>(kvb, WvT, vTb, KVLEN, 512, 512, KVLEN); // v^T (512,4096)
  gemmTile<0, 1><<<dim3(32, 8), 256, 0, stream>>>(kvb + (size_t)S_LEN * 512, WqT, qb2, QLEN, 512, 512, 512); // q

  attn_mfma<<<dim3(NBLK, 8), 256, 0, stream>>>(qb2, kb, vTb, anchors, keep, attnb);

  gemmTile<0, 1><<<dim3(32, 8), 256, 0, stream>>>(attnb, WoT, ob, QLEN, 512, 512, 512);   // o = attn @ Wo

  lm_fused<<<4000, 256, 0, stream>>>(ob, WlmT, input_ids, anchors, pl, pt, pbv, pbi);

  loss_rows<<<512, 256, 0, stream>>>(pl, pt, pbv, pbi, input_ids, anchors, keep, loss_mask, rowacc);

  final_sum<<<1, 256, 0, stream>>>(rowacc, (float*)d_out);
}

// Round 7
// 250.356 us; speedup vs baseline: 11.6138x; 1.1804x over previous
//
#include <hip/hip_runtime.h>

typedef unsigned short u16;
typedef __attribute__((ext_vector_type(4))) float f32x4;
typedef __attribute__((ext_vector_type(8))) short short8;
typedef __attribute__((ext_vector_type(4))) unsigned int uv4;
typedef __attribute__((ext_vector_type(4))) float fv4;
typedef __attribute__((ext_vector_type(4))) unsigned short usv4;

#define S_LEN 2048
#define NBLK 128
#define DMODEL 512
#define VOCAB 32000
#define QLEN 2048
#define KVLEN 4096
#define NSPLIT 250   // 32000 vocab / 128-vocab blocks

#define GAS(p) ((const __attribute__((address_space(1))) void*)(const void*)(p))
#define LAS(p) ((__attribute__((address_space(3))) void*)(void*)(p))

__device__ __forceinline__ float bf2f(u16 u){
  union { unsigned int i; float f; } x; x.i = ((unsigned int)u) << 16; return x.f;
}
__device__ __forceinline__ u16 f2bf(float f){
  union { float f; unsigned int i; } x; x.f = f;
  unsigned int r = x.i + 0x7fffu + ((x.i >> 16) & 1u);
  return (u16)(r >> 16);
}

// ---------------- transpose + cast f32(K,N) -> bf16(N,K), 512x512, 4 matrices ----------------
__global__ __launch_bounds__(256) void transpose4(const float* __restrict__ i0, const float* __restrict__ i1,
                                                  const float* __restrict__ i2, const float* __restrict__ i3,
                                                  u16* __restrict__ o0, u16* __restrict__ o1,
                                                  u16* __restrict__ o2, u16* __restrict__ o3){
  const float* in; u16* out;
  switch (blockIdx.z){
    case 0: in = i0; out = o0; break;
    case 1: in = i1; out = o1; break;
    case 2: in = i2; out = o2; break;
    default: in = i3; out = o3; break;
  }
  __shared__ float tile[32][33];
  int t = threadIdx.x, tx = t & 31, ty = t >> 5;
  int nb = blockIdx.x * 32, kb = blockIdx.y * 32;
  #pragma unroll
  for (int i = 0; i < 4; i++){
    int r = ty + i * 8;
    tile[r][tx] = in[(size_t)(kb + r) * 512 + nb + tx];
  }
  __syncthreads();
  #pragma unroll
  for (int i = 0; i < 4; i++){
    int r = ty + i * 8;
    out[(size_t)(nb + r) * 512 + kb + tx] = f2bf(tile[tx][r]);
  }
}

// ---------------- transpose + cast f32(K,N) -> bf16(N,K), generic (for W_lm) ----------------
__global__ __launch_bounds__(256) void transpose_cast(const float* __restrict__ in,
                                                      u16* __restrict__ out,
                                                      int K, int N){
  __shared__ float tile[32][33];
  int t = threadIdx.x, tx = t & 31, ty = t >> 5;
  int nb = blockIdx.x * 32, kb = blockIdx.y * 32;
  #pragma unroll
  for (int i = 0; i < 4; i++){
    int r = ty + i * 8;
    tile[r][tx] = in[(size_t)(kb + r) * N + nb + tx];
  }
  __syncthreads();
  #pragma unroll
  for (int i = 0; i < 4; i++){
    int r = ty + i * 8;
    out[(size_t)(nb + r) * K + kb + tx] = f2bf(tile[tx][r]);
  }
}

// ---------------- build kv_in (bf16 4096x512): [hidden ; noise_embedding] ----------------
__global__ __launch_bounds__(128) void build_kv(const float* __restrict__ hidden,
                                                const float* __restrict__ embed,
                                                const int* __restrict__ input_ids,
                                                const int* __restrict__ anchors,
                                                const unsigned char* __restrict__ keep,
                                                u16* __restrict__ kvb){
  int row = blockIdx.x;           // 0..4095
  int t = threadIdx.x;            // 0..127
  const float* src;
  if (row < S_LEN){
    src = hidden + (size_t)row * DMODEL;
  } else {
    int q = row - S_LEN;
    int id = 3;                   // MASK_TOKEN_ID
    if ((q & 15) == 0){
      int n = q >> 4;
      if (keep[n]){
        int a = anchors[n]; a = min(max(a, 0), S_LEN - 1);
        id = input_ids[a];
      }
    }
    src = embed + (size_t)id * DMODEL;
  }
  int c = t * 4;
  fv4 v = *(const fv4*)&src[c];
  usv4 o; o[0] = f2bf(v[0]); o[1] = f2bf(v[1]); o[2] = f2bf(v[2]); o[3] = f2bf(v[3]);
  *(usv4*)&kvb[(size_t)row * DMODEL + c] = o;
}

// ---------------- projection GEMM: (64*MF)x64 tile, gload_lds staged, XOR-swizzled, dbuf ----------------
template<int TRANS, int MF>
__global__ __launch_bounds__(256) void gemmTile(const u16* __restrict__ A,
                                                const u16* __restrict__ BT,
                                                u16* __restrict__ C,
                                                int M, int N, int K, int ldc){
  __shared__ __align__(16) u16 As[2][64 * MF * 64];
  __shared__ __align__(16) u16 Bs[2][64 * 64];
  int t = threadIdx.x, w = t >> 6, lane = t & 63;
  int g = lane >> 4, li = lane & 15;
  int rowbase = blockIdx.x * (64 * MF), colbase = blockIdx.y * 64;
  int r0 = t >> 3, cg0 = t & 7;
  int swz = (cg0 ^ (r0 & 7)) << 3;

  auto stageA = [&](u16* dst, int kb){
    #pragma unroll
    for (int i = 0; i < 2 * MF; i++)
      __builtin_amdgcn_global_load_lds(GAS(&A[(size_t)(rowbase + r0 + i * 32) * K + kb + swz]),
                                       LAS(dst + i * 2048 + w * 512), 16, 0, 0);
  };
  auto stageB = [&](u16* dst, int kb){
    #pragma unroll
    for (int i = 0; i < 2; i++)
      __builtin_amdgcn_global_load_lds(GAS(&BT[(size_t)(colbase + r0 + i * 32) * K + kb + swz]),
                                       LAS(dst + i * 2048 + w * 512), 16, 0, 0);
  };

  f32x4 acc[MF][4];
  #pragma unroll
  for (int i = 0; i < MF; i++)
    #pragma unroll
    for (int j = 0; j < 4; j++)
      acc[i][j] = (f32x4){0.f, 0.f, 0.f, 0.f};

  stageA(As[0], 0); stageB(Bs[0], 0);
  __syncthreads();

  int nkt = K >> 6;
  for (int kt = 0; kt < nkt; kt++){
    u16* curA = As[kt & 1]; u16* curB = Bs[kt & 1];
    if (kt + 1 < nkt){ stageA(As[(kt + 1) & 1], (kt + 1) * 64); stageB(Bs[(kt + 1) & 1], (kt + 1) * 64); }
    #pragma unroll
    for (int ks = 0; ks < 2; ks++){
      short8 af[MF], bf[4];
      #pragma unroll
      for (int mf = 0; mf < MF; mf++){
        int row = w * 16 * MF + mf * 16 + li;
        af[mf] = *(const short8*)&curA[row * 64 + (((ks * 4 + g) ^ (li & 7)) << 3)];
      }
      #pragma unroll
      for (int nf = 0; nf < 4; nf++){
        int row = nf * 16 + li;
        bf[nf] = *(const short8*)&curB[row * 64 + (((ks * 4 + g) ^ (li & 7)) << 3)];
      }
      #pragma unroll
      for (int mf = 0; mf < MF; mf++)
        #pragma unroll
        for (int nf = 0; nf < 4; nf++)
          acc[mf][nf] = __builtin_amdgcn_mfma_f32_16x16x32_bf16(af[mf], bf[nf], acc[mf][nf], 0, 0, 0);
    }
    __syncthreads();
  }

  #pragma unroll
  for (int mf = 0; mf < MF; mf++)
    #pragma unroll
    for (int nf = 0; nf < 4; nf++)
      #pragma unroll
      for (int r = 0; r < 4; r++){
        int row = rowbase + w * 16 * MF + mf * 16 + g * 4 + r;
        int col = colbase + nf * 16 + li;
        u16 vv = f2bf(acc[mf][nf][r]);
        if (TRANS) C[(size_t)col * ldc + row] = vv;
        else       C[(size_t)row * ldc + col] = vv;
      }
}

// ---------------- MFMA flash attention: one (draft block n, head h) per workgroup ----------------
__global__ __launch_bounds__(256) void attn_mfma(const u16* __restrict__ qb,
                                                 const u16* __restrict__ kb,
                                                 const u16* __restrict__ vT,
                                                 const int* __restrict__ anchors,
                                                 const unsigned char* __restrict__ keep,
                                                 u16* __restrict__ attnb){
  int n = blockIdx.x, h = blockIdx.y;
  int t = threadIdx.x, w = t >> 6, lane = t & 63;
  int g = lane >> 4, li = lane & 15;

  __shared__ __align__(16) u16 q_s[16][72];
  __shared__ __align__(16) u16 p_s[4][16][72];
  __shared__ float o_s[4][16][64];
  __shared__ float ml_s[4][2][16];

  {
    int r = t >> 4, c4 = (t & 15) * 4;
    *(usv4*)&q_s[r][c4] = *(const usv4*)&qb[(size_t)(n * 16 + r) * DMODEL + h * 64 + c4];
  }
  __syncthreads();

  int anchor = anchors[n];
  bool kp = keep[n] != 0;
  const u16* kh  = kb + h * 64;
  const u16* vTh = vT + (size_t)(h * 64) * KVLEN;

  if (!kp){
    if (w == 0){
      float acc = 0.f;
      const u16* row = vTh + (size_t)lane * KVLEN;
      for (int k2 = 0; k2 < KVLEN; k2 += 8){
        short8 vv = *(const short8*)&row[k2];
        #pragma unroll
        for (int j = 0; j < 8; j++) acc += bf2f((u16)vv[j]);
      }
      acc *= (1.f / 4096.f);
      u16 ov = f2bf(acc);
      for (int r = 0; r < 16; r++)
        attnb[(size_t)(n * 16 + r) * DMODEL + h * 64 + lane] = ov;
    }
    return;
  }

  short8 qa[2];
  #pragma unroll
  for (int ks = 0; ks < 2; ks++)
    qa[ks] = *(const short8*)&q_s[li][ks * 32 + g * 8];

  int nctx = (anchor + 63) >> 6;
  int ntot = nctx + 1;

  f32x4 o_acc[4];
  float m[4], l[4];
  #pragma unroll
  for (int i = 0; i < 4; i++){ o_acc[i] = (f32x4){0.f,0.f,0.f,0.f}; m[i] = -3e38f; l[i] = 0.f; }

  for (int c = w; c < ntot; c += 4){
    bool draft = (c == nctx);
    int kbase = draft ? (S_LEN + n * 16) : c * 64;
    int nk    = draft ? 16 : min(64, anchor - c * 64);

    f32x4 s[4];
    #pragma unroll
    for (int nf = 0; nf < 4; nf++) s[nf] = (f32x4){0.f,0.f,0.f,0.f};
    #pragma unroll
    for (int ks = 0; ks < 2; ks++){
      #pragma unroll
      for (int nf = 0; nf < 4; nf++){
        int krow = min(kbase + nf * 16 + li, KVLEN - 1);
        short8 bfrag = *(const short8*)&kh[(size_t)krow * DMODEL + ks * 32 + g * 8];
        s[nf] = __builtin_amdgcn_mfma_f32_16x16x32_bf16(qa[ks], bfrag, s[nf], 0, 0, 0);
      }
    }

    #pragma unroll
    for (int r = 0; r < 4; r++){
      float mx = -3e38f;
      #pragma unroll
      for (int nf = 0; nf < 4; nf++){
        float sv = s[nf][r] * 0.125f;
        if (nf * 16 + li >= nk) sv = -3e38f;
        s[nf][r] = sv;
        mx = fmaxf(mx, sv);
      }
      #pragma unroll
      for (int mm = 1; mm < 16; mm <<= 1) mx = fmaxf(mx, __shfl_xor(mx, mm));
      float mn = fmaxf(m[r], mx);
      float sc = __expf(m[r] - mn);
      float ps = 0.f;
      #pragma unroll
      for (int nf = 0; nf < 4; nf++){
        float p = __expf(s[nf][r] - mn);
        ps += p;
        p_s[w][g * 4 + r][nf * 16 + li] = f2bf(p);
      }
      #pragma unroll
      for (int mm = 1; mm < 16; mm <<= 1) ps += __shfl_xor(ps, mm);
      l[r] = l[r] * sc + ps;
      m[r] = mn;
      #pragma unroll
      for (int nfd = 0; nfd < 4; nfd++) o_acc[nfd][r] *= sc;
    }

    #pragma unroll
    for (int ks = 0; ks < 2; ks++){
      short8 pa = *(const short8*)&p_s[w][li][ks * 32 + g * 8];
      int kcol = min(kbase + ks * 32 + g * 8, KVLEN - 8);
      #pragma unroll
      for (int nfd = 0; nfd < 4; nfd++){
        short8 vfrag = *(const short8*)&vTh[(size_t)(nfd * 16 + li) * KVLEN + kcol];
        o_acc[nfd] = __builtin_amdgcn_mfma_f32_16x16x32_bf16(pa, vfrag, o_acc[nfd], 0, 0, 0);
      }
    }
  }

  #pragma unroll
  for (int r = 0; r < 4; r++){
    if (li == 0){ ml_s[w][0][g * 4 + r] = m[r]; ml_s[w][1][g * 4 + r] = l[r]; }
    #pragma unroll
    for (int nfd = 0; nfd < 4; nfd++)
      o_s[w][g * 4 + r][nfd * 16 + li] = o_acc[nfd][r];
  }
  __syncthreads();

  {
    int row = t >> 4, c0 = (t & 15) * 4;
    float M = -3e38f;
    #pragma unroll
    for (int ww = 0; ww < 4; ww++) M = fmaxf(M, ml_s[ww][0][row]);
    float L = 0.f, ew[4];
    #pragma unroll
    for (int ww = 0; ww < 4; ww++){
      ew[ww] = __expf(ml_s[ww][0][row] - M);
      L += ml_s[ww][1][row] * ew[ww];
    }
    float inv = 1.f / L;
    #pragma unroll
    for (int j = 0; j < 4; j++){
      float ov = 0.f;
      #pragma unroll
      for (int ww = 0; ww < 4; ww++) ov += o_s[ww][row][c0 + j] * ew[ww];
      attnb[(size_t)(n * 16 + row) * DMODEL + h * 64 + c0 + j] = f2bf(ov * inv);
    }
  }
}

// ---------------- LM head: 128q x 128vocab, BOTH operands gload_lds-staged (coalesced),
// swapped operands (W=A, ob=B) so per-q stats are lane-local; cross-wave LDS combine;
// one split per block, coalesced [split][row] partial writes; XCD-aware vocab-contiguous grid.
__global__ __launch_bounds__(256) void lm_fused(const u16* __restrict__ obp,
                                                const u16* __restrict__ WT,
                                                const int* __restrict__ input_ids,
                                                const int* __restrict__ anchors,
                                                float* __restrict__ pl,
                                                float* __restrict__ pt, float* __restrict__ pbv,
                                                int* __restrict__ pbi){
  __shared__ __align__(16) u16 Wb[2][128 * 64];
  __shared__ __align__(16) u16 Ob[2][128 * 64];
  __shared__ int tcol_s[128];
  __shared__ float cse[4][128], ctv[4][128], cbv[4][128];
  __shared__ int cbi[4][128];

  int L = blockIdx.x;                       // 0..3999
  int T = (L & 7) * 500 + (L >> 3);         // bijective (4000 % 8 == 0); XCD-contiguous T ranges
  int qbase = (T & 15) * 128;               // q fastest within an XCD -> W slice reused in its L2
  int vb = T >> 4;                          // 0..249 vocab block
  int vocabbase = vb * 128;
  int t = threadIdx.x, w = t >> 6, lane = t & 63;
  int g = lane >> 4, li = lane & 15;

  if (t < 128){
    int r = qbase + t; int n = r >> 4, off = r & 15;
    int lab = anchors[n] + off;
    int safe = min(max(lab, 0), S_LEN - 1);
    tcol_s[t] = input_ids[safe];
  }

  int r0 = t >> 3, cg0 = t & 7;
  int swz = (cg0 ^ (r0 & 7)) << 3;
  auto stage = [&](u16* wdst, u16* odst, int kb){
    #pragma unroll
    for (int i = 0; i < 4; i++){
      __builtin_amdgcn_global_load_lds(GAS(&WT [(size_t)(vocabbase + r0 + i * 32) * DMODEL + kb + swz]),
                                       LAS(wdst + i * 2048 + w * 512), 16, 0, 0);
      __builtin_amdgcn_global_load_lds(GAS(&obp[(size_t)(qbase     + r0 + i * 32) * DMODEL + kb + swz]),
                                       LAS(odst + i * 2048 + w * 512), 16, 0, 0);
    }
  };

  f32x4 acc[2][8];
  #pragma unroll
  for (int i = 0; i < 2; i++)
    #pragma unroll
    for (int j = 0; j < 8; j++)
      acc[i][j] = (f32x4){0.f, 0.f, 0.f, 0.f};

  stage(Wb[0], Ob[0], 0);
  __syncthreads();

  for (int kt = 0; kt < 8; kt++){
    const u16* curW = Wb[kt & 1]; const u16* curO = Ob[kt & 1];
    if (kt < 7) stage(Wb[(kt + 1) & 1], Ob[(kt + 1) & 1], (kt + 1) * 64);
    #pragma unroll
    for (int ks = 0; ks < 2; ks++){
      int cg = ((ks * 4 + g) ^ (li & 7)) << 3;
      short8 wfr[2], obf[8];
      #pragma unroll
      for (int vf = 0; vf < 2; vf++)
        wfr[vf] = *(const short8*)&curW[(w * 32 + vf * 16 + li) * 64 + cg];
      #pragma unroll
      for (int qf = 0; qf < 8; qf++)
        obf[qf] = *(const short8*)&curO[(qf * 16 + li) * 64 + cg];
      #pragma unroll
      for (int vf = 0; vf < 2; vf++)
        #pragma unroll
        for (int qf = 0; qf < 8; qf++)
          acc[vf][qf] = __builtin_amdgcn_mfma_f32_16x16x32_bf16(wfr[vf], obf[qf], acc[vf][qf], 0, 0, 0);
    }
    __syncthreads();
  }

  // per-lane stats over this wave's 32-vocab slice, per q-column (lane-local)
  #pragma unroll
  for (int qf = 0; qf < 8; qf++){
    int qloc = qf * 16 + li;
    int tc = tcol_s[qloc] - vocabbase;     // target pos within the 128-vocab block
    float se = 0.f, tv = -3e38f, bv = -3e38f; int bi = 0x7fffffff;
    #pragma unroll
    for (int vf = 0; vf < 2; vf++){
      #pragma unroll
      for (int r = 0; r < 4; r++){
        float v = acc[vf][qf][r];
        int pos = w * 32 + vf * 16 + g * 4 + r;
        se += __expf(v);
        if (pos == tc) tv = v;
        if (v > bv){ bv = v; bi = pos; }
      }
    }
    #pragma unroll
    for (int off = 16; off <= 32; off <<= 1){
      se += __shfl_xor(se, off);
      tv = fmaxf(tv, __shfl_xor(tv, off));
      float ob_ = __shfl_xor(bv, off); int oi = __shfl_xor(bi, off);
      if (ob_ > bv || (ob_ == bv && oi < bi)){ bv = ob_; bi = oi; }
    }
    if (g == 0){
      cse[w][qloc] = se; ctv[w][qloc] = tv; cbv[w][qloc] = bv; cbi[w][qloc] = bi;
    }
  }
  __syncthreads();

  if (t < 128){
    float SE = 0.f, TV = -3e38f, BV = -3e38f; int BI = 0x7fffffff;
    #pragma unroll
    for (int ww = 0; ww < 4; ww++){
      SE += cse[ww][t];
      TV = fmaxf(TV, ctv[ww][t]);
      float v = cbv[ww][t];
      if (v > BV){ BV = v; BI = cbi[ww][t]; }   // waves ascend in vocab: strict > keeps first-max
    }
    size_t idx = (size_t)vb * QLEN + qbase + t;  // [split][row] -> coalesced
    pl[idx] = SE; pt[idx] = TV; pbv[idx] = BV; pbi[idx] = vocabbase + BI;
  }
}

// ---------------- per-row split merge: one wave per row ----------------
__global__ __launch_bounds__(256) void loss_rows(const float* __restrict__ pl,
                                                 const float* __restrict__ pt, const float* __restrict__ pbv,
                                                 const int* __restrict__ pbi,
                                                 const int* __restrict__ input_ids,
                                                 const int* __restrict__ anchors,
                                                 const unsigned char* __restrict__ keep,
                                                 const float* __restrict__ loss_mask,
                                                 float* __restrict__ rowacc){
  int t = threadIdx.x, w = t >> 6, lane = t & 63;
  int row = blockIdx.x * 4 + w;
  float L = 0.f, TV = -3e38f, BV = -3e38f; int BI = 0x7fffffff;
  for (int s = lane; s < NSPLIT; s += 64){
    size_t idx = (size_t)s * QLEN + row;    // [split][row]
    L += pl[idx];
    TV = fmaxf(TV, pt[idx]);
    float bv_ = pbv[idx]; int bi_ = pbi[idx];
    if (bv_ > BV || (bv_ == BV && bi_ < BI)){ BV = bv_; BI = bi_; }
  }
  #pragma unroll
  for (int mm = 1; mm < 64; mm <<= 1){
    L += __shfl_xor(L, mm);
    TV = fmaxf(TV, __shfl_xor(TV, mm));
    float ob = __shfl_xor(BV, mm); int oi = __shfl_xor(BI, mm);
    if (ob > BV || (ob == BV && oi < BI)){ BV = ob; BI = oi; }
  }
  if (lane == 0){
    int n = row >> 4, off = row & 15;
    int lab = anchors[n] + off;
    int valid = (lab < S_LEN) ? 1 : 0;
    int safe = min(max(lab, 0), S_LEN - 1);
    int tgt = input_ids[safe];
    float wgt = (keep[n] ? 1.f : 0.f) * (valid ? 1.f : 0.f) * ((off > 0) ? 1.f : 0.f) * loss_mask[safe];
    float logp = TV - __logf(L);
    rowacc[row * 3 + 0] = -logp * wgt;
    rowacc[row * 3 + 1] = wgt;
    rowacc[row * 3 + 2] = ((BI == tgt) && (wgt > 0.5f)) ? 1.f : 0.f;
  }
}

// ---------------- final sum over rows ----------------
__global__ __launch_bounds__(256) void final_sum(const float* __restrict__ rowacc, float* __restrict__ out){
  int t = threadIdx.x;
  float a = 0.f, b = 0.f, c = 0.f;
  for (int r = t; r < QLEN; r += 256){
    a += rowacc[r * 3 + 0]; b += rowacc[r * 3 + 1]; c += rowacc[r * 3 + 2];
  }
  __shared__ float sa[256], sb[256], sc_[256];
  sa[t] = a; sb[t] = b; sc_[t] = c;
  __syncthreads();
  for (int s = 128; s >= 1; s >>= 1){
    if (t < s){ sa[t] += sa[t + s]; sb[t] += sb[t + s]; sc_[t] += sc_[t + s]; }
    __syncthreads();
  }
  if (t == 0){
    out[0] = sa[0] / (sb[0] + 1e-6f);
    out[1] = sc_[0] / (sb[0] + 1e-6f);
  }
}

// ---------------- host ----------------
extern "C" void kernel_launch(void* const* d_in, const int* in_sizes, int n_in,
                              void* d_out, int out_size, void* d_ws, size_t ws_size,
                              hipStream_t stream) {
  const int*   input_ids = (const int*)  d_in[0];
  const float* hidden    = (const float*)d_in[1];
  const float* loss_mask = (const float*)d_in[2];
  const int*   anchors   = (const int*)  d_in[3];
  const unsigned char* keep = (const unsigned char*)d_in[4];
  const float* embed     = (const float*)d_in[5];
  const float* Wq        = (const float*)d_in[6];
  const float* Wk        = (const float*)d_in[7];
  const float* Wv        = (const float*)d_in[8];
  const float* Wo        = (const float*)d_in[9];
  const float* Wlm       = (const float*)d_in[10];

  char* ws = (char*)d_ws;
  size_t off = 0;
  auto take = [&](size_t bytes) -> char* {
    char* p = ws + off;
    off += (bytes + 255) & ~(size_t)255;
    return p;
  };
  u16* WqT  = (u16*)take((size_t)512 * 512 * 2);
  u16* WkT  = (u16*)take((size_t)512 * 512 * 2);
  u16* WvT  = (u16*)take((size_t)512 * 512 * 2);
  u16* WoT  = (u16*)take((size_t)512 * 512 * 2);
  u16* WlmT = (u16*)take((size_t)VOCAB * 512 * 2);
  u16* kvb  = (u16*)take((size_t)KVLEN * 512 * 2);
  u16* qb2  = (u16*)take((size_t)QLEN * 512 * 2);
  u16* kb   = (u16*)take((size_t)KVLEN * 512 * 2);
  u16* vTb  = (u16*)take((size_t)512 * KVLEN * 2);
  u16* attnb= (u16*)take((size_t)QLEN * 512 * 2);
  u16* ob   = (u16*)take((size_t)QLEN * 512 * 2);
  float* pl = (float*)take((size_t)QLEN * NSPLIT * 4);
  float* pt = (float*)take((size_t)QLEN * NSPLIT * 4);
  float* pbv= (float*)take((size_t)QLEN * NSPLIT * 4);
  int*   pbi= (int*)  take((size_t)QLEN * NSPLIT * 4);
  float* rowacc = (float*)take((size_t)QLEN * 3 * 4);

  transpose4<<<dim3(16, 16, 4), 256, 0, stream>>>(Wq, Wk, Wv, Wo, WqT, WkT, WvT, WoT);
  transpose_cast<<<dim3(1000, 16), 256, 0, stream>>>(Wlm, WlmT, 512, VOCAB);

  build_kv<<<KVLEN, 128, 0, stream>>>(hidden, embed, input_ids, anchors, keep, kvb);

  gemmTile<0, 2><<<dim3(32, 8), 256, 0, stream>>>(kvb, WkT, kb,  KVLEN, 512, 512, 512);   // k (4096,512)
  gemmTile<1, 2><<<dim3(32, 8), 256, 0, stream>>>(kvb, WvT, vTb, KVLEN, 512, 512, KVLEN); // v^T (512,4096)
  gemmTile<0, 1><<<dim3(32, 8), 256, 0, stream>>>(kvb + (size_t)S_LEN * 512, WqT, qb2, QLEN, 512, 512, 512); // q

  attn_mfma<<<dim3(NBLK, 8), 256, 0, stream>>>(qb2, kb, vTb, anchors, keep, attnb);

  gemmTile<0, 1><<<dim3(32, 8), 256, 0, stream>>>(attnb, WoT, ob, QLEN, 512, 512, 512);   // o = attn @ Wo

  lm_fused<<<4000, 256, 0, stream>>>(ob, WlmT, input_ids, anchors, pl, pt, pbv, pbi);

  loss_rows<<<512, 256, 0, stream>>>(pl, pt, pbv, pbi, input_ids, anchors, keep, loss_mask, rowacc);

  final_sum<<<1, 256, 0, stream>>>(rowacc, (float*)d_out);
}

// Round 8
// 247.876 us; speedup vs baseline: 11.7301x; 1.0100x over previous
//
#include <hip/hip_runtime.h>

typedef unsigned short u16;
typedef __attribute__((ext_vector_type(4))) float f32x4;
typedef __attribute__((ext_vector_type(8))) short short8;
typedef __attribute__((ext_vector_type(4))) unsigned int uv4;
typedef __attribute__((ext_vector_type(4))) float fv4;
typedef __attribute__((ext_vector_type(4))) unsigned short usv4;

#define S_LEN 2048
#define NBLK 128
#define DMODEL 512
#define VOCAB 32000
#define QLEN 2048
#define KVLEN 4096
#define NSPLIT 250   // 32000 vocab / 128-vocab blocks

#define GAS(p) ((const __attribute__((address_space(1))) void*)(const void*)(p))
#define LAS(p) ((__attribute__((address_space(3))) void*)(void*)(p))

__device__ __forceinline__ float bf2f(u16 u){
  union { unsigned int i; float f; } x; x.i = ((unsigned int)u) << 16; return x.f;
}
__device__ __forceinline__ u16 f2bf(float f){
  union { float f; unsigned int i; } x; x.f = f;
  unsigned int r = x.i + 0x7fffu + ((x.i >> 16) & 1u);
  return (u16)(r >> 16);
}

// ---------------- transpose + cast f32(K,N) -> bf16(N,K), 512x512, 4 matrices ----------------
__global__ __launch_bounds__(256) void transpose4(const float* __restrict__ i0, const float* __restrict__ i1,
                                                  const float* __restrict__ i2, const float* __restrict__ i3,
                                                  u16* __restrict__ o0, u16* __restrict__ o1,
                                                  u16* __restrict__ o2, u16* __restrict__ o3){
  const float* in; u16* out;
  switch (blockIdx.z){
    case 0: in = i0; out = o0; break;
    case 1: in = i1; out = o1; break;
    case 2: in = i2; out = o2; break;
    default: in = i3; out = o3; break;
  }
  __shared__ float tile[32][33];
  int t = threadIdx.x, tx = t & 31, ty = t >> 5;
  int nb = blockIdx.x * 32, kb = blockIdx.y * 32;
  #pragma unroll
  for (int i = 0; i < 4; i++){
    int r = ty + i * 8;
    tile[r][tx] = in[(size_t)(kb + r) * 512 + nb + tx];
  }
  __syncthreads();
  #pragma unroll
  for (int i = 0; i < 4; i++){
    int r = ty + i * 8;
    out[(size_t)(nb + r) * 512 + kb + tx] = f2bf(tile[tx][r]);
  }
}

// ---------------- transpose + cast f32(K,N) -> bf16(N,K), generic (for W_lm) ----------------
__global__ __launch_bounds__(256) void transpose_cast(const float* __restrict__ in,
                                                      u16* __restrict__ out,
                                                      int K, int N){
  __shared__ float tile[32][33];
  int t = threadIdx.x, tx = t & 31, ty = t >> 5;
  int nb = blockIdx.x * 32, kb = blockIdx.y * 32;
  #pragma unroll
  for (int i = 0; i < 4; i++){
    int r = ty + i * 8;
    tile[r][tx] = in[(size_t)(kb + r) * N + nb + tx];
  }
  __syncthreads();
  #pragma unroll
  for (int i = 0; i < 4; i++){
    int r = ty + i * 8;
    out[(size_t)(nb + r) * K + kb + tx] = f2bf(tile[tx][r]);
  }
}

// ---------------- build kv_in (bf16 4096x512): [hidden ; noise_embedding] ----------------
__global__ __launch_bounds__(128) void build_kv(const float* __restrict__ hidden,
                                                const float* __restrict__ embed,
                                                const int* __restrict__ input_ids,
                                                const int* __restrict__ anchors,
                                                const unsigned char* __restrict__ keep,
                                                u16* __restrict__ kvb){
  int row = blockIdx.x;           // 0..4095
  int t = threadIdx.x;            // 0..127
  const float* src;
  if (row < S_LEN){
    src = hidden + (size_t)row * DMODEL;
  } else {
    int q = row - S_LEN;
    int id = 3;                   // MASK_TOKEN_ID
    if ((q & 15) == 0){
      int n = q >> 4;
      if (keep[n]){
        int a = anchors[n]; a = min(max(a, 0), S_LEN - 1);
        id = input_ids[a];
      }
    }
    src = embed + (size_t)id * DMODEL;
  }
  int c = t * 4;
  fv4 v = *(const fv4*)&src[c];
  usv4 o; o[0] = f2bf(v[0]); o[1] = f2bf(v[1]); o[2] = f2bf(v[2]); o[3] = f2bf(v[3]);
  *(usv4*)&kvb[(size_t)row * DMODEL + c] = o;
}

// ---------------- projection GEMM: (64*MF)x64 tile, gload_lds staged, XOR-swizzled,
// counted-vmcnt double-buffer (2 raw barriers per K-step, loads stay in flight) ----------------
template<int TRANS, int MF>
__global__ __launch_bounds__(256) void gemmTile(const u16* __restrict__ A,
                                                const u16* __restrict__ BT,
                                                u16* __restrict__ C,
                                                int M, int N, int K, int ldc){
  __shared__ __align__(16) u16 As[2][64 * MF * 64];
  __shared__ __align__(16) u16 Bs[2][64 * 64];
  int t = threadIdx.x, w = t >> 6, lane = t & 63;
  int g = lane >> 4, li = lane & 15;
  int rowbase = blockIdx.x * (64 * MF), colbase = blockIdx.y * 64;
  int r0 = t >> 3, cg0 = t & 7;
  int swz = (cg0 ^ (r0 & 7)) << 3;

  auto stageA = [&](u16* dst, int kb){
    #pragma unroll
    for (int i = 0; i < 2 * MF; i++)
      __builtin_amdgcn_global_load_lds(GAS(&A[(size_t)(rowbase + r0 + i * 32) * K + kb + swz]),
                                       LAS(dst + i * 2048 + w * 512), 16, 0, 0);
  };
  auto stageB = [&](u16* dst, int kb){
    #pragma unroll
    for (int i = 0; i < 2; i++)
      __builtin_amdgcn_global_load_lds(GAS(&BT[(size_t)(colbase + r0 + i * 32) * K + kb + swz]),
                                       LAS(dst + i * 2048 + w * 512), 16, 0, 0);
  };

  f32x4 acc[MF][4];
  #pragma unroll
  for (int i = 0; i < MF; i++)
    #pragma unroll
    for (int j = 0; j < 4; j++)
      acc[i][j] = (f32x4){0.f, 0.f, 0.f, 0.f};

  stageA(As[0], 0); stageB(Bs[0], 0);

  int nkt = K >> 6;
  for (int kt = 0; kt < nkt; kt++){
    u16* curA = As[kt & 1]; u16* curB = Bs[kt & 1];
    if (kt + 1 < nkt){
      stageA(As[(kt + 1) & 1], (kt + 1) * 64); stageB(Bs[(kt + 1) & 1], (kt + 1) * 64);
      // wait only for stage(kt): the 2*MF+2 loads just issued stay in flight
      if constexpr (MF == 2) asm volatile("s_waitcnt vmcnt(6)" ::: "memory");
      else                   asm volatile("s_waitcnt vmcnt(4)" ::: "memory");
    } else {
      asm volatile("s_waitcnt vmcnt(0)" ::: "memory");
    }
    __builtin_amdgcn_s_barrier();          // all waves: stage(kt) data visible
    #pragma unroll
    for (int ks = 0; ks < 2; ks++){
      short8 af[MF], bf[4];
      #pragma unroll
      for (int mf = 0; mf < MF; mf++){
        int row = w * 16 * MF + mf * 16 + li;
        af[mf] = *(const short8*)&curA[row * 64 + (((ks * 4 + g) ^ (li & 7)) << 3)];
      }
      #pragma unroll
      for (int nf = 0; nf < 4; nf++){
        int row = nf * 16 + li;
        bf[nf] = *(const short8*)&curB[row * 64 + (((ks * 4 + g) ^ (li & 7)) << 3)];
      }
      #pragma unroll
      for (int mf = 0; mf < MF; mf++)
        #pragma unroll
        for (int nf = 0; nf < 4; nf++)
          acc[mf][nf] = __builtin_amdgcn_mfma_f32_16x16x32_bf16(af[mf], bf[nf], acc[mf][nf], 0, 0, 0);
    }
    __builtin_amdgcn_s_barrier();          // all waves done reading buf[kt&1]
  }

  #pragma unroll
  for (int mf = 0; mf < MF; mf++)
    #pragma unroll
    for (int nf = 0; nf < 4; nf++)
      #pragma unroll
      for (int r = 0; r < 4; r++){
        int row = rowbase + w * 16 * MF + mf * 16 + g * 4 + r;
        int col = colbase + nf * 16 + li;
        u16 vv = f2bf(acc[mf][nf][r]);
        if (TRANS) C[(size_t)col * ldc + row] = vv;
        else       C[(size_t)row * ldc + col] = vv;
      }
}

// ---------------- MFMA flash attention: one (draft block n, head h) per workgroup ----------------
__global__ __launch_bounds__(256) void attn_mfma(const u16* __restrict__ qb,
                                                 const u16* __restrict__ kb,
                                                 const u16* __restrict__ vT,
                                                 const int* __restrict__ anchors,
                                                 const unsigned char* __restrict__ keep,
                                                 u16* __restrict__ attnb){
  int n = blockIdx.x, h = blockIdx.y;
  int t = threadIdx.x, w = t >> 6, lane = t & 63;
  int g = lane >> 4, li = lane & 15;

  __shared__ __align__(16) u16 q_s[16][72];
  __shared__ __align__(16) u16 p_s[4][16][72];
  __shared__ float o_s[4][16][64];
  __shared__ float ml_s[4][2][16];

  {
    int r = t >> 4, c4 = (t & 15) * 4;
    *(usv4*)&q_s[r][c4] = *(const usv4*)&qb[(size_t)(n * 16 + r) * DMODEL + h * 64 + c4];
  }
  __syncthreads();

  int anchor = anchors[n];
  bool kp = keep[n] != 0;
  const u16* kh  = kb + h * 64;
  const u16* vTh = vT + (size_t)(h * 64) * KVLEN;

  if (!kp){
    if (w == 0){
      float acc = 0.f;
      const u16* row = vTh + (size_t)lane * KVLEN;
      for (int k2 = 0; k2 < KVLEN; k2 += 8){
        short8 vv = *(const short8*)&row[k2];
        #pragma unroll
        for (int j = 0; j < 8; j++) acc += bf2f((u16)vv[j]);
      }
      acc *= (1.f / 4096.f);
      u16 ov = f2bf(acc);
      for (int r = 0; r < 16; r++)
        attnb[(size_t)(n * 16 + r) * DMODEL + h * 64 + lane] = ov;
    }
    return;
  }

  short8 qa[2];
  #pragma unroll
  for (int ks = 0; ks < 2; ks++)
    qa[ks] = *(const short8*)&q_s[li][ks * 32 + g * 8];

  int nctx = (anchor + 63) >> 6;
  int ntot = nctx + 1;

  f32x4 o_acc[4];
  float m[4], l[4];
  #pragma unroll
  for (int i = 0; i < 4; i++){ o_acc[i] = (f32x4){0.f,0.f,0.f,0.f}; m[i] = -3e38f; l[i] = 0.f; }

  for (int c = w; c < ntot; c += 4){
    bool draft = (c == nctx);
    int kbase = draft ? (S_LEN + n * 16) : c * 64;
    int nk    = draft ? 16 : min(64, anchor - c * 64);

    f32x4 s[4];
    #pragma unroll
    for (int nf = 0; nf < 4; nf++) s[nf] = (f32x4){0.f,0.f,0.f,0.f};
    #pragma unroll
    for (int ks = 0; ks < 2; ks++){
      #pragma unroll
      for (int nf = 0; nf < 4; nf++){
        int krow = min(kbase + nf * 16 + li, KVLEN - 1);
        short8 bfrag = *(const short8*)&kh[(size_t)krow * DMODEL + ks * 32 + g * 8];
        s[nf] = __builtin_amdgcn_mfma_f32_16x16x32_bf16(qa[ks], bfrag, s[nf], 0, 0, 0);
      }
    }

    #pragma unroll
    for (int r = 0; r < 4; r++){
      float mx = -3e38f;
      #pragma unroll
      for (int nf = 0; nf < 4; nf++){
        float sv = s[nf][r] * 0.125f;
        if (nf * 16 + li >= nk) sv = -3e38f;
        s[nf][r] = sv;
        mx = fmaxf(mx, sv);
      }
      #pragma unroll
      for (int mm = 1; mm < 16; mm <<= 1) mx = fmaxf(mx, __shfl_xor(mx, mm));
      float mn = fmaxf(m[r], mx);
      float sc = __expf(m[r] - mn);
      float ps = 0.f;
      #pragma unroll
      for (int nf = 0; nf < 4; nf++){
        float p = __expf(s[nf][r] - mn);
        ps += p;
        p_s[w][g * 4 + r][nf * 16 + li] = f2bf(p);
      }
      #pragma unroll
      for (int mm = 1; mm < 16; mm <<= 1) ps += __shfl_xor(ps, mm);
      l[r] = l[r] * sc + ps;
      m[r] = mn;
      #pragma unroll
      for (int nfd = 0; nfd < 4; nfd++) o_acc[nfd][r] *= sc;
    }

    #pragma unroll
    for (int ks = 0; ks < 2; ks++){
      short8 pa = *(const short8*)&p_s[w][li][ks * 32 + g * 8];
      int kcol = min(kbase + ks * 32 + g * 8, KVLEN - 8);
      #pragma unroll
      for (int nfd = 0; nfd < 4; nfd++){
        short8 vfrag = *(const short8*)&vTh[(size_t)(nfd * 16 + li) * KVLEN + kcol];
        o_acc[nfd] = __builtin_amdgcn_mfma_f32_16x16x32_bf16(pa, vfrag, o_acc[nfd], 0, 0, 0);
      }
    }
  }

  #pragma unroll
  for (int r = 0; r < 4; r++){
    if (li == 0){ ml_s[w][0][g * 4 + r] = m[r]; ml_s[w][1][g * 4 + r] = l[r]; }
    #pragma unroll
    for (int nfd = 0; nfd < 4; nfd++)
      o_s[w][g * 4 + r][nfd * 16 + li] = o_acc[nfd][r];
  }
  __syncthreads();

  {
    int row = t >> 4, c0 = (t & 15) * 4;
    float M = -3e38f;
    #pragma unroll
    for (int ww = 0; ww < 4; ww++) M = fmaxf(M, ml_s[ww][0][row]);
    float L = 0.f, ew[4];
    #pragma unroll
    for (int ww = 0; ww < 4; ww++){
      ew[ww] = __expf(ml_s[ww][0][row] - M);
      L += ml_s[ww][1][row] * ew[ww];
    }
    float inv = 1.f / L;
    #pragma unroll
    for (int j = 0; j < 4; j++){
      float ov = 0.f;
      #pragma unroll
      for (int ww = 0; ww < 4; ww++) ov += o_s[ww][row][c0 + j] * ew[ww];
      attnb[(size_t)(n * 16 + row) * DMODEL + h * 64 + c0 + j] = f2bf(ov * inv);
    }
  }
}

// ---------------- LM head: 128q x 128vocab, both operands gload_lds-staged,
// counted-vmcnt 2-barrier pipeline + setprio around MFMA; swapped operands for
// lane-local stats; cross-wave LDS combine; coalesced [split][row] partials. ----------------
__global__ __launch_bounds__(256) void lm_fused(const u16* __restrict__ obp,
                                                const u16* __restrict__ WT,
                                                const int* __restrict__ input_ids,
                                                const int* __restrict__ anchors,
                                                float* __restrict__ pl,
                                                float* __restrict__ pt, float* __restrict__ pbv,
                                                int* __restrict__ pbi){
  __shared__ __align__(16) u16 Wb[2][128 * 64];
  __shared__ __align__(16) u16 Ob[2][128 * 64];
  __shared__ int tcol_s[128];
  __shared__ float cse[4][128], ctv[4][128], cbv[4][128];
  __shared__ int cbi[4][128];

  int L = blockIdx.x;                       // 0..3999
  int T = (L & 7) * 500 + (L >> 3);         // bijective (4000 % 8 == 0); XCD-contiguous T ranges
  int qbase = (T & 15) * 128;               // q fastest within an XCD -> W slice reused in its L2
  int vb = T >> 4;                          // 0..249 vocab block
  int vocabbase = vb * 128;
  int t = threadIdx.x, w = t >> 6, lane = t & 63;
  int g = lane >> 4, li = lane & 15;

  if (t < 128){
    int r = qbase + t; int n = r >> 4, off = r & 15;
    int lab = anchors[n] + off;
    int safe = min(max(lab, 0), S_LEN - 1);
    tcol_s[t] = input_ids[safe];
  }

  int r0 = t >> 3, cg0 = t & 7;
  int swz = (cg0 ^ (r0 & 7)) << 3;
  auto stage = [&](u16* wdst, u16* odst, int kb){
    #pragma unroll
    for (int i = 0; i < 4; i++){
      __builtin_amdgcn_global_load_lds(GAS(&WT [(size_t)(vocabbase + r0 + i * 32) * DMODEL + kb + swz]),
                                       LAS(wdst + i * 2048 + w * 512), 16, 0, 0);
      __builtin_amdgcn_global_load_lds(GAS(&obp[(size_t)(qbase     + r0 + i * 32) * DMODEL + kb + swz]),
                                       LAS(odst + i * 2048 + w * 512), 16, 0, 0);
    }
  };

  f32x4 acc[2][8];
  #pragma unroll
  for (int i = 0; i < 2; i++)
    #pragma unroll
    for (int j = 0; j < 8; j++)
      acc[i][j] = (f32x4){0.f, 0.f, 0.f, 0.f};

  stage(Wb[0], Ob[0], 0);

  for (int kt = 0; kt < 8; kt++){
    const u16* curW = Wb[kt & 1]; const u16* curO = Ob[kt & 1];
    if (kt < 7){
      stage(Wb[(kt + 1) & 1], Ob[(kt + 1) & 1], (kt + 1) * 64);
      asm volatile("s_waitcnt vmcnt(8)" ::: "memory");   // stage(kt) landed; stage(kt+1) in flight
    } else {
      asm volatile("s_waitcnt vmcnt(0)" ::: "memory");
    }
    __builtin_amdgcn_s_barrier();          // all waves: stage(kt) visible
    __builtin_amdgcn_s_setprio(1);
    #pragma unroll
    for (int ks = 0; ks < 2; ks++){
      int cg = ((ks * 4 + g) ^ (li & 7)) << 3;
      short8 wfr[2], obf[8];
      #pragma unroll
      for (int vf = 0; vf < 2; vf++)
        wfr[vf] = *(const short8*)&curW[(w * 32 + vf * 16 + li) * 64 + cg];
      #pragma unroll
      for (int qf = 0; qf < 8; qf++)
        obf[qf] = *(const short8*)&curO[(qf * 16 + li) * 64 + cg];
      #pragma unroll
      for (int vf = 0; vf < 2; vf++)
        #pragma unroll
        for (int qf = 0; qf < 8; qf++)
          acc[vf][qf] = __builtin_amdgcn_mfma_f32_16x16x32_bf16(wfr[vf], obf[qf], acc[vf][qf], 0, 0, 0);
    }
    __builtin_amdgcn_s_setprio(0);
    __builtin_amdgcn_s_barrier();          // all waves done reading buf[kt&1]
  }

  // per-lane stats over this wave's 32-vocab slice, per q-column (lane-local)
  #pragma unroll
  for (int qf = 0; qf < 8; qf++){
    int qloc = qf * 16 + li;
    int tc = tcol_s[qloc] - vocabbase;     // target pos within the 128-vocab block
    float se = 0.f, tv = -3e38f, bv = -3e38f; int bi = 0x7fffffff;
    #pragma unroll
    for (int vf = 0; vf < 2; vf++){
      #pragma unroll
      for (int r = 0; r < 4; r++){
        float v = acc[vf][qf][r];
        int pos = w * 32 + vf * 16 + g * 4 + r;
        se += __expf(v);
        if (pos == tc) tv = v;
        if (v > bv){ bv = v; bi = pos; }
      }
    }
    #pragma unroll
    for (int off = 16; off <= 32; off <<= 1){
      se += __shfl_xor(se, off);
      tv = fmaxf(tv, __shfl_xor(tv, off));
      float ob_ = __shfl_xor(bv, off); int oi = __shfl_xor(bi, off);
      if (ob_ > bv || (ob_ == bv && oi < bi)){ bv = ob_; bi = oi; }
    }
    if (g == 0){
      cse[w][qloc] = se; ctv[w][qloc] = tv; cbv[w][qloc] = bv; cbi[w][qloc] = bi;
    }
  }
  __syncthreads();

  if (t < 128){
    float SE = 0.f, TV = -3e38f, BV = -3e38f; int BI = 0x7fffffff;
    #pragma unroll
    for (int ww = 0; ww < 4; ww++){
      SE += cse[ww][t];
      TV = fmaxf(TV, ctv[ww][t]);
      float v = cbv[ww][t];
      if (v > BV){ BV = v; BI = cbi[ww][t]; }   // waves ascend in vocab: strict > keeps first-max
    }
    size_t idx = (size_t)vb * QLEN + qbase + t;  // [split][row] -> coalesced
    pl[idx] = SE; pt[idx] = TV; pbv[idx] = BV; pbi[idx] = vocabbase + BI;
  }
}

// ---------------- per-row split merge: one wave per row ----------------
__global__ __launch_bounds__(256) void loss_rows(const float* __restrict__ pl,
                                                 const float* __restrict__ pt, const float* __restrict__ pbv,
                                                 const int* __restrict__ pbi,
                                                 const int* __restrict__ input_ids,
                                                 const int* __restrict__ anchors,
                                                 const unsigned char* __restrict__ keep,
                                                 const float* __restrict__ loss_mask,
                                                 float* __restrict__ rowacc){
  int t = threadIdx.x, w = t >> 6, lane = t & 63;
  int row = blockIdx.x * 4 + w;
  float L = 0.f, TV = -3e38f, BV = -3e38f; int BI = 0x7fffffff;
  for (int s = lane; s < NSPLIT; s += 64){
    size_t idx = (size_t)s * QLEN + row;    // [split][row]
    L += pl[idx];
    TV = fmaxf(TV, pt[idx]);
    float bv_ = pbv[idx]; int bi_ = pbi[idx];
    if (bv_ > BV || (bv_ == BV && bi_ < BI)){ BV = bv_; BI = bi_; }
  }
  #pragma unroll
  for (int mm = 1; mm < 64; mm <<= 1){
    L += __shfl_xor(L, mm);
    TV = fmaxf(TV, __shfl_xor(TV, mm));
    float ob = __shfl_xor(BV, mm); int oi = __shfl_xor(BI, mm);
    if (ob > BV || (ob == BV && oi < BI)){ BV = ob; BI = oi; }
  }
  if (lane == 0){
    int n = row >> 4, off = row & 15;
    int lab = anchors[n] + off;
    int valid = (lab < S_LEN) ? 1 : 0;
    int safe = min(max(lab, 0), S_LEN - 1);
    int tgt = input_ids[safe];
    float wgt = (keep[n] ? 1.f : 0.f) * (valid ? 1.f : 0.f) * ((off > 0) ? 1.f : 0.f) * loss_mask[safe];
    float logp = TV - __logf(L);
    rowacc[row * 3 + 0] = -logp * wgt;
    rowacc[row * 3 + 1] = wgt;
    rowacc[row * 3 + 2] = ((BI == tgt) && (wgt > 0.5f)) ? 1.f : 0.f;
  }
}

// ---------------- final sum over rows ----------------
__global__ __launch_bounds__(256) void final_sum(const float* __restrict__ rowacc, float* __restrict__ out){
  int t = threadIdx.x;
  float a = 0.f, b = 0.f, c = 0.f;
  for (int r = t; r < QLEN; r += 256){
    a += rowacc[r * 3 + 0]; b += rowacc[r * 3 + 1]; c += rowacc[r * 3 + 2];
  }
  __shared__ float sa[256], sb[256], sc_[256];
  sa[t] = a; sb[t] = b; sc_[t] = c;
  __syncthreads();
  for (int s = 128; s >= 1; s >>= 1){
    if (t < s){ sa[t] += sa[t + s]; sb[t] += sb[t + s]; sc_[t] += sc_[t + s]; }
    __syncthreads();
  }
  if (t == 0){
    out[0] = sa[0] / (sb[0] + 1e-6f);
    out[1] = sc_[0] / (sb[0] + 1e-6f);
  }
}

// ---------------- host ----------------
extern "C" void kernel_launch(void* const* d_in, const int* in_sizes, int n_in,
                              void* d_out, int out_size, void* d_ws, size_t ws_size,
                              hipStream_t stream) {
  const int*   input_ids = (const int*)  d_in[0];
  const float* hidden    = (const float*)d_in[1];
  const float* loss_mask = (const float*)d_in[2];
  const int*   anchors   = (const int*)  d_in[3];
  const unsigned char* keep = (const unsigned char*)d_in[4];
  const float* embed     = (const float*)d_in[5];
  const float* Wq        = (const float*)d_in[6];
  const float* Wk        = (const float*)d_in[7];
  const float* Wv        = (const float*)d_in[8];
  const float* Wo        = (const float*)d_in[9];
  const float* Wlm       = (const float*)d_in[10];

  char* ws = (char*)d_ws;
  size_t off = 0;
  auto take = [&](size_t bytes) -> char* {
    char* p = ws + off;
    off += (bytes + 255) & ~(size_t)255;
    return p;
  };
  u16* WqT  = (u16*)take((size_t)512 * 512 * 2);
  u16* WkT  = (u16*)take((size_t)512 * 512 * 2);
  u16* WvT  = (u16*)take((size_t)512 * 512 * 2);
  u16* WoT  = (u16*)take((size_t)512 * 512 * 2);
  u16* WlmT = (u16*)take((size_t)VOCAB * 512 * 2);
  u16* kvb  = (u16*)take((size_t)KVLEN * 512 * 2);
  u16* qb2  = (u16*)take((size_t)QLEN * 512 * 2);
  u16* kb   = (u16*)take((size_t)KVLEN * 512 * 2);
  u16* vTb  = (u16*)take((size_t)512 * KVLEN * 2);
  u16* attnb= (u16*)take((size_t)QLEN * 512 * 2);
  u16* ob   = (u16*)take((size_t)QLEN * 512 * 2);
  float* pl = (float*)take((size_t)QLEN * NSPLIT * 4);
  float* pt = (float*)take((size_t)QLEN * NSPLIT * 4);
  float* pbv= (float*)take((size_t)QLEN * NSPLIT * 4);
  int*   pbi= (int*)  take((size_t)QLEN * NSPLIT * 4);
  float* rowacc = (float*)take((size_t)QLEN * 3 * 4);

  transpose4<<<dim3(16, 16, 4), 256, 0, stream>>>(Wq, Wk, Wv, Wo, WqT, WkT, WvT, WoT);
  transpose_cast<<<dim3(1000, 16), 256, 0, stream>>>(Wlm, WlmT, 512, VOCAB);

  build_kv<<<KVLEN, 128, 0, stream>>>(hidden, embed, input_ids, anchors, keep, kvb);

  gemmTile<0, 2><<<dim3(32, 8), 256, 0, stream>>>(kvb, WkT, kb,  KVLEN, 512, 512, 512);   // k (4096,512)
  gemmTile<1, 2><<<dim3(32, 8), 256, 0, stream>>>(kvb, WvT, vTb, KVLEN, 512, 512, KVLEN); // v^T (512,4096)
  gemmTile<0, 1><<<dim3(32, 8), 256, 0, stream>>>(kvb + (size_t)S_LEN * 512, WqT, qb2, QLEN, 512, 512, 512); // q

  attn_mfma<<<dim3(NBLK, 8), 256, 0, stream>>>(qb2, kb, vTb, anchors, keep, attnb);

  gemmTile<0, 1><<<dim3(32, 8), 256, 0, stream>>>(attnb, WoT, ob, QLEN, 512, 512, 512);   // o = attn @ Wo

  lm_fused<<<4000, 256, 0, stream>>>(ob, WlmT, input_ids, anchors, pl, pt, pbv, pbi);

  loss_rows<<<512, 256, 0, stream>>>(pl, pt, pbv, pbi, input_ids, anchors, keep, loss_mask, rowacc);

  final_sum<<<1, 256, 0, stream>>>(rowacc, (float*)d_out);
}

// Round 9
// 244.122 us; speedup vs baseline: 11.9104x; 1.0154x over previous
//
#include <hip/hip_runtime.h>

typedef unsigned short u16;
typedef __attribute__((ext_vector_type(4))) float f32x4;
typedef __attribute__((ext_vector_type(8))) short short8;
typedef __attribute__((ext_vector_type(4))) unsigned int uv4;
typedef __attribute__((ext_vector_type(4))) float fv4;
typedef __attribute__((ext_vector_type(4))) unsigned short usv4;

#define S_LEN 2048
#define NBLK 128
#define DMODEL 512
#define VOCAB 32000
#define QLEN 2048
#define KVLEN 4096
#define NSPLIT 250   // 32000 vocab / 128-vocab blocks

#define GAS(p) ((const __attribute__((address_space(1))) void*)(const void*)(p))
#define LAS(p) ((__attribute__((address_space(3))) void*)(void*)(p))

__device__ __forceinline__ float bf2f(u16 u){
  union { unsigned int i; float f; } x; x.i = ((unsigned int)u) << 16; return x.f;
}
__device__ __forceinline__ u16 f2bf(float f){
  union { float f; unsigned int i; } x; x.f = f;
  unsigned int r = x.i + 0x7fffu + ((x.i >> 16) & 1u);
  return (u16)(r >> 16);
}

// ---------------- transpose + cast f32(K,N) -> bf16(N,K), 512x512, 4 matrices ----------------
__global__ __launch_bounds__(256) void transpose4(const float* __restrict__ i0, const float* __restrict__ i1,
                                                  const float* __restrict__ i2, const float* __restrict__ i3,
                                                  u16* __restrict__ o0, u16* __restrict__ o1,
                                                  u16* __restrict__ o2, u16* __restrict__ o3){
  const float* in; u16* out;
  switch (blockIdx.z){
    case 0: in = i0; out = o0; break;
    case 1: in = i1; out = o1; break;
    case 2: in = i2; out = o2; break;
    default: in = i3; out = o3; break;
  }
  __shared__ float tile[32][33];
  int t = threadIdx.x, tx = t & 31, ty = t >> 5;
  int nb = blockIdx.x * 32, kb = blockIdx.y * 32;
  #pragma unroll
  for (int i = 0; i < 4; i++){
    int r = ty + i * 8;
    tile[r][tx] = in[(size_t)(kb + r) * 512 + nb + tx];
  }
  __syncthreads();
  #pragma unroll
  for (int i = 0; i < 4; i++){
    int r = ty + i * 8;
    out[(size_t)(nb + r) * 512 + kb + tx] = f2bf(tile[tx][r]);
  }
}

// ---------------- transpose + cast f32(K,N) -> bf16(N,K), generic (for W_lm) ----------------
__global__ __launch_bounds__(256) void transpose_cast(const float* __restrict__ in,
                                                      u16* __restrict__ out,
                                                      int K, int N){
  __shared__ float tile[32][33];
  int t = threadIdx.x, tx = t & 31, ty = t >> 5;
  int nb = blockIdx.x * 32, kb = blockIdx.y * 32;
  #pragma unroll
  for (int i = 0; i < 4; i++){
    int r = ty + i * 8;
    tile[r][tx] = in[(size_t)(kb + r) * N + nb + tx];
  }
  __syncthreads();
  #pragma unroll
  for (int i = 0; i < 4; i++){
    int r = ty + i * 8;
    out[(size_t)(nb + r) * K + kb + tx] = f2bf(tile[tx][r]);
  }
}

// ---------------- build kv_in (bf16 4096x512): [hidden ; noise_embedding] ----------------
__global__ __launch_bounds__(128) void build_kv(const float* __restrict__ hidden,
                                                const float* __restrict__ embed,
                                                const int* __restrict__ input_ids,
                                                const int* __restrict__ anchors,
                                                const unsigned char* __restrict__ keep,
                                                u16* __restrict__ kvb){
  int row = blockIdx.x;           // 0..4095
  int t = threadIdx.x;            // 0..127
  const float* src;
  if (row < S_LEN){
    src = hidden + (size_t)row * DMODEL;
  } else {
    int q = row - S_LEN;
    int id = 3;                   // MASK_TOKEN_ID
    if ((q & 15) == 0){
      int n = q >> 4;
      if (keep[n]){
        int a = anchors[n]; a = min(max(a, 0), S_LEN - 1);
        id = input_ids[a];
      }
    }
    src = embed + (size_t)id * DMODEL;
  }
  int c = t * 4;
  fv4 v = *(const fv4*)&src[c];
  usv4 o; o[0] = f2bf(v[0]); o[1] = f2bf(v[1]); o[2] = f2bf(v[2]); o[3] = f2bf(v[3]);
  *(usv4*)&kvb[(size_t)row * DMODEL + c] = o;
}

// ---------------- projection GEMM: (64*MF)x64 tile, gload_lds staged, XOR-swizzled,
// counted-vmcnt double-buffer (2 raw barriers per K-step, loads stay in flight) ----------------
template<int TRANS, int MF>
__global__ __launch_bounds__(256) void gemmTile(const u16* __restrict__ A,
                                                const u16* __restrict__ BT,
                                                u16* __restrict__ C,
                                                int M, int N, int K, int ldc){
  __shared__ __align__(16) u16 As[2][64 * MF * 64];
  __shared__ __align__(16) u16 Bs[2][64 * 64];
  int t = threadIdx.x, w = t >> 6, lane = t & 63;
  int g = lane >> 4, li = lane & 15;
  int rowbase = blockIdx.x * (64 * MF), colbase = blockIdx.y * 64;
  int r0 = t >> 3, cg0 = t & 7;
  int swz = (cg0 ^ (r0 & 7)) << 3;

  auto stageA = [&](u16* dst, int kb){
    #pragma unroll
    for (int i = 0; i < 2 * MF; i++)
      __builtin_amdgcn_global_load_lds(GAS(&A[(size_t)(rowbase + r0 + i * 32) * K + kb + swz]),
                                       LAS(dst + i * 2048 + w * 512), 16, 0, 0);
  };
  auto stageB = [&](u16* dst, int kb){
    #pragma unroll
    for (int i = 0; i < 2; i++)
      __builtin_amdgcn_global_load_lds(GAS(&BT[(size_t)(colbase + r0 + i * 32) * K + kb + swz]),
                                       LAS(dst + i * 2048 + w * 512), 16, 0, 0);
  };

  f32x4 acc[MF][4];
  #pragma unroll
  for (int i = 0; i < MF; i++)
    #pragma unroll
    for (int j = 0; j < 4; j++)
      acc[i][j] = (f32x4){0.f, 0.f, 0.f, 0.f};

  stageA(As[0], 0); stageB(Bs[0], 0);

  int nkt = K >> 6;
  for (int kt = 0; kt < nkt; kt++){
    u16* curA = As[kt & 1]; u16* curB = Bs[kt & 1];
    if (kt + 1 < nkt){
      stageA(As[(kt + 1) & 1], (kt + 1) * 64); stageB(Bs[(kt + 1) & 1], (kt + 1) * 64);
      // wait only for stage(kt): the 2*MF+2 loads just issued stay in flight
      if constexpr (MF == 2) asm volatile("s_waitcnt vmcnt(6)" ::: "memory");
      else                   asm volatile("s_waitcnt vmcnt(4)" ::: "memory");
    } else {
      asm volatile("s_waitcnt vmcnt(0)" ::: "memory");
    }
    __builtin_amdgcn_s_barrier();          // all waves: stage(kt) data visible
    #pragma unroll
    for (int ks = 0; ks < 2; ks++){
      short8 af[MF], bf[4];
      #pragma unroll
      for (int mf = 0; mf < MF; mf++){
        int row = w * 16 * MF + mf * 16 + li;
        af[mf] = *(const short8*)&curA[row * 64 + (((ks * 4 + g) ^ (li & 7)) << 3)];
      }
      #pragma unroll
      for (int nf = 0; nf < 4; nf++){
        int row = nf * 16 + li;
        bf[nf] = *(const short8*)&curB[row * 64 + (((ks * 4 + g) ^ (li & 7)) << 3)];
      }
      #pragma unroll
      for (int mf = 0; mf < MF; mf++)
        #pragma unroll
        for (int nf = 0; nf < 4; nf++)
          acc[mf][nf] = __builtin_amdgcn_mfma_f32_16x16x32_bf16(af[mf], bf[nf], acc[mf][nf], 0, 0, 0);
    }
    __builtin_amdgcn_s_barrier();          // all waves done reading buf[kt&1]
  }

  #pragma unroll
  for (int mf = 0; mf < MF; mf++)
    #pragma unroll
    for (int nf = 0; nf < 4; nf++)
      #pragma unroll
      for (int r = 0; r < 4; r++){
        int row = rowbase + w * 16 * MF + mf * 16 + g * 4 + r;
        int col = colbase + nf * 16 + li;
        u16 vv = f2bf(acc[mf][nf][r]);
        if (TRANS) C[(size_t)col * ldc + row] = vv;
        else       C[(size_t)row * ldc + col] = vv;
      }
}

// ---------------- MFMA flash attention: one (draft block n, head h) per workgroup ----------------
__global__ __launch_bounds__(256) void attn_mfma(const u16* __restrict__ qb,
                                                 const u16* __restrict__ kb,
                                                 const u16* __restrict__ vT,
                                                 const int* __restrict__ anchors,
                                                 const unsigned char* __restrict__ keep,
                                                 u16* __restrict__ attnb){
  int n = blockIdx.x, h = blockIdx.y;
  int t = threadIdx.x, w = t >> 6, lane = t & 63;
  int g = lane >> 4, li = lane & 15;

  __shared__ __align__(16) u16 q_s[16][72];
  __shared__ __align__(16) u16 p_s[4][16][72];
  __shared__ float o_s[4][16][64];
  __shared__ float ml_s[4][2][16];

  {
    int r = t >> 4, c4 = (t & 15) * 4;
    *(usv4*)&q_s[r][c4] = *(const usv4*)&qb[(size_t)(n * 16 + r) * DMODEL + h * 64 + c4];
  }
  __syncthreads();

  int anchor = anchors[n];
  bool kp = keep[n] != 0;
  const u16* kh  = kb + h * 64;
  const u16* vTh = vT + (size_t)(h * 64) * KVLEN;

  if (!kp){
    if (w == 0){
      float acc = 0.f;
      const u16* row = vTh + (size_t)lane * KVLEN;
      for (int k2 = 0; k2 < KVLEN; k2 += 8){
        short8 vv = *(const short8*)&row[k2];
        #pragma unroll
        for (int j = 0; j < 8; j++) acc += bf2f((u16)vv[j]);
      }
      acc *= (1.f / 4096.f);
      u16 ov = f2bf(acc);
      for (int r = 0; r < 16; r++)
        attnb[(size_t)(n * 16 + r) * DMODEL + h * 64 + lane] = ov;
    }
    return;
  }

  short8 qa[2];
  #pragma unroll
  for (int ks = 0; ks < 2; ks++)
    qa[ks] = *(const short8*)&q_s[li][ks * 32 + g * 8];

  int nctx = (anchor + 63) >> 6;
  int ntot = nctx + 1;

  f32x4 o_acc[4];
  float m[4], l[4];
  #pragma unroll
  for (int i = 0; i < 4; i++){ o_acc[i] = (f32x4){0.f,0.f,0.f,0.f}; m[i] = -3e38f; l[i] = 0.f; }

  for (int c = w; c < ntot; c += 4){
    bool draft = (c == nctx);
    int kbase = draft ? (S_LEN + n * 16) : c * 64;
    int nk    = draft ? 16 : min(64, anchor - c * 64);

    f32x4 s[4];
    #pragma unroll
    for (int nf = 0; nf < 4; nf++) s[nf] = (f32x4){0.f,0.f,0.f,0.f};
    #pragma unroll
    for (int ks = 0; ks < 2; ks++){
      #pragma unroll
      for (int nf = 0; nf < 4; nf++){
        int krow = min(kbase + nf * 16 + li, KVLEN - 1);
        short8 bfrag = *(const short8*)&kh[(size_t)krow * DMODEL + ks * 32 + g * 8];
        s[nf] = __builtin_amdgcn_mfma_f32_16x16x32_bf16(qa[ks], bfrag, s[nf], 0, 0, 0);
      }
    }

    #pragma unroll
    for (int r = 0; r < 4; r++){
      float mx = -3e38f;
      #pragma unroll
      for (int nf = 0; nf < 4; nf++){
        float sv = s[nf][r] * 0.125f;
        if (nf * 16 + li >= nk) sv = -3e38f;
        s[nf][r] = sv;
        mx = fmaxf(mx, sv);
      }
      #pragma unroll
      for (int mm = 1; mm < 16; mm <<= 1) mx = fmaxf(mx, __shfl_xor(mx, mm));
      float mn = fmaxf(m[r], mx);
      float sc = __expf(m[r] - mn);
      float ps = 0.f;
      #pragma unroll
      for (int nf = 0; nf < 4; nf++){
        float p = __expf(s[nf][r] - mn);
        ps += p;
        p_s[w][g * 4 + r][nf * 16 + li] = f2bf(p);
      }
      #pragma unroll
      for (int mm = 1; mm < 16; mm <<= 1) ps += __shfl_xor(ps, mm);
      l[r] = l[r] * sc + ps;
      m[r] = mn;
      #pragma unroll
      for (int nfd = 0; nfd < 4; nfd++) o_acc[nfd][r] *= sc;
    }

    #pragma unroll
    for (int ks = 0; ks < 2; ks++){
      short8 pa = *(const short8*)&p_s[w][li][ks * 32 + g * 8];
      int kcol = min(kbase + ks * 32 + g * 8, KVLEN - 8);
      #pragma unroll
      for (int nfd = 0; nfd < 4; nfd++){
        short8 vfrag = *(const short8*)&vTh[(size_t)(nfd * 16 + li) * KVLEN + kcol];
        o_acc[nfd] = __builtin_amdgcn_mfma_f32_16x16x32_bf16(pa, vfrag, o_acc[nfd], 0, 0, 0);
      }
    }
  }

  #pragma unroll
  for (int r = 0; r < 4; r++){
    if (li == 0){ ml_s[w][0][g * 4 + r] = m[r]; ml_s[w][1][g * 4 + r] = l[r]; }
    #pragma unroll
    for (int nfd = 0; nfd < 4; nfd++)
      o_s[w][g * 4 + r][nfd * 16 + li] = o_acc[nfd][r];
  }
  __syncthreads();

  {
    int row = t >> 4, c0 = (t & 15) * 4;
    float M = -3e38f;
    #pragma unroll
    for (int ww = 0; ww < 4; ww++) M = fmaxf(M, ml_s[ww][0][row]);
    float L = 0.f, ew[4];
    #pragma unroll
    for (int ww = 0; ww < 4; ww++){
      ew[ww] = __expf(ml_s[ww][0][row] - M);
      L += ml_s[ww][1][row] * ew[ww];
    }
    float inv = 1.f / L;
    #pragma unroll
    for (int j = 0; j < 4; j++){
      float ov = 0.f;
      #pragma unroll
      for (int ww = 0; ww < 4; ww++) ov += o_s[ww][row][c0 + j] * ew[ww];
      attnb[(size_t)(n * 16 + row) * DMODEL + h * 64 + c0 + j] = f2bf(ov * inv);
    }
  }
}

// ---------------- LM head: 128q x 128vocab, BK=32 double-buffer (LDS ~33KB -> 4 blocks/CU),
// counted-vmcnt 2-barrier pipeline + setprio; swapped operands for lane-local stats;
// combine scratch ALIASED onto Wb after the K-loop; coalesced [split][row] partials. ----------------
__global__ __launch_bounds__(256) void lm_fused(const u16* __restrict__ obp,
                                                const u16* __restrict__ WT,
                                                const int* __restrict__ input_ids,
                                                const int* __restrict__ anchors,
                                                float* __restrict__ pl,
                                                float* __restrict__ pt, float* __restrict__ pbv,
                                                int* __restrict__ pbi){
  __shared__ __align__(16) u16 Wb[2][128 * 32];
  __shared__ __align__(16) u16 Ob[2][128 * 32];
  __shared__ int tcol_s[128];

  int L = blockIdx.x;                       // 0..3999
  int T = (L & 7) * 500 + (L >> 3);         // bijective (4000 % 8 == 0); XCD-contiguous T ranges
  int qbase = (T & 15) * 128;               // q fastest within an XCD -> W slice reused in its L2
  int vb = T >> 4;                          // 0..249 vocab block
  int vocabbase = vb * 128;
  int t = threadIdx.x, w = t >> 6, lane = t & 63;
  int g = lane >> 4, li = lane & 15;

  if (t < 128){
    int r = qbase + t; int n = r >> 4, off = r & 15;
    int lab = anchors[n] + off;
    int safe = min(max(lab, 0), S_LEN - 1);
    tcol_s[t] = input_ids[safe];
  }

  // [128][32] bf16 tile (64B rows). Stored col-group cg holds logical group cg^((r>>1)&3):
  // within any 16-consecutive-lane read group -> 2 lanes/bank-class (free).
  int sr = t >> 2;                          // row within 64-row round
  int scg = (t & 3) ^ ((sr >> 1) & 3);      // pre-swizzled SOURCE col-group (involution)
  auto stage = [&](u16* wdst, u16* odst, int kb){
    #pragma unroll
    for (int i = 0; i < 2; i++){
      __builtin_amdgcn_global_load_lds(GAS(&WT [(size_t)(vocabbase + i * 64 + sr) * DMODEL + kb + (scg << 3)]),
                                       LAS(wdst + i * 2048 + w * 512), 16, 0, 0);
      __builtin_amdgcn_global_load_lds(GAS(&obp[(size_t)(qbase     + i * 64 + sr) * DMODEL + kb + (scg << 3)]),
                                       LAS(odst + i * 2048 + w * 512), 16, 0, 0);
    }
  };

  f32x4 acc[2][8];
  #pragma unroll
  for (int i = 0; i < 2; i++)
    #pragma unroll
    for (int j = 0; j < 8; j++)
      acc[i][j] = (f32x4){0.f, 0.f, 0.f, 0.f};

  stage(Wb[0], Ob[0], 0);

  int cgr = (g ^ ((li >> 1) & 3)) << 3;     // u16 offset of this lane's 8-elem k-group
  for (int kt = 0; kt < 16; kt++){
    const u16* curW = Wb[kt & 1]; const u16* curO = Ob[kt & 1];
    if (kt < 15){
      stage(Wb[(kt + 1) & 1], Ob[(kt + 1) & 1], (kt + 1) * 32);
      asm volatile("s_waitcnt vmcnt(4)" ::: "memory");   // stage(kt) landed; stage(kt+1) in flight
    } else {
      asm volatile("s_waitcnt vmcnt(0)" ::: "memory");
    }
    __builtin_amdgcn_s_barrier();          // all waves: stage(kt) visible
    __builtin_amdgcn_s_setprio(1);
    short8 wfr[2], obf[8];
    #pragma unroll
    for (int vf = 0; vf < 2; vf++)
      wfr[vf] = *(const short8*)&curW[(w * 32 + vf * 16 + li) * 32 + cgr];
    #pragma unroll
    for (int qf = 0; qf < 8; qf++)
      obf[qf] = *(const short8*)&curO[(qf * 16 + li) * 32 + cgr];
    #pragma unroll
    for (int vf = 0; vf < 2; vf++)
      #pragma unroll
      for (int qf = 0; qf < 8; qf++)
        acc[vf][qf] = __builtin_amdgcn_mfma_f32_16x16x32_bf16(wfr[vf], obf[qf], acc[vf][qf], 0, 0, 0);
    __builtin_amdgcn_s_setprio(0);
    __builtin_amdgcn_s_barrier();          // all waves done reading buf[kt&1]
  }
  __syncthreads();                          // full memory barrier before aliasing Wb as scratch

  // combine scratch aliased onto Wb (8KB within its 16KB)
  u16* sb = &Wb[0][0];
  float* cse = (float*)(sb);                // [4][128]
  float* ctv = (float*)(sb + 1024);
  float* cbv = (float*)(sb + 2048);
  int*   cbi = (int*)  (sb + 3072);

  // per-lane stats over this wave's 32-vocab slice, per q-column (lane-local)
  #pragma unroll
  for (int qf = 0; qf < 8; qf++){
    int qloc = qf * 16 + li;
    int tc = tcol_s[qloc] - vocabbase;     // target pos within the 128-vocab block
    float se = 0.f, tv = -3e38f, bv = -3e38f; int bi = 0x7fffffff;
    #pragma unroll
    for (int vf = 0; vf < 2; vf++){
      #pragma unroll
      for (int r = 0; r < 4; r++){
        float v = acc[vf][qf][r];
        int pos = w * 32 + vf * 16 + g * 4 + r;
        se += __expf(v);
        if (pos == tc) tv = v;
        if (v > bv){ bv = v; bi = pos; }
      }
    }
    #pragma unroll
    for (int off = 16; off <= 32; off <<= 1){
      se += __shfl_xor(se, off);
      tv = fmaxf(tv, __shfl_xor(tv, off));
      float ob_ = __shfl_xor(bv, off); int oi = __shfl_xor(bi, off);
      if (ob_ > bv || (ob_ == bv && oi < bi)){ bv = ob_; bi = oi; }
    }
    if (g == 0){
      cse[w * 128 + qloc] = se; ctv[w * 128 + qloc] = tv;
      cbv[w * 128 + qloc] = bv; cbi[w * 128 + qloc] = bi;
    }
  }
  __syncthreads();

  if (t < 128){
    float SE = 0.f, TV = -3e38f, BV = -3e38f; int BI = 0x7fffffff;
    #pragma unroll
    for (int ww = 0; ww < 4; ww++){
      SE += cse[ww * 128 + t];
      TV = fmaxf(TV, ctv[ww * 128 + t]);
      float v = cbv[ww * 128 + t];
      if (v > BV){ BV = v; BI = cbi[ww * 128 + t]; }  // waves ascend in vocab: strict > keeps first-max
    }
    size_t idx = (size_t)vb * QLEN + qbase + t;  // [split][row] -> coalesced
    pl[idx] = SE; pt[idx] = TV; pbv[idx] = BV; pbi[idx] = vocabbase + BI;
  }
}

// ---------------- per-row split merge: one wave per row ----------------
__global__ __launch_bounds__(256) void loss_rows(const float* __restrict__ pl,
                                                 const float* __restrict__ pt, const float* __restrict__ pbv,
                                                 const int* __restrict__ pbi,
                                                 const int* __restrict__ input_ids,
                                                 const int* __restrict__ anchors,
                                                 const unsigned char* __restrict__ keep,
                                                 const float* __restrict__ loss_mask,
                                                 float* __restrict__ rowacc){
  int t = threadIdx.x, w = t >> 6, lane = t & 63;
  int row = blockIdx.x * 4 + w;
  float L = 0.f, TV = -3e38f, BV = -3e38f; int BI = 0x7fffffff;
  for (int s = lane; s < NSPLIT; s += 64){
    size_t idx = (size_t)s * QLEN + row;    // [split][row]
    L += pl[idx];
    TV = fmaxf(TV, pt[idx]);
    float bv_ = pbv[idx]; int bi_ = pbi[idx];
    if (bv_ > BV || (bv_ == BV && bi_ < BI)){ BV = bv_; BI = bi_; }
  }
  #pragma unroll
  for (int mm = 1; mm < 64; mm <<= 1){
    L += __shfl_xor(L, mm);
    TV = fmaxf(TV, __shfl_xor(TV, mm));
    float ob = __shfl_xor(BV, mm); int oi = __shfl_xor(BI, mm);
    if (ob > BV || (ob == BV && oi < BI)){ BV = ob; BI = oi; }
  }
  if (lane == 0){
    int n = row >> 4, off = row & 15;
    int lab = anchors[n] + off;
    int valid = (lab < S_LEN) ? 1 : 0;
    int safe = min(max(lab, 0), S_LEN - 1);
    int tgt = input_ids[safe];
    float wgt = (keep[n] ? 1.f : 0.f) * (valid ? 1.f : 0.f) * ((off > 0) ? 1.f : 0.f) * loss_mask[safe];
    float logp = TV - __logf(L);
    rowacc[row * 3 + 0] = -logp * wgt;
    rowacc[row * 3 + 1] = wgt;
    rowacc[row * 3 + 2] = ((BI == tgt) && (wgt > 0.5f)) ? 1.f : 0.f;
  }
}

// ---------------- final sum over rows ----------------
__global__ __launch_bounds__(256) void final_sum(const float* __restrict__ rowacc, float* __restrict__ out){
  int t = threadIdx.x;
  float a = 0.f, b = 0.f, c = 0.f;
  for (int r = t; r < QLEN; r += 256){
    a += rowacc[r * 3 + 0]; b += rowacc[r * 3 + 1]; c += rowacc[r * 3 + 2];
  }
  __shared__ float sa[256], sb[256], sc_[256];
  sa[t] = a; sb[t] = b; sc_[t] = c;
  __syncthreads();
  for (int s = 128; s >= 1; s >>= 1){
    if (t < s){ sa[t] += sa[t + s]; sb[t] += sb[t + s]; sc_[t] += sc_[t + s]; }
    __syncthreads();
  }
  if (t == 0){
    out[0] = sa[0] / (sb[0] + 1e-6f);
    out[1] = sc_[0] / (sb[0] + 1e-6f);
  }
}

// ---------------- host ----------------
extern "C" void kernel_launch(void* const* d_in, const int* in_sizes, int n_in,
                              void* d_out, int out_size, void* d_ws, size_t ws_size,
                              hipStream_t stream) {
  const int*   input_ids = (const int*)  d_in[0];
  const float* hidden    = (const float*)d_in[1];
  const float* loss_mask = (const float*)d_in[2];
  const int*   anchors   = (const int*)  d_in[3];
  const unsigned char* keep = (const unsigned char*)d_in[4];
  const float* embed     = (const float*)d_in[5];
  const float* Wq        = (const float*)d_in[6];
  const float* Wk        = (const float*)d_in[7];
  const float* Wv        = (const float*)d_in[8];
  const float* Wo        = (const float*)d_in[9];
  const float* Wlm       = (const float*)d_in[10];

  char* ws = (char*)d_ws;
  size_t off = 0;
  auto take = [&](size_t bytes) -> char* {
    char* p = ws + off;
    off += (bytes + 255) & ~(size_t)255;
    return p;
  };
  u16* WqT  = (u16*)take((size_t)512 * 512 * 2);
  u16* WkT  = (u16*)take((size_t)512 * 512 * 2);
  u16* WvT  = (u16*)take((size_t)512 * 512 * 2);
  u16* WoT  = (u16*)take((size_t)512 * 512 * 2);
  u16* WlmT = (u16*)take((size_t)VOCAB * 512 * 2);
  u16* kvb  = (u16*)take((size_t)KVLEN * 512 * 2);
  u16* qb2  = (u16*)take((size_t)QLEN * 512 * 2);
  u16* kb   = (u16*)take((size_t)KVLEN * 512 * 2);
  u16* vTb  = (u16*)take((size_t)512 * KVLEN * 2);
  u16* attnb= (u16*)take((size_t)QLEN * 512 * 2);
  u16* ob   = (u16*)take((size_t)QLEN * 512 * 2);
  float* pl = (float*)take((size_t)QLEN * NSPLIT * 4);
  float* pt = (float*)take((size_t)QLEN * NSPLIT * 4);
  float* pbv= (float*)take((size_t)QLEN * NSPLIT * 4);
  int*   pbi= (int*)  take((size_t)QLEN * NSPLIT * 4);
  float* rowacc = (float*)take((size_t)QLEN * 3 * 4);

  transpose4<<<dim3(16, 16, 4), 256, 0, stream>>>(Wq, Wk, Wv, Wo, WqT, WkT, WvT, WoT);
  transpose_cast<<<dim3(1000, 16), 256, 0, stream>>>(Wlm, WlmT, 512, VOCAB);

  build_kv<<<KVLEN, 128, 0, stream>>>(hidden, embed, input_ids, anchors, keep, kvb);

  gemmTile<0, 2><<<dim3(32, 8), 256, 0, stream>>>(kvb, WkT, kb,  KVLEN, 512, 512, 512);   // k (4096,512)
  gemmTile<1, 2><<<dim3(32, 8), 256, 0, stream>>>(kvb, WvT, vTb, KVLEN, 512, 512, KVLEN); // v^T (512,4096)
  gemmTile<0, 1><<<dim3(32, 8), 256, 0, stream>>>(kvb + (size_t)S_LEN * 512, WqT, qb2, QLEN, 512, 512, 512); // q

  attn_mfma<<<dim3(NBLK, 8), 256, 0, stream>>>(qb2, kb, vTb, anchors, keep, attnb);

  gemmTile<0, 1><<<dim3(32, 8), 256, 0, stream>>>(attnb, WoT, ob, QLEN, 512, 512, 512);   // o = attn @ Wo

  lm_fused<<<4000, 256, 0, stream>>>(ob, WlmT, input_ids, anchors, pl, pt, pbv, pbi);

  loss_rows<<<512, 256, 0, stream>>>(pl, pt, pbv, pbi, input_ids, anchors, keep, loss_mask, rowacc);

  final_sum<<<1, 256, 0, stream>>>(rowacc, (float*)d_out);
}